// Round 13
// baseline (304.427 us; speedup 1.0000x reference)
//
#include <hip/hip_runtime.h>
#include <hip/hip_bf16.h>
#include <math.h>

#define BB 64
#define KV 128
#define ME 256
#define NH 256
#define DC 684
#define DA 512
#define MC 256
#define HH_ 16
#define WW_ 48
#define HW_ 768
#define NS 22   // K-steps of 32 (684 -> 704 padded)

typedef __attribute__((ext_vector_type(8))) short bf16x8;
typedef __attribute__((ext_vector_type(4))) float f32x4;

// workspace layout (floats)
#define WS_G     0                    // 512*9
#define WS_RB    (WS_G + 4608)        // rowbias 64*512
#define WS_EMB   (WS_RB + 32768)      // 64*256
#define WS_SH    (WS_EMB + 16384)     // 64*256 s_hat
#define WS_AL    (WS_SH + 16384)      // 64*768 alpha logits (fallback)
#define WS_CT    (WS_AL + 49152)      // 64*684 ct
#define WS_APACK (WS_CT + 43776)      // 22*512*32 bf16 = 180224 floats
#define WS_GI    (WS_APACK + 180224)  // 64*768
#define WS_GH    (WS_GI + 49152)      // 64*768
#define WS_LG    WS_GI                // logit 64*256 reuses GI after gru2
#define WS_BP    (WS_GH + 49152)      // = 441600; Bpack 64*12*22*2048 bf16
#define WS_ALQ   (WS_BP + 17301504)   // 4 x 64*768 alpha-logit quarters
#define NEED_BYTES ((size_t)(441600 + 17301504 + 196608) * 4)

static __device__ __forceinline__ unsigned short f2b(float v) {
    __hip_bfloat16 h = __float2bfloat16(v);
    return *reinterpret_cast<unsigned short*>(&h);
}

// async global->LDS, 16B per lane. LDS base must be wave-uniform; HW adds
// lane*16. Global address is per-lane. AUX = CPol: 0 = cached, 2 = NT.
template <int AUX>
static __device__ __forceinline__ void gl_lds16(const unsigned short* g,
                                                unsigned short* l) {
    __builtin_amdgcn_global_load_lds(
        (const __attribute__((address_space(1))) unsigned int*)g,
        (__attribute__((address_space(3))) unsigned int*)l, 16, 0, AUX);
}

// =================== fused prep ============================================
__global__ __launch_bounds__(512) void k_prep(
    const float* __restrict__ ctx, const float* __restrict__ Ua,
    const float* __restrict__ Uf, const float* __restrict__ convQ,
    const int* __restrict__ y, const float* __restrict__ emb,
    unsigned short* __restrict__ Bpack, unsigned short* __restrict__ Apack,
    float* __restrict__ G, float* __restrict__ embedded) {
    __shared__ unsigned short Ts[64 * 360];  // 45 KB
    int bx = blockIdx.x, t = threadIdx.x;
    if (bx < 768) {
        int b = bx / 12, pt = bx % 12, p0 = pt * 64;
        int w = t >> 6, p = t & 63;  // 8 waves, lane = p
        unsigned short* dst = Bpack + (long)(b * 12 + pt) * 22 * 2048;
        for (int ch = 0; ch < 2; ch++) {
            int dbase = ch * 352;
            if (ch) __syncthreads();
#pragma unroll
            for (int iter = 0; iter < 11; iter++) {
                int d0 = dbase + iter * 32 + w * 4;
                float v0 = 0.f, v1 = 0.f, v2 = 0.f, v3 = 0.f;
                const float* src = ctx + ((long)b * DC + d0) * HW_ + p0 + p;
                if (d0 + 0 < DC) v0 = src[0];
                if (d0 + 1 < DC) v1 = src[HW_];
                if (d0 + 2 < DC) v2 = src[2 * HW_];
                if (d0 + 3 < DC) v3 = src[3 * HW_];
                unsigned u01 = (unsigned)f2b(v0) | ((unsigned)f2b(v1) << 16);
                unsigned u23 = (unsigned)f2b(v2) | ((unsigned)f2b(v3) << 16);
                *(uint2*)&Ts[p * 360 + (d0 - dbase)] = make_uint2(u01, u23);
            }
            __syncthreads();
            int so = t >> 8;
            int tt = t & 255;
            int pp = tt >> 2, slot = tt & 3;
#pragma unroll
            for (int s2 = 0; s2 < 12; s2 += 2) {
                int sl = s2 + so;
                if (sl < 11) {
                    int s = ch * 11 + sl;
                    bf16x8 v = *(const bf16x8*)&Ts[pp * 360 + sl * 32 +
                                                   ((slot ^ ((pp >> 1) & 3))
                                                    << 3)];
                    *(bf16x8*)(dst + (long)(s * 256 + tt) * 8) = v;
                }
            }
        }
    } else if (bx < 856) {
        int bi = bx - 768;
#pragma unroll
        for (int r = 0; r < 8; r++) {
            int idx = bi * 4096 + r * 512 + t;
            int e = idx & 7, slot = (idx >> 3) & 3;
            int a = (idx >> 5) & 511, s = idx >> 14;
            int d = s * 32 + ((slot ^ ((a >> 1) & 3)) << 3) + e;
            float v = (d < DC) ? Ua[a * DC + d] : 0.f;
            Apack[idx] = f2b(v);
        }
    } else if (bx < 865) {
        int idx = (bx - 856) * 512 + t;
        if (idx < DA * 9) {
            int a = idx / 9, k = idx % 9;
            float s = 0.f;
            for (int m = 0; m < MC; m++) s += Uf[a * MC + m] * convQ[m * 9 + k];
            G[idx] = s;
        }
    } else {
        int b = bx - 865;
        if (t < ME) embedded[b * ME + t] = emb[y[b] * ME + t];
    }
}

// =================== fallback-path prep kernels ============================
__global__ __launch_bounds__(256) void k_G(const float* __restrict__ Uf,
                                           const float* __restrict__ convQ,
                                           float* __restrict__ G) {
    int idx = blockIdx.x * 256 + threadIdx.x;
    if (idx >= DA * 9) return;
    int a = idx / 9, k = idx % 9;
    float s = 0.f;
    for (int m = 0; m < MC; m++) s += Uf[a * MC + m] * convQ[m * 9 + k];
    G[idx] = s;
}

__global__ __launch_bounds__(256) void k_prepA(const float* __restrict__ Ua,
                                               unsigned short* __restrict__ Apack) {
    int idx = blockIdx.x * 256 + threadIdx.x;
    if (idx >= NS * DA * 32) return;
    int e = idx & 7, slot = (idx >> 3) & 3;
    int a = (idx >> 5) & 511, s = idx >> 14;
    int d = s * 32 + ((slot ^ ((a >> 1) & 3)) << 3) + e;
    float v = (d < DC) ? Ua[a * DC + d] : 0.f;
    Apack[idx] = f2b(v);
}

__global__ __launch_bounds__(256) void k_emb(const int* __restrict__ y,
                                             const float* __restrict__ emb,
                                             float* __restrict__ embedded) {
    int b = blockIdx.x, t = threadIdx.x;
    embedded[b * ME + t] = emb[y[b] * ME + t];
}

// ------- generic rows-of-W kernel, K=256 -----------------------------------
__global__ __launch_bounds__(256) void k_rows256(
    const float* __restrict__ X, const float* __restrict__ W,
    const float* __restrict__ bias, const float* __restrict__ bias2,
    float* __restrict__ out, int outStride) {
    __shared__ float Xs[64 * 257];
    __shared__ float Ws[4 * 260];
    int t = threadIdx.x, w = t >> 6, lane = t & 63;
    for (int i = t; i < 64 * 256; i += 256) {
        int bb = i >> 8, k = i & 255;
        Xs[bb * 257 + k] = X[bb * 256 + k];
    }
    int r = blockIdx.x * 4 + w;
    *(f32x4*)(Ws + w * 260 + lane * 4) = *(const f32x4*)(W + r * 256 + lane * 4);
    __syncthreads();
    const float* xrow = Xs + lane * 257;
    const float* wrow = Ws + w * 260;
    float acc = 0.f;
#pragma unroll 8
    for (int k = 0; k < 256; k++) acc += wrow[k] * xrow[k];
    acc += bias[r];
    if (bias2) acc += bias2[r];
    out[lane * outStride + r] = acc;
}

// ------- fused GRU1 gate GEMVs ---------------------------------------------
__global__ __launch_bounds__(256) void k_gih1(
    const float* __restrict__ embedded, const float* __restrict__ pre_hidden,
    const float* __restrict__ W_ih1, const float* __restrict__ W_hh1,
    const float* __restrict__ b_ih1, const float* __restrict__ b_hh1,
    float* __restrict__ gi, float* __restrict__ gh) {
    __shared__ float Xs[64 * 257];
    __shared__ float Ws[4 * 260];
    int bx = blockIdx.x, t = threadIdx.x, w = t >> 6, lane = t & 63;
    const float *X, *W, *bias;
    float* outp;
    int r;
    if (bx < 192) {
        X = embedded; W = W_ih1; bias = b_ih1; outp = gi; r = bx * 4 + w;
    } else {
        X = pre_hidden; W = W_hh1; bias = b_hh1; outp = gh; r = (bx - 192) * 4 + w;
    }
    for (int i = t; i < 64 * 256; i += 256) {
        int bb = i >> 8, k = i & 255;
        Xs[bb * 257 + k] = X[bb * 256 + k];
    }
    *(f32x4*)(Ws + w * 260 + lane * 4) = *(const f32x4*)(W + r * 256 + lane * 4);
    __syncthreads();
    const float* xrow = Xs + lane * 257;
    const float* wrow = Ws + w * 260;
    float acc = 0.f;
#pragma unroll 8
    for (int k = 0; k < 256; k++) acc += wrow[k] * xrow[k];
    outp[lane * 768 + r] = acc + bias[r];
}

// ------- fused GRU2 gate GEMVs ---------------------------------------------
__global__ __launch_bounds__(256) void k_gih2(
    const float* __restrict__ ctv, const float* __restrict__ s_hat,
    const float* __restrict__ W_ih2, const float* __restrict__ W_hh2,
    const float* __restrict__ b_ih2, const float* __restrict__ b_hh2,
    float* __restrict__ gi, float* __restrict__ gh) {
    __shared__ float Xs[64 * 257];
    __shared__ float Ws[4 * 260];
    int bx = blockIdx.x, t = threadIdx.x, w = t >> 6, lane = t & 63;
    if (bx < 192) {
        int r = bx * 4 + w;
        float acc = 0.f;
        for (int c = 0; c < 3; c++) {
            int c0 = c * 228;
            __syncthreads();
            for (int i = t; i < 64 * 228; i += 256) {
                int bb = i / 228, kk = i - bb * 228;
                Xs[bb * 229 + kk] = ctv[bb * DC + c0 + kk];
            }
            for (int j = lane; j < 228; j += 64)
                Ws[w * 260 + j] = W_ih2[r * DC + c0 + j];
            __syncthreads();
            const float* xrow = Xs + lane * 229;
            const float* wrow = Ws + w * 260;
#pragma unroll 4
            for (int k = 0; k < 228; k++) acc += wrow[k] * xrow[k];
        }
        gi[lane * 768 + r] = acc + b_ih2[r];
    } else {
        int r = (bx - 192) * 4 + w;
        for (int i = t; i < 64 * 256; i += 256) {
            int bb = i >> 8, k = i & 255;
            Xs[bb * 257 + k] = s_hat[bb * 256 + k];
        }
        *(f32x4*)(Ws + w * 260 + lane * 4) =
            *(const f32x4*)(W_hh2 + r * 256 + lane * 4);
        __syncthreads();
        const float* xrow = Xs + lane * 257;
        const float* wrow = Ws + w * 260;
        float acc = 0.f;
#pragma unroll 8
        for (int k = 0; k < 256; k++) acc += wrow[k] * xrow[k];
        gh[lane * 768 + r] = acc + b_hh2[r];
    }
}

// ---------------- GRU elementwise ------------------------------------------
__global__ __launch_bounds__(256) void k_gru(const float* __restrict__ gi,
                                             const float* __restrict__ gh,
                                             const float* __restrict__ h,
                                             const float* __restrict__ y_mask,
                                             float* __restrict__ outp) {
    int b = blockIdx.x, t = threadIdx.x;
    float hv = h[b * NH + t];
    float r = 1.f / (1.f + expf(-(gi[b * 768 + t] + gh[b * 768 + t])));
    float z = 1.f / (1.f + expf(-(gi[b * 768 + 256 + t] + gh[b * 768 + 256 + t])));
    float n = tanhf(gi[b * 768 + 512 + t] + r * gh[b * 768 + 512 + t]);
    float sv = (1.f - z) * n + z * hv;
    float m = y_mask[b];
    outp[b * NH + t] = m * sv + (1.f - m) * hv;
}

// ======= K2 fast: 256-thread Ptile=192 / a-split=4 counted-vmcnt GEMM ======
// R12 post-mortem: 512-thread kernels are VGPR-capped at 128 in this
// toolchain (launch_bounds 2nd arg cannot lift it) -> 18.8MB spills.
// Only proven >128 config: 256-thread block, plain launch_bounds (R6: 228).
// Block (pt,ah,b): 128a x 192p, 4 waves; wave = 64a(aw=w&1) x 96p(pw=w>>1).
// acc[4][6]=96 + frags 40 ~ 170 VGPR. LDS 46KB -> 3 blocks/CU.
// 5 gl_lds/wave/step (2 A + 3 B, exact), vmcnt(5), 2-barrier loop.
// 4 a-quarters write alq[ah]; k_ctsm sums in fixed order (deterministic).
__global__ __launch_bounds__(256) void k_att3(
    const unsigned short* __restrict__ Apack,
    const unsigned short* __restrict__ Bpack, const float* __restrict__ G,
    const float* __restrict__ rb, const float* __restrict__ va,
    const float* __restrict__ apast, float* __restrict__ alq) {
    __shared__ __attribute__((aligned(16))) unsigned short lsA[2][4096];
    __shared__ __attribute__((aligned(16))) unsigned short lsB[2][6144];
    __shared__ float ap_s[18 * 50];
    __shared__ float part_s[4][96];
    int pt = blockIdx.x, ah = blockIdx.y, b = blockIdx.z;
    int t = threadIdx.x, w = t >> 6, lane = t & 63;
    int l15 = lane & 15, lg = lane >> 4;
    int aw = w & 1, pw = w >> 1;
    int sx = lg ^ ((l15 >> 1) & 3);  // swizzled k-slot (depends only on l15)

    for (int idx = t; idx < 900; idx += 256) {
        int hh = idx / 50, ww = idx % 50;
        float v = 0.f;
        if (hh >= 1 && hh <= HH_ && ww >= 1 && ww <= WW_)
            v = apast[b * HW_ + (hh - 1) * WW_ + (ww - 1)];
        ap_s[idx] = v;
    }
    __syncthreads();  // full drain before pipeline starts

    // A: step tile = Apack + s*16384 + ah*4096 (128a x 32k = 4096 shorts);
    // wave w stages 2x512-short chunks at w*1024 + i*512.
    const unsigned short* Ap0 = Apack + ah * 4096 + w * 1024 + lane * 8;
    // B: 3 old-64p chunks {pt*3+c}; 12 sub-chunks of 512 shorts per step;
    // wave w stages l = w*3+i, i<3 (exact, no duplicates).
    const unsigned short* Bp0[3];
    int ldst[3];
#pragma unroll
    for (int i = 0; i < 3; i++) {
        int l = w * 3 + i;
        int c = l >> 2, q = l & 3;
        Bp0[i] = Bpack + (long)(b * 12 + pt * 3 + c) * 22 * 2048 + q * 512 +
                 lane * 8;
        ldst[i] = l * 512;
    }

#define STAGE(S, BUF)                                                        \
    do {                                                                     \
        _Pragma("unroll") for (int i_ = 0; i_ < 2; i_++)                     \
            gl_lds16<0>(Ap0 + (long)(S)*16384 + i_ * 512,                    \
                        &lsA[BUF][w * 1024 + i_ * 512]);                     \
        _Pragma("unroll") for (int i_ = 0; i_ < 3; i_++)                     \
            gl_lds16<2>(Bp0[i_] + (long)(S)*2048, &lsB[BUF][ldst[i_]]);      \
    } while (0)

#define STEP_BODY(CUR)                                                       \
    do {                                                                     \
        bf16x8 af[4], bf[6];                                                 \
        _Pragma("unroll") for (int i = 0; i < 4; i++)                        \
            af[i] = *(const bf16x8*)&lsA[CUR][(aw * 64 + i * 16 + l15) * 32 +\
                                             sx * 8];                        \
        _Pragma("unroll") for (int j = 0; j < 6; j++)                        \
            bf[j] = *(const bf16x8*)&lsB[CUR][(pw * 96 + j * 16 + l15) * 32 +\
                                             sx * 8];                        \
        _Pragma("unroll") for (int i = 0; i < 4; i++)                        \
            _Pragma("unroll") for (int j = 0; j < 6; j++)                    \
                acc[i][j] = __builtin_amdgcn_mfma_f32_16x16x32_bf16(         \
                    af[i], bf[j], acc[i][j], 0, 0, 0);                       \
    } while (0)

    f32x4 acc[4][6];
#pragma unroll
    for (int i = 0; i < 4; i++)
#pragma unroll
        for (int j = 0; j < 6; j++) acc[i][j] = {0.f, 0.f, 0.f, 0.f};

    STAGE(0, 0);
    STAGE(1, 1);

    for (int s = 0; s < NS - 1; s++) {
        int cur = s & 1;
        asm volatile("s_waitcnt vmcnt(5)" ::: "memory");
        __builtin_amdgcn_sched_barrier(0);
        __builtin_amdgcn_s_barrier();   // step-s stages visible to all waves
        __builtin_amdgcn_sched_barrier(0);
        STEP_BODY(cur);
        __builtin_amdgcn_s_barrier();   // buf cur fully consumed
        __builtin_amdgcn_sched_barrier(0);
        if (s + 2 < NS) STAGE(s + 2, cur);
    }
    asm volatile("s_waitcnt vmcnt(0)" ::: "memory");
    __builtin_amdgcn_sched_barrier(0);
    __builtin_amdgcn_s_barrier();
    __builtin_amdgcn_sched_barrier(0);
    STEP_BODY((NS - 1) & 1);
#undef STAGE
#undef STEP_BODY

    // epilogue: + rowbias + 9-tap coverage, tanh, dot with va, reduce over a
    float partial[6] = {0.f, 0.f, 0.f, 0.f, 0.f, 0.f};
#pragma unroll
    for (int i = 0; i < 4; i++) {
#pragma unroll
        for (int r = 0; r < 4; r++) {
            int a = ah * 128 + aw * 64 + i * 16 + lg * 4 + r;
            float rbv = rb[b * DA + a];
            float vav = va[a];
            const float* Ga = G + a * 9;
            float g0 = Ga[0], g1 = Ga[1], g2 = Ga[2], g3 = Ga[3], g4 = Ga[4];
            float g5 = Ga[5], g6 = Ga[6], g7 = Ga[7], g8 = Ga[8];
#pragma unroll
            for (int j = 0; j < 6; j++) {
                int p = pt * 192 + pw * 96 + j * 16 + l15;
                int hh = p / WW_, ww = p % WW_;
                const float* ap = ap_s + hh * 50 + ww;
                float cov = g0 * ap[0] + g1 * ap[1] + g2 * ap[2] +
                            g3 * ap[50] + g4 * ap[51] + g5 * ap[52] +
                            g6 * ap[100] + g7 * ap[101] + g8 * ap[102];
                float e = tanhf(acc[i][j][r] + rbv + cov);
                partial[j] += vav * e;
            }
        }
    }
#pragma unroll
    for (int j = 0; j < 6; j++) {
        partial[j] += __shfl_xor(partial[j], 16);
        partial[j] += __shfl_xor(partial[j], 32);
    }
    if (lane < 16) {
#pragma unroll
        for (int j = 0; j < 6; j++) part_s[w][j * 16 + lane] = partial[j];
    }
    __syncthreads();
    if (t < 192) {
        int pg = t / 96, pl = t % 96;
        float sum = part_s[2 * pg][pl] + part_s[2 * pg + 1][pl];
        alq[ah * 49152 + b * HW_ + pt * 192 + t] = sum;
    }
}

// ======= K2 fallback: LDS-staging version (Apack slot-swizzle aware) =======
#define LDW 40
__global__ __launch_bounds__(256) void k_att_lds(
    const unsigned short* __restrict__ Apack, const float* __restrict__ ctx,
    const float* __restrict__ G, const float* __restrict__ rb,
    const float* __restrict__ va, const float* __restrict__ apast,
    float* __restrict__ alogit) {
    __shared__ __attribute__((aligned(16))) short lsB[2][64 * LDW];
    __shared__ float ap_s[18 * 50];
    __shared__ float part_s[4 * 64];
    int b = blockIdx.y;
    int p0 = blockIdx.x * 64;
    int t = threadIdx.x;
    int w = t >> 6, lane = t & 63;
    int l15 = lane & 15, lg = lane >> 4;
    int sxA = lg ^ ((l15 >> 1) & 3);
    int pq = t & 15, kp = t >> 4;
    const float* ctx_b = ctx + (long)b * DC * HW_ + p0;

    for (int idx = t; idx < 900; idx += 256) {
        int hh = idx / 50, ww = idx % 50;
        float v = 0.f;
        if (hh >= 1 && hh <= HH_ && ww >= 1 && ww <= WW_)
            v = apast[b * HW_ + (hh - 1) * WW_ + (ww - 1)];
        ap_s[idx] = v;
    }

#define CTXLOAD(FA, FB, S)                                                   \
    do {                                                                     \
        int d_ = (S) * 32 + 2 * kp;                                          \
        const float* s0_ = ctx_b + (long)d_ * HW_ + pq;                      \
        bool g0_ = d_ < DC, g1_ = (d_ + 1) < DC;                             \
        _Pragma("unroll") for (int j_ = 0; j_ < 4; j_++) {                   \
            FA[j_] = g0_ ? s0_[16 * j_] : 0.f;                               \
            FB[j_] = g1_ ? s0_[HW_ + 16 * j_] : 0.f;                         \
        }                                                                    \
    } while (0)
#define STAGEW(FA, FB, BUF)                                                  \
    do {                                                                     \
        _Pragma("unroll") for (int j_ = 0; j_ < 4; j_++) {                   \
            ((unsigned*)lsB[BUF])[(pq + 16 * j_) * (LDW / 2) + kp] =         \
                (unsigned)f2b(FA[j_]) | ((unsigned)f2b(FB[j_]) << 16);       \
        }                                                                    \
    } while (0)
#define ALOAD(AF, S)                                                         \
    do {                                                                     \
        _Pragma("unroll") for (int i_ = 0; i_ < 8; i_++)                     \
            AF[i_] = *(const bf16x8*)(Apack +                                \
                ((long)((S)*512 + w * 128 + i_ * 16 + l15) * 4 + sxA) * 8);  \
    } while (0)
#define BREAD(BF, BUF)                                                       \
    do {                                                                     \
        _Pragma("unroll") for (int j_ = 0; j_ < 4; j_++)                     \
            BF[j_] = *(const bf16x8*)(&lsB[BUF][(j_ * 16 + l15) * LDW +      \
                                               lg * 8]);                     \
    } while (0)
#define MFMA8x4(AF, BF)                                                      \
    do {                                                                     \
        _Pragma("unroll") for (int i_ = 0; i_ < 8; i_++)                     \
            _Pragma("unroll") for (int j_ = 0; j_ < 4; j_++)                 \
                acc[i_][j_] = __builtin_amdgcn_mfma_f32_16x16x32_bf16(       \
                    AF[i_], BF[j_], acc[i_][j_], 0, 0, 0);                   \
    } while (0)

    f32x4 acc[8][4];
#pragma unroll
    for (int i = 0; i < 8; i++)
#pragma unroll
        for (int j = 0; j < 4; j++) acc[i][j] = {0.f, 0.f, 0.f, 0.f};

    float fa0[4], fb0[4], fa1[4], fb1[4];
    bf16x8 afr0[8], afr1[8], bfr[4];

    CTXLOAD(fa1, fb1, 0);
    ALOAD(afr0, 0);
    STAGEW(fa1, fb1, 0);
    CTXLOAD(fa1, fb1, 1);
    __syncthreads();

    for (int ss = 0; ss < NS; ss += 2) {
        if (ss + 2 < NS) CTXLOAD(fa0, fb0, ss + 2);
        ALOAD(afr1, ss + 1);
        BREAD(bfr, 0);
        STAGEW(fa1, fb1, 1);
        MFMA8x4(afr0, bfr);
        __syncthreads();
        if (ss + 3 < NS) CTXLOAD(fa1, fb1, ss + 3);
        if (ss + 2 < NS) {
            ALOAD(afr0, ss + 2);
            BREAD(bfr, 1);
            STAGEW(fa0, fb0, 0);
            MFMA8x4(afr1, bfr);
        } else {
            BREAD(bfr, 1);
            MFMA8x4(afr1, bfr);
        }
        __syncthreads();
    }

    float partial[4] = {0.f, 0.f, 0.f, 0.f};
#pragma unroll
    for (int i = 0; i < 8; i++) {
#pragma unroll
        for (int r = 0; r < 4; r++) {
            int a = w * 128 + i * 16 + lg * 4 + r;
            float rbv = rb[b * DA + a];
            float vav = va[a];
            const float* Ga = G + a * 9;
            float g0 = Ga[0], g1 = Ga[1], g2 = Ga[2], g3 = Ga[3], g4 = Ga[4];
            float g5 = Ga[5], g6 = Ga[6], g7 = Ga[7], g8 = Ga[8];
#pragma unroll
            for (int j = 0; j < 4; j++) {
                int p = p0 + j * 16 + l15;
                int hh = p / WW_, ww = p % WW_;
                const float* ap = ap_s + hh * 50 + ww;
                float cov = g0 * ap[0] + g1 * ap[1] + g2 * ap[2] +
                            g3 * ap[50] + g4 * ap[51] + g5 * ap[52] +
                            g6 * ap[100] + g7 * ap[101] + g8 * ap[102];
                float e = tanhf(acc[i][j][r] + rbv + cov);
                partial[j] += vav * e;
            }
        }
    }
#pragma unroll
    for (int j = 0; j < 4; j++) {
        partial[j] += __shfl_xor(partial[j], 16);
        partial[j] += __shfl_xor(partial[j], 32);
    }
    if (lane < 16) {
#pragma unroll
        for (int j = 0; j < 4; j++) part_s[w * 64 + j * 16 + lane] = partial[j];
    }
    __syncthreads();
    if (t < 64) {
        float s = part_s[t] + part_s[64 + t] + part_s[128 + t] +
                  part_s[192 + t];
        alogit[b * HW_ + p0 + t] = s;
    }
}

// ---------------- K3+K4 fused: (sum quarters) + softmax + ct ---------------
__global__ __launch_bounds__(256) void k_ctsm(const float* __restrict__ ctx,
                                              const float* __restrict__ alq,
                                              float* __restrict__ ct,
                                              float* __restrict__ alpha_out) {
    __shared__ float al_s[HW_];
    __shared__ float red[16];
    int b = blockIdx.y, t = threadIdx.x;
    float v[3];
    float mx = -1e30f;
    for (int i = 0; i < 3; i++) {
        int idx = b * HW_ + i * 256 + t;
        v[i] = (alq[idx] + alq[49152 + idx]) +
               (alq[98304 + idx] + alq[147456 + idx]);
        mx = fmaxf(mx, v[i]);
    }
    for (int off = 32; off > 0; off >>= 1) mx = fmaxf(mx, __shfl_down(mx, off));
    if ((t & 63) == 0) red[t >> 6] = mx;
    __syncthreads();
    if (t == 0) red[0] = fmaxf(fmaxf(red[0], red[1]), fmaxf(red[2], red[3]));
    __syncthreads();
    mx = red[0];
    float sum = 0.f;
    for (int i = 0; i < 3; i++) {
        v[i] = expf(v[i] - mx);
        sum += v[i];
    }
    for (int off = 32; off > 0; off >>= 1) sum += __shfl_down(sum, off);
    if ((t & 63) == 0) red[8 + (t >> 6)] = sum;
    __syncthreads();
    if (t == 0) red[8] = red[8] + red[9] + red[10] + red[11];
    __syncthreads();
    float inv = 1.f / red[8];
    for (int i = 0; i < 3; i++) {
        float a = v[i] * inv;
        al_s[i * 256 + t] = a;
        if (blockIdx.x == 0) alpha_out[b * HW_ + i * 256 + t] = a;
    }
    __syncthreads();
    int dc0 = blockIdx.x * 114;
    int wave = t >> 6, lane = t & 63;
    for (int d = dc0 + wave; d < dc0 + 114; d += 4) {
        const float* row = &ctx[((long)b * DC + d) * HW_];
        float s = 0.f;
#pragma unroll
        for (int q = 0; q < 12; q++) s += row[lane + q * 64] * al_s[lane + q * 64];
        for (int off = 32; off > 0; off >>= 1) s += __shfl_down(s, off);
        if (lane == 0) ct[b * DC + d] = s;
    }
}

// ---------------- K5: logit rows -------------------------------------------
__global__ __launch_bounds__(256) void k_logit(
    const float* __restrict__ ctv, const float* __restrict__ s,
    const float* __restrict__ embedded, const float* __restrict__ Wct,
    const float* __restrict__ Wht, const float* __restrict__ Wct_b,
    const float* __restrict__ Wht_b, float* __restrict__ lg) {
    __shared__ float Xs[64 * 257];
    __shared__ float Ws[4 * 232];
    int t = threadIdx.x, w = t >> 6, lane = t & 63;
    int r = blockIdx.x * 4 + w;
    float acc = 0.f;
    for (int c = 0; c < 3; c++) {
        int c0 = c * 228;
        __syncthreads();
        for (int i = t; i < 64 * 228; i += 256) {
            int bb = i / 228, kk = i - bb * 228;
            Xs[bb * 229 + kk] = ctv[bb * DC + c0 + kk];
        }
        for (int j = lane; j < 228; j += 64) Ws[w * 232 + j] = Wct[r * DC + c0 + j];
        __syncthreads();
        const float* xrow = Xs + lane * 229;
        const float* wrow = Ws + w * 232;
#pragma unroll 4
        for (int k = 0; k < 228; k++) acc += wrow[k] * xrow[k];
    }
    __syncthreads();
    for (int i = t; i < 64 * 256; i += 256) {
        int bb = i >> 8, k = i & 255;
        Xs[bb * 257 + k] = s[bb * 256 + k];
    }
    __syncthreads();
    const float* xrow2 = Xs + lane * 257;
    const float* wr = Wht + r * 256;
    float acc2 = 0.f;
#pragma unroll 8
    for (int k = 0; k < 256; k++) acc2 += wr[k] * xrow2[k];
    lg[lane * 256 + r] = acc + acc2 + Wct_b[r] + Wht_b[r] + embedded[lane * 256 + r];
}

// ---------------- K6: maxout + W0 head -------------------------------------
__global__ __launch_bounds__(256) void k_head(const float* __restrict__ lg,
                                              const float* __restrict__ W0,
                                              const float* __restrict__ W0_b,
                                              float* __restrict__ out) {
    __shared__ float Xs[64 * 129];
    __shared__ float Ws[4 * 132];
    int t = threadIdx.x, w = t >> 6, lane = t & 63;
    for (int i = t; i < 64 * 128; i += 256) {
        int bb = i >> 7, m = i & 127;
        Xs[bb * 129 + m] = fmaxf(lg[bb * 256 + 2 * m], lg[bb * 256 + 2 * m + 1]);
    }
    int r = blockIdx.x * 4 + w;
    Ws[w * 132 + lane] = W0[r * 128 + lane];
    Ws[w * 132 + 64 + lane] = W0[r * 128 + 64 + lane];
    __syncthreads();
    const float* xrow = Xs + lane * 129;
    const float* wrow = Ws + w * 132;
    float acc = 0.f;
#pragma unroll 8
    for (int k = 0; k < 128; k++) acc += wrow[k] * xrow[k];
    out[lane * KV + r] = acc + W0_b[r];
}

extern "C" void kernel_launch(void* const* d_in, const int* in_sizes, int n_in,
                              void* d_out, int out_size, void* d_ws,
                              size_t ws_size, hipStream_t stream) {
    const int* y = (const int*)d_in[0];
    const float* y_mask = (const float*)d_in[1];
    const float* context = (const float*)d_in[2];
    const float* pre_hidden = (const float*)d_in[3];
    const float* alpha_past = (const float*)d_in[4];
    const float* emb = (const float*)d_in[5];
    const float* W_ih1 = (const float*)d_in[6];
    const float* W_hh1 = (const float*)d_in[7];
    const float* b_ih1 = (const float*)d_in[8];
    const float* b_hh1 = (const float*)d_in[9];
    const float* conv_Ua_w = (const float*)d_in[10];
    const float* conv_Ua_b = (const float*)d_in[11];
    const float* Wa = (const float*)d_in[12];
    const float* conv_Q_w = (const float*)d_in[13];
    const float* Uf = (const float*)d_in[14];
    const float* Uf_b = (const float*)d_in[15];
    const float* va = (const float*)d_in[16];
    const float* va_b = (const float*)d_in[17];
    const float* W_ih2 = (const float*)d_in[18];
    const float* W_hh2 = (const float*)d_in[19];
    const float* b_ih2 = (const float*)d_in[20];
    const float* b_hh2 = (const float*)d_in[21];
    const float* Wct = (const float*)d_in[22];
    const float* Wct_b = (const float*)d_in[23];
    const float* Wht = (const float*)d_in[24];
    const float* Wht_b = (const float*)d_in[25];
    const float* W0 = (const float*)d_in[26];
    const float* W0_b = (const float*)d_in[27];

    float* ws = (float*)d_ws;
    float* out = (float*)d_out;
    float* G = ws + WS_G;
    float* rbias = ws + WS_RB;
    float* embedded = ws + WS_EMB;
    float* s_hat = ws + WS_SH;
    float* ctv = ws + WS_CT;
    unsigned short* Apack = (unsigned short*)(ws + WS_APACK);
    float* gi = ws + WS_GI;
    float* gh = ws + WS_GH;
    float* lg = ws + WS_LG;
    unsigned short* Bpack = (unsigned short*)(ws + WS_BP);
    float* alq = ws + WS_ALQ;
    float* s_out = out + 8192;
    float* alpha_out = out + 24576;

    bool fast = ws_size >= NEED_BYTES;

    if (fast) {
        k_prep<<<dim3(929), dim3(512), 0, stream>>>(context, conv_Ua_w, Uf,
                                                    conv_Q_w, y, emb, Bpack,
                                                    Apack, G, embedded);
    } else {
        k_G<<<dim3(18), dim3(256), 0, stream>>>(Uf, conv_Q_w, G);
        k_prepA<<<dim3((NS * DA * 32 + 255) / 256), dim3(256), 0, stream>>>(
            conv_Ua_w, Apack);
        k_emb<<<dim3(64), dim3(256), 0, stream>>>(y, emb, embedded);
    }
    k_gih1<<<dim3(384), dim3(256), 0, stream>>>(embedded, pre_hidden, W_ih1,
                                                W_hh1, b_ih1, b_hh1, gi, gh);
    k_gru<<<dim3(64), dim3(256), 0, stream>>>(gi, gh, pre_hidden, y_mask, s_hat);
    k_rows256<<<dim3(128), dim3(256), 0, stream>>>(s_hat, Wa, conv_Ua_b, Uf_b,
                                                   rbias, 512);
    if (fast) {
        k_att3<<<dim3(4, 4, 64), dim3(256), 0, stream>>>(
            Apack, Bpack, G, rbias, va, alpha_past, alq);
    } else {
        // fallback: write quarter 0, zero quarters 1-3
        hipMemsetAsync(alq + 49152, 0, (size_t)3 * 49152 * sizeof(float),
                       stream);
        k_att_lds<<<dim3(12, 64), dim3(256), 0, stream>>>(
            Apack, context, G, rbias, va, alpha_past, alq);
    }
    k_ctsm<<<dim3(6, 64), dim3(256), 0, stream>>>(context, alq, ctv, alpha_out);
    k_gih2<<<dim3(384), dim3(256), 0, stream>>>(ctv, s_hat, W_ih2, W_hh2, b_ih2,
                                                b_hh2, gi, gh);
    k_gru<<<dim3(64), dim3(256), 0, stream>>>(gi, gh, s_hat, y_mask, s_out);
    k_logit<<<dim3(64), dim3(256), 0, stream>>>(ctv, s_out, embedded, Wct, Wht,
                                                Wct_b, Wht_b, lg);
    k_head<<<dim3(32), dim3(256), 0, stream>>>(lg, W0, W0_b, out);
}

// Round 14
// 299.914 us; speedup vs baseline: 1.0150x; 1.0150x over previous
//
#include <hip/hip_runtime.h>
#include <hip/hip_bf16.h>
#include <math.h>

#define BB 64
#define KV 128
#define ME 256
#define NH 256
#define DC 684
#define DA 512
#define MC 256
#define HH_ 16
#define WW_ 48
#define HW_ 768
#define NS 22   // K-steps of 32 (684 -> 704 padded)

typedef __attribute__((ext_vector_type(8))) short bf16x8;
typedef __attribute__((ext_vector_type(4))) float f32x4;

// workspace layout (floats)
#define WS_G     0                    // 512*9
#define WS_RB    (WS_G + 4608)        // rowbias 64*512
#define WS_EMB   (WS_RB + 32768)      // 64*256
#define WS_SH    (WS_EMB + 16384)     // 64*256 s_hat
#define WS_AL    (WS_SH + 16384)      // 64*768 alpha logits (fallback)
#define WS_CT    (WS_AL + 49152)      // 64*684 ct
#define WS_APACK (WS_CT + 43776)      // 22*512*32 bf16 = 180224 floats
#define WS_GI    (WS_APACK + 180224)  // 64*768
#define WS_GH    (WS_GI + 49152)      // 64*768
#define WS_LG    WS_GI                // logit 64*256 reuses GI after gru2
#define WS_BP    (WS_GH + 49152)      // = 441600; Bpack 64*12*22*2048 bf16
#define WS_ALQ   (WS_BP + 17301504)   // 2 x 64*768 alpha-logit halves
#define NEED_BYTES ((size_t)(441600 + 17301504 + 98304) * 4)

static __device__ __forceinline__ unsigned short f2b(float v) {
    __hip_bfloat16 h = __float2bfloat16(v);
    return *reinterpret_cast<unsigned short*>(&h);
}

// async global->LDS, 16B per lane. LDS base must be wave-uniform; HW adds
// lane*16. Global address is per-lane.
static __device__ __forceinline__ void gl_lds16(const unsigned short* g,
                                                unsigned short* l) {
    __builtin_amdgcn_global_load_lds(
        (const __attribute__((address_space(1))) unsigned int*)g,
        (__attribute__((address_space(3))) unsigned int*)l, 16, 0, 0);
}

// =================== fused prep ============================================
__global__ __launch_bounds__(512) void k_prep(
    const float* __restrict__ ctx, const float* __restrict__ Ua,
    const float* __restrict__ Uf, const float* __restrict__ convQ,
    const int* __restrict__ y, const float* __restrict__ emb,
    unsigned short* __restrict__ Bpack, unsigned short* __restrict__ Apack,
    float* __restrict__ G, float* __restrict__ embedded) {
    __shared__ unsigned short Ts[64 * 360];  // 45 KB
    int bx = blockIdx.x, t = threadIdx.x;
    if (bx < 768) {
        int b = bx / 12, pt = bx % 12, p0 = pt * 64;
        int w = t >> 6, p = t & 63;  // 8 waves, lane = p
        unsigned short* dst = Bpack + (long)(b * 12 + pt) * 22 * 2048;
        for (int ch = 0; ch < 2; ch++) {
            int dbase = ch * 352;
            if (ch) __syncthreads();
#pragma unroll
            for (int iter = 0; iter < 11; iter++) {
                int d0 = dbase + iter * 32 + w * 4;
                float v0 = 0.f, v1 = 0.f, v2 = 0.f, v3 = 0.f;
                const float* src = ctx + ((long)b * DC + d0) * HW_ + p0 + p;
                if (d0 + 0 < DC) v0 = src[0];
                if (d0 + 1 < DC) v1 = src[HW_];
                if (d0 + 2 < DC) v2 = src[2 * HW_];
                if (d0 + 3 < DC) v3 = src[3 * HW_];
                unsigned u01 = (unsigned)f2b(v0) | ((unsigned)f2b(v1) << 16);
                unsigned u23 = (unsigned)f2b(v2) | ((unsigned)f2b(v3) << 16);
                *(uint2*)&Ts[p * 360 + (d0 - dbase)] = make_uint2(u01, u23);
            }
            __syncthreads();
            int so = t >> 8;
            int tt = t & 255;
            int pp = tt >> 2, slot = tt & 3;
#pragma unroll
            for (int s2 = 0; s2 < 12; s2 += 2) {
                int sl = s2 + so;
                if (sl < 11) {
                    int s = ch * 11 + sl;
                    bf16x8 v = *(const bf16x8*)&Ts[pp * 360 + sl * 32 +
                                                   ((slot ^ ((pp >> 1) & 3))
                                                    << 3)];
                    *(bf16x8*)(dst + (long)(s * 256 + tt) * 8) = v;
                }
            }
        }
    } else if (bx < 856) {
        int bi = bx - 768;
#pragma unroll
        for (int r = 0; r < 8; r++) {
            int idx = bi * 4096 + r * 512 + t;
            int e = idx & 7, slot = (idx >> 3) & 3;
            int a = (idx >> 5) & 511, s = idx >> 14;
            int d = s * 32 + ((slot ^ ((a >> 1) & 3)) << 3) + e;
            float v = (d < DC) ? Ua[a * DC + d] : 0.f;
            Apack[idx] = f2b(v);
        }
    } else if (bx < 865) {
        int idx = (bx - 856) * 512 + t;
        if (idx < DA * 9) {
            int a = idx / 9, k = idx % 9;
            float s = 0.f;
            for (int m = 0; m < MC; m++) s += Uf[a * MC + m] * convQ[m * 9 + k];
            G[idx] = s;
        }
    } else {
        int b = bx - 865;
        if (t < ME) embedded[b * ME + t] = emb[y[b] * ME + t];
    }
}

// =================== fallback-path prep kernels ============================
__global__ __launch_bounds__(256) void k_G(const float* __restrict__ Uf,
                                           const float* __restrict__ convQ,
                                           float* __restrict__ G) {
    int idx = blockIdx.x * 256 + threadIdx.x;
    if (idx >= DA * 9) return;
    int a = idx / 9, k = idx % 9;
    float s = 0.f;
    for (int m = 0; m < MC; m++) s += Uf[a * MC + m] * convQ[m * 9 + k];
    G[idx] = s;
}

__global__ __launch_bounds__(256) void k_prepA(const float* __restrict__ Ua,
                                               unsigned short* __restrict__ Apack) {
    int idx = blockIdx.x * 256 + threadIdx.x;
    if (idx >= NS * DA * 32) return;
    int e = idx & 7, slot = (idx >> 3) & 3;
    int a = (idx >> 5) & 511, s = idx >> 14;
    int d = s * 32 + ((slot ^ ((a >> 1) & 3)) << 3) + e;
    float v = (d < DC) ? Ua[a * DC + d] : 0.f;
    Apack[idx] = f2b(v);
}

__global__ __launch_bounds__(256) void k_emb(const int* __restrict__ y,
                                             const float* __restrict__ emb,
                                             float* __restrict__ embedded) {
    int b = blockIdx.x, t = threadIdx.x;
    embedded[b * ME + t] = emb[y[b] * ME + t];
}

// ------- generic rows-of-W kernel, K=256 -----------------------------------
__global__ __launch_bounds__(256) void k_rows256(
    const float* __restrict__ X, const float* __restrict__ W,
    const float* __restrict__ bias, const float* __restrict__ bias2,
    float* __restrict__ out, int outStride) {
    __shared__ float Xs[64 * 257];
    __shared__ float Ws[4 * 260];
    int t = threadIdx.x, w = t >> 6, lane = t & 63;
    for (int i = t; i < 64 * 256; i += 256) {
        int bb = i >> 8, k = i & 255;
        Xs[bb * 257 + k] = X[bb * 256 + k];
    }
    int r = blockIdx.x * 4 + w;
    *(f32x4*)(Ws + w * 260 + lane * 4) = *(const f32x4*)(W + r * 256 + lane * 4);
    __syncthreads();
    const float* xrow = Xs + lane * 257;
    const float* wrow = Ws + w * 260;
    float acc = 0.f;
#pragma unroll 8
    for (int k = 0; k < 256; k++) acc += wrow[k] * xrow[k];
    acc += bias[r];
    if (bias2) acc += bias2[r];
    out[lane * outStride + r] = acc;
}

// ------- fused GRU1 gate GEMVs ---------------------------------------------
__global__ __launch_bounds__(256) void k_gih1(
    const float* __restrict__ embedded, const float* __restrict__ pre_hidden,
    const float* __restrict__ W_ih1, const float* __restrict__ W_hh1,
    const float* __restrict__ b_ih1, const float* __restrict__ b_hh1,
    float* __restrict__ gi, float* __restrict__ gh) {
    __shared__ float Xs[64 * 257];
    __shared__ float Ws[4 * 260];
    int bx = blockIdx.x, t = threadIdx.x, w = t >> 6, lane = t & 63;
    const float *X, *W, *bias;
    float* outp;
    int r;
    if (bx < 192) {
        X = embedded; W = W_ih1; bias = b_ih1; outp = gi; r = bx * 4 + w;
    } else {
        X = pre_hidden; W = W_hh1; bias = b_hh1; outp = gh; r = (bx - 192) * 4 + w;
    }
    for (int i = t; i < 64 * 256; i += 256) {
        int bb = i >> 8, k = i & 255;
        Xs[bb * 257 + k] = X[bb * 256 + k];
    }
    *(f32x4*)(Ws + w * 260 + lane * 4) = *(const f32x4*)(W + r * 256 + lane * 4);
    __syncthreads();
    const float* xrow = Xs + lane * 257;
    const float* wrow = Ws + w * 260;
    float acc = 0.f;
#pragma unroll 8
    for (int k = 0; k < 256; k++) acc += wrow[k] * xrow[k];
    outp[lane * 768 + r] = acc + bias[r];
}

// ------- fused GRU2 gate GEMVs ---------------------------------------------
__global__ __launch_bounds__(256) void k_gih2(
    const float* __restrict__ ctv, const float* __restrict__ s_hat,
    const float* __restrict__ W_ih2, const float* __restrict__ W_hh2,
    const float* __restrict__ b_ih2, const float* __restrict__ b_hh2,
    float* __restrict__ gi, float* __restrict__ gh) {
    __shared__ float Xs[64 * 257];
    __shared__ float Ws[4 * 260];
    int bx = blockIdx.x, t = threadIdx.x, w = t >> 6, lane = t & 63;
    if (bx < 192) {
        int r = bx * 4 + w;
        float acc = 0.f;
        for (int c = 0; c < 3; c++) {
            int c0 = c * 228;
            __syncthreads();
            for (int i = t; i < 64 * 228; i += 256) {
                int bb = i / 228, kk = i - bb * 228;
                Xs[bb * 229 + kk] = ctv[bb * DC + c0 + kk];
            }
            for (int j = lane; j < 228; j += 64)
                Ws[w * 260 + j] = W_ih2[r * DC + c0 + j];
            __syncthreads();
            const float* xrow = Xs + lane * 229;
            const float* wrow = Ws + w * 260;
#pragma unroll 4
            for (int k = 0; k < 228; k++) acc += wrow[k] * xrow[k];
        }
        gi[lane * 768 + r] = acc + b_ih2[r];
    } else {
        int r = (bx - 192) * 4 + w;
        for (int i = t; i < 64 * 256; i += 256) {
            int bb = i >> 8, k = i & 255;
            Xs[bb * 257 + k] = s_hat[bb * 256 + k];
        }
        *(f32x4*)(Ws + w * 260 + lane * 4) =
            *(const f32x4*)(W_hh2 + r * 256 + lane * 4);
        __syncthreads();
        const float* xrow = Xs + lane * 257;
        const float* wrow = Ws + w * 260;
        float acc = 0.f;
#pragma unroll 8
        for (int k = 0; k < 256; k++) acc += wrow[k] * xrow[k];
        gh[lane * 768 + r] = acc + b_hh2[r];
    }
}

// ---------------- GRU elementwise ------------------------------------------
__global__ __launch_bounds__(256) void k_gru(const float* __restrict__ gi,
                                             const float* __restrict__ gh,
                                             const float* __restrict__ h,
                                             const float* __restrict__ y_mask,
                                             float* __restrict__ outp) {
    int b = blockIdx.x, t = threadIdx.x;
    float hv = h[b * NH + t];
    float r = 1.f / (1.f + expf(-(gi[b * 768 + t] + gh[b * 768 + t])));
    float z = 1.f / (1.f + expf(-(gi[b * 768 + 256 + t] + gh[b * 768 + 256 + t])));
    float n = tanhf(gi[b * 768 + 512 + t] + r * gh[b * 768 + 512 + t]);
    float sv = (1.f - z) * n + z * hv;
    float m = y_mask[b];
    outp[b * NH + t] = m * sv + (1.f - m) * hv;
}

// ======= K2 fast: 256-thread Ptile=64 / a-split=2, 3 blocks/CU =============
// R13 post-mortem: binding constraint is per-step memory latency at ~1
// block/CU (nothing co-resident to hide the vmcnt stall). Re-cut for
// 3 blocks/CU: block = 256a x 64p, 4 waves (wave = 64a x 64p, acc[4][4]=64,
// ~150 VGPR <= 168 -> 3 waves/SIMD); LDS 46KB (<53KB). 5 gl_lds/wave/step
// (4 A + 1 B, exact), vmcnt(5), counted 2-barrier loop. No NT (B reused
// by 2 ah-blocks -> keep L2-cacheable). Grid (12 pt, 2 ah, 64 b) = 1536.
__global__ __launch_bounds__(256) void k_att3(
    const unsigned short* __restrict__ Apack,
    const unsigned short* __restrict__ Bpack, const float* __restrict__ G,
    const float* __restrict__ rb, const float* __restrict__ va,
    const float* __restrict__ apast, float* __restrict__ alq) {
    __shared__ __attribute__((aligned(16))) unsigned short lsA[2][8192];
    __shared__ __attribute__((aligned(16))) unsigned short lsB[2][2048];
    __shared__ float ap_s[18 * 50];
    __shared__ float part_s[4][64];
    int pt = blockIdx.x, ah = blockIdx.y, b = blockIdx.z;
    int t = threadIdx.x, w = t >> 6, lane = t & 63;
    int l15 = lane & 15, lg = lane >> 4;
    int sx = lg ^ ((l15 >> 1) & 3);  // swizzled k-slot for ds_read

    for (int idx = t; idx < 900; idx += 256) {
        int hh = idx / 50, ww = idx % 50;
        float v = 0.f;
        if (hh >= 1 && hh <= HH_ && ww >= 1 && ww <= WW_)
            v = apast[b * HW_ + (hh - 1) * WW_ + (ww - 1)];
        ap_s[idx] = v;
    }
    __syncthreads();  // full drain before pipeline starts

    // A: step tile = Apack + s*16384 + ah*8192 (256a x 32k = 8192 shorts,
    // linear); wave w stages 4x512-short chunks at w*2048 + i*512.
    const unsigned short* Ap0 = Apack + ah * 8192 + w * 2048 + lane * 8;
    // B: step chunk = Bpack[(b*12+pt)] + s*2048 (2048 shorts); wave w
    // stages quarter w (512 shorts).
    const unsigned short* Bp0 =
        Bpack + (long)(b * 12 + pt) * 22 * 2048 + w * 512 + lane * 8;

#define STAGE(S, BUF)                                                        \
    do {                                                                     \
        _Pragma("unroll") for (int i_ = 0; i_ < 4; i_++)                     \
            gl_lds16(Ap0 + (long)(S)*16384 + i_ * 512,                       \
                     &lsA[BUF][w * 2048 + i_ * 512]);                        \
        gl_lds16(Bp0 + (long)(S)*2048, &lsB[BUF][w * 512]);                  \
    } while (0)

#define STEP_BODY(CUR)                                                       \
    do {                                                                     \
        bf16x8 af[4], bf[4];                                                 \
        _Pragma("unroll") for (int i = 0; i < 4; i++)                        \
            af[i] = *(const bf16x8*)&lsA[CUR][(w * 64 + i * 16 + l15) * 32 + \
                                             sx * 8];                        \
        _Pragma("unroll") for (int j = 0; j < 4; j++)                        \
            bf[j] = *(const bf16x8*)&lsB[CUR][(j * 16 + l15) * 32 + sx * 8]; \
        _Pragma("unroll") for (int i = 0; i < 4; i++)                        \
            _Pragma("unroll") for (int j = 0; j < 4; j++)                    \
                acc[i][j] = __builtin_amdgcn_mfma_f32_16x16x32_bf16(         \
                    af[i], bf[j], acc[i][j], 0, 0, 0);                       \
    } while (0)

    f32x4 acc[4][4];
#pragma unroll
    for (int i = 0; i < 4; i++)
#pragma unroll
        for (int j = 0; j < 4; j++) acc[i][j] = {0.f, 0.f, 0.f, 0.f};

    STAGE(0, 0);
    STAGE(1, 1);

    for (int s = 0; s < NS - 1; s++) {
        int cur = s & 1;
        asm volatile("s_waitcnt vmcnt(5)" ::: "memory");
        __builtin_amdgcn_sched_barrier(0);
        __builtin_amdgcn_s_barrier();   // step-s stages visible to all waves
        __builtin_amdgcn_sched_barrier(0);
        STEP_BODY(cur);
        __builtin_amdgcn_s_barrier();   // buf cur fully consumed
        __builtin_amdgcn_sched_barrier(0);
        if (s + 2 < NS) STAGE(s + 2, cur);
    }
    asm volatile("s_waitcnt vmcnt(0)" ::: "memory");
    __builtin_amdgcn_sched_barrier(0);
    __builtin_amdgcn_s_barrier();
    __builtin_amdgcn_sched_barrier(0);
    STEP_BODY((NS - 1) & 1);
#undef STAGE
#undef STEP_BODY

    // epilogue: + rowbias + 9-tap coverage, tanh, dot with va, reduce over a
    float partial[4] = {0.f, 0.f, 0.f, 0.f};
#pragma unroll
    for (int i = 0; i < 4; i++) {
#pragma unroll
        for (int r = 0; r < 4; r++) {
            int a = ah * 256 + w * 64 + i * 16 + lg * 4 + r;
            float rbv = rb[b * DA + a];
            float vav = va[a];
            const float* Ga = G + a * 9;
            float g0 = Ga[0], g1 = Ga[1], g2 = Ga[2], g3 = Ga[3], g4 = Ga[4];
            float g5 = Ga[5], g6 = Ga[6], g7 = Ga[7], g8 = Ga[8];
#pragma unroll
            for (int j = 0; j < 4; j++) {
                int p = pt * 64 + j * 16 + l15;
                int hh = p / WW_, ww = p % WW_;
                const float* ap = ap_s + hh * 50 + ww;
                float cov = g0 * ap[0] + g1 * ap[1] + g2 * ap[2] +
                            g3 * ap[50] + g4 * ap[51] + g5 * ap[52] +
                            g6 * ap[100] + g7 * ap[101] + g8 * ap[102];
                float e = tanhf(acc[i][j][r] + rbv + cov);
                partial[j] += vav * e;
            }
        }
    }
#pragma unroll
    for (int j = 0; j < 4; j++) {
        partial[j] += __shfl_xor(partial[j], 16);
        partial[j] += __shfl_xor(partial[j], 32);
    }
    if (lane < 16) {
#pragma unroll
        for (int j = 0; j < 4; j++) part_s[w][j * 16 + lane] = partial[j];
    }
    __syncthreads();
    if (t < 64) {
        float sum = (part_s[0][t] + part_s[1][t]) +
                    (part_s[2][t] + part_s[3][t]);
        alq[ah * 49152 + b * HW_ + pt * 64 + t] = sum;
    }
}

// ======= K2 fallback: LDS-staging version (Apack slot-swizzle aware) =======
#define LDW 40
__global__ __launch_bounds__(256) void k_att_lds(
    const unsigned short* __restrict__ Apack, const float* __restrict__ ctx,
    const float* __restrict__ G, const float* __restrict__ rb,
    const float* __restrict__ va, const float* __restrict__ apast,
    float* __restrict__ alogit) {
    __shared__ __attribute__((aligned(16))) short lsB[2][64 * LDW];
    __shared__ float ap_s[18 * 50];
    __shared__ float part_s[4 * 64];
    int b = blockIdx.y;
    int p0 = blockIdx.x * 64;
    int t = threadIdx.x;
    int w = t >> 6, lane = t & 63;
    int l15 = lane & 15, lg = lane >> 4;
    int sxA = lg ^ ((l15 >> 1) & 3);
    int pq = t & 15, kp = t >> 4;
    const float* ctx_b = ctx + (long)b * DC * HW_ + p0;

    for (int idx = t; idx < 900; idx += 256) {
        int hh = idx / 50, ww = idx % 50;
        float v = 0.f;
        if (hh >= 1 && hh <= HH_ && ww >= 1 && ww <= WW_)
            v = apast[b * HW_ + (hh - 1) * WW_ + (ww - 1)];
        ap_s[idx] = v;
    }

#define CTXLOAD(FA, FB, S)                                                   \
    do {                                                                     \
        int d_ = (S) * 32 + 2 * kp;                                          \
        const float* s0_ = ctx_b + (long)d_ * HW_ + pq;                      \
        bool g0_ = d_ < DC, g1_ = (d_ + 1) < DC;                             \
        _Pragma("unroll") for (int j_ = 0; j_ < 4; j_++) {                   \
            FA[j_] = g0_ ? s0_[16 * j_] : 0.f;                               \
            FB[j_] = g1_ ? s0_[HW_ + 16 * j_] : 0.f;                         \
        }                                                                    \
    } while (0)
#define STAGEW(FA, FB, BUF)                                                  \
    do {                                                                     \
        _Pragma("unroll") for (int j_ = 0; j_ < 4; j_++) {                   \
            ((unsigned*)lsB[BUF])[(pq + 16 * j_) * (LDW / 2) + kp] =         \
                (unsigned)f2b(FA[j_]) | ((unsigned)f2b(FB[j_]) << 16);       \
        }                                                                    \
    } while (0)
#define ALOAD(AF, S)                                                         \
    do {                                                                     \
        _Pragma("unroll") for (int i_ = 0; i_ < 8; i_++)                     \
            AF[i_] = *(const bf16x8*)(Apack +                                \
                ((long)((S)*512 + w * 128 + i_ * 16 + l15) * 4 + sxA) * 8);  \
    } while (0)
#define BREAD(BF, BUF)                                                       \
    do {                                                                     \
        _Pragma("unroll") for (int j_ = 0; j_ < 4; j_++)                     \
            BF[j_] = *(const bf16x8*)(&lsB[BUF][(j_ * 16 + l15) * LDW +      \
                                               lg * 8]);                     \
    } while (0)
#define MFMA8x4(AF, BF)                                                      \
    do {                                                                     \
        _Pragma("unroll") for (int i_ = 0; i_ < 8; i_++)                     \
            _Pragma("unroll") for (int j_ = 0; j_ < 4; j_++)                 \
                acc[i_][j_] = __builtin_amdgcn_mfma_f32_16x16x32_bf16(       \
                    AF[i_], BF[j_], acc[i_][j_], 0, 0, 0);                   \
    } while (0)

    f32x4 acc[8][4];
#pragma unroll
    for (int i = 0; i < 8; i++)
#pragma unroll
        for (int j = 0; j < 4; j++) acc[i][j] = {0.f, 0.f, 0.f, 0.f};

    float fa0[4], fb0[4], fa1[4], fb1[4];
    bf16x8 afr0[8], afr1[8], bfr[4];

    CTXLOAD(fa1, fb1, 0);
    ALOAD(afr0, 0);
    STAGEW(fa1, fb1, 0);
    CTXLOAD(fa1, fb1, 1);
    __syncthreads();

    for (int ss = 0; ss < NS; ss += 2) {
        if (ss + 2 < NS) CTXLOAD(fa0, fb0, ss + 2);
        ALOAD(afr1, ss + 1);
        BREAD(bfr, 0);
        STAGEW(fa1, fb1, 1);
        MFMA8x4(afr0, bfr);
        __syncthreads();
        if (ss + 3 < NS) CTXLOAD(fa1, fb1, ss + 3);
        if (ss + 2 < NS) {
            ALOAD(afr0, ss + 2);
            BREAD(bfr, 1);
            STAGEW(fa0, fb0, 0);
            MFMA8x4(afr1, bfr);
        } else {
            BREAD(bfr, 1);
            MFMA8x4(afr1, bfr);
        }
        __syncthreads();
    }

    float partial[4] = {0.f, 0.f, 0.f, 0.f};
#pragma unroll
    for (int i = 0; i < 8; i++) {
#pragma unroll
        for (int r = 0; r < 4; r++) {
            int a = w * 128 + i * 16 + lg * 4 + r;
            float rbv = rb[b * DA + a];
            float vav = va[a];
            const float* Ga = G + a * 9;
            float g0 = Ga[0], g1 = Ga[1], g2 = Ga[2], g3 = Ga[3], g4 = Ga[4];
            float g5 = Ga[5], g6 = Ga[6], g7 = Ga[7], g8 = Ga[8];
#pragma unroll
            for (int j = 0; j < 4; j++) {
                int p = p0 + j * 16 + l15;
                int hh = p / WW_, ww = p % WW_;
                const float* ap = ap_s + hh * 50 + ww;
                float cov = g0 * ap[0] + g1 * ap[1] + g2 * ap[2] +
                            g3 * ap[50] + g4 * ap[51] + g5 * ap[52] +
                            g6 * ap[100] + g7 * ap[101] + g8 * ap[102];
                float e = tanhf(acc[i][j][r] + rbv + cov);
                partial[j] += vav * e;
            }
        }
    }
#pragma unroll
    for (int j = 0; j < 4; j++) {
        partial[j] += __shfl_xor(partial[j], 16);
        partial[j] += __shfl_xor(partial[j], 32);
    }
    if (lane < 16) {
#pragma unroll
        for (int j = 0; j < 4; j++) part_s[w * 64 + j * 16 + lane] = partial[j];
    }
    __syncthreads();
    if (t < 64) {
        float s = part_s[t] + part_s[64 + t] + part_s[128 + t] +
                  part_s[192 + t];
        alogit[b * HW_ + p0 + t] = s;
    }
}

// ---------------- K3+K4 fused: (sum halves) + softmax + ct -----------------
__global__ __launch_bounds__(256) void k_ctsm(const float* __restrict__ ctx,
                                              const float* __restrict__ alq,
                                              float* __restrict__ ct,
                                              float* __restrict__ alpha_out) {
    __shared__ float al_s[HW_];
    __shared__ float red[16];
    int b = blockIdx.y, t = threadIdx.x;
    float v[3];
    float mx = -1e30f;
    for (int i = 0; i < 3; i++) {
        int idx = b * HW_ + i * 256 + t;
        v[i] = alq[idx] + alq[49152 + idx];
        mx = fmaxf(mx, v[i]);
    }
    for (int off = 32; off > 0; off >>= 1) mx = fmaxf(mx, __shfl_down(mx, off));
    if ((t & 63) == 0) red[t >> 6] = mx;
    __syncthreads();
    if (t == 0) red[0] = fmaxf(fmaxf(red[0], red[1]), fmaxf(red[2], red[3]));
    __syncthreads();
    mx = red[0];
    float sum = 0.f;
    for (int i = 0; i < 3; i++) {
        v[i] = expf(v[i] - mx);
        sum += v[i];
    }
    for (int off = 32; off > 0; off >>= 1) sum += __shfl_down(sum, off);
    if ((t & 63) == 0) red[8 + (t >> 6)] = sum;
    __syncthreads();
    if (t == 0) red[8] = red[8] + red[9] + red[10] + red[11];
    __syncthreads();
    float inv = 1.f / red[8];
    for (int i = 0; i < 3; i++) {
        float a = v[i] * inv;
        al_s[i * 256 + t] = a;
        if (blockIdx.x == 0) alpha_out[b * HW_ + i * 256 + t] = a;
    }
    __syncthreads();
    int dc0 = blockIdx.x * 114;
    int wave = t >> 6, lane = t & 63;
    for (int d = dc0 + wave; d < dc0 + 114; d += 4) {
        const float* row = &ctx[((long)b * DC + d) * HW_];
        float s = 0.f;
#pragma unroll
        for (int q = 0; q < 12; q++) s += row[lane + q * 64] * al_s[lane + q * 64];
        for (int off = 32; off > 0; off >>= 1) s += __shfl_down(s, off);
        if (lane == 0) ct[b * DC + d] = s;
    }
}

// ---------------- K5: logit rows -------------------------------------------
__global__ __launch_bounds__(256) void k_logit(
    const float* __restrict__ ctv, const float* __restrict__ s,
    const float* __restrict__ embedded, const float* __restrict__ Wct,
    const float* __restrict__ Wht, const float* __restrict__ Wct_b,
    const float* __restrict__ Wht_b, float* __restrict__ lg) {
    __shared__ float Xs[64 * 257];
    __shared__ float Ws[4 * 232];
    int t = threadIdx.x, w = t >> 6, lane = t & 63;
    int r = blockIdx.x * 4 + w;
    float acc = 0.f;
    for (int c = 0; c < 3; c++) {
        int c0 = c * 228;
        __syncthreads();
        for (int i = t; i < 64 * 228; i += 256) {
            int bb = i / 228, kk = i - bb * 228;
            Xs[bb * 229 + kk] = ctv[bb * DC + c0 + kk];
        }
        for (int j = lane; j < 228; j += 64) Ws[w * 232 + j] = Wct[r * DC + c0 + j];
        __syncthreads();
        const float* xrow = Xs + lane * 229;
        const float* wrow = Ws + w * 232;
#pragma unroll 4
        for (int k = 0; k < 228; k++) acc += wrow[k] * xrow[k];
    }
    __syncthreads();
    for (int i = t; i < 64 * 256; i += 256) {
        int bb = i >> 8, k = i & 255;
        Xs[bb * 257 + k] = s[bb * 256 + k];
    }
    __syncthreads();
    const float* xrow2 = Xs + lane * 257;
    const float* wr = Wht + r * 256;
    float acc2 = 0.f;
#pragma unroll 8
    for (int k = 0; k < 256; k++) acc2 += wr[k] * xrow2[k];
    lg[lane * 256 + r] = acc + acc2 + Wct_b[r] + Wht_b[r] + embedded[lane * 256 + r];
}

// ---------------- K6: maxout + W0 head -------------------------------------
__global__ __launch_bounds__(256) void k_head(const float* __restrict__ lg,
                                              const float* __restrict__ W0,
                                              const float* __restrict__ W0_b,
                                              float* __restrict__ out) {
    __shared__ float Xs[64 * 129];
    __shared__ float Ws[4 * 132];
    int t = threadIdx.x, w = t >> 6, lane = t & 63;
    for (int i = t; i < 64 * 128; i += 256) {
        int bb = i >> 7, m = i & 127;
        Xs[bb * 129 + m] = fmaxf(lg[bb * 256 + 2 * m], lg[bb * 256 + 2 * m + 1]);
    }
    int r = blockIdx.x * 4 + w;
    Ws[w * 132 + lane] = W0[r * 128 + lane];
    Ws[w * 132 + 64 + lane] = W0[r * 128 + 64 + lane];
    __syncthreads();
    const float* xrow = Xs + lane * 129;
    const float* wrow = Ws + w * 132;
    float acc = 0.f;
#pragma unroll 8
    for (int k = 0; k < 128; k++) acc += wrow[k] * xrow[k];
    out[lane * KV + r] = acc + W0_b[r];
}

extern "C" void kernel_launch(void* const* d_in, const int* in_sizes, int n_in,
                              void* d_out, int out_size, void* d_ws,
                              size_t ws_size, hipStream_t stream) {
    const int* y = (const int*)d_in[0];
    const float* y_mask = (const float*)d_in[1];
    const float* context = (const float*)d_in[2];
    const float* pre_hidden = (const float*)d_in[3];
    const float* alpha_past = (const float*)d_in[4];
    const float* emb = (const float*)d_in[5];
    const float* W_ih1 = (const float*)d_in[6];
    const float* W_hh1 = (const float*)d_in[7];
    const float* b_ih1 = (const float*)d_in[8];
    const float* b_hh1 = (const float*)d_in[9];
    const float* conv_Ua_w = (const float*)d_in[10];
    const float* conv_Ua_b = (const float*)d_in[11];
    const float* Wa = (const float*)d_in[12];
    const float* conv_Q_w = (const float*)d_in[13];
    const float* Uf = (const float*)d_in[14];
    const float* Uf_b = (const float*)d_in[15];
    const float* va = (const float*)d_in[16];
    const float* va_b = (const float*)d_in[17];
    const float* W_ih2 = (const float*)d_in[18];
    const float* W_hh2 = (const float*)d_in[19];
    const float* b_ih2 = (const float*)d_in[20];
    const float* b_hh2 = (const float*)d_in[21];
    const float* Wct = (const float*)d_in[22];
    const float* Wct_b = (const float*)d_in[23];
    const float* Wht = (const float*)d_in[24];
    const float* Wht_b = (const float*)d_in[25];
    const float* W0 = (const float*)d_in[26];
    const float* W0_b = (const float*)d_in[27];

    float* ws = (float*)d_ws;
    float* out = (float*)d_out;
    float* G = ws + WS_G;
    float* rbias = ws + WS_RB;
    float* embedded = ws + WS_EMB;
    float* s_hat = ws + WS_SH;
    float* ctv = ws + WS_CT;
    unsigned short* Apack = (unsigned short*)(ws + WS_APACK);
    float* gi = ws + WS_GI;
    float* gh = ws + WS_GH;
    float* lg = ws + WS_LG;
    unsigned short* Bpack = (unsigned short*)(ws + WS_BP);
    float* alq = ws + WS_ALQ;
    float* s_out = out + 8192;
    float* alpha_out = out + 24576;

    bool fast = ws_size >= NEED_BYTES;

    if (fast) {
        k_prep<<<dim3(929), dim3(512), 0, stream>>>(context, conv_Ua_w, Uf,
                                                    conv_Q_w, y, emb, Bpack,
                                                    Apack, G, embedded);
    } else {
        k_G<<<dim3(18), dim3(256), 0, stream>>>(Uf, conv_Q_w, G);
        k_prepA<<<dim3((NS * DA * 32 + 255) / 256), dim3(256), 0, stream>>>(
            conv_Ua_w, Apack);
        k_emb<<<dim3(64), dim3(256), 0, stream>>>(y, emb, embedded);
    }
    k_gih1<<<dim3(384), dim3(256), 0, stream>>>(embedded, pre_hidden, W_ih1,
                                                W_hh1, b_ih1, b_hh1, gi, gh);
    k_gru<<<dim3(64), dim3(256), 0, stream>>>(gi, gh, pre_hidden, y_mask, s_hat);
    k_rows256<<<dim3(128), dim3(256), 0, stream>>>(s_hat, Wa, conv_Ua_b, Uf_b,
                                                   rbias, 512);
    if (fast) {
        k_att3<<<dim3(12, 2, 64), dim3(256), 0, stream>>>(
            Apack, Bpack, G, rbias, va, alpha_past, alq);
    } else {
        // fallback: write half 0, zero half 1
        hipMemsetAsync(alq + 49152, 0, (size_t)49152 * sizeof(float), stream);
        k_att_lds<<<dim3(12, 64), dim3(256), 0, stream>>>(
            Apack, context, G, rbias, va, alpha_past, alq);
    }
    k_ctsm<<<dim3(6, 64), dim3(256), 0, stream>>>(context, alq, ctv, alpha_out);
    k_gih2<<<dim3(384), dim3(256), 0, stream>>>(ctv, s_hat, W_ih2, W_hh2, b_ih2,
                                                b_hh2, gi, gh);
    k_gru<<<dim3(64), dim3(256), 0, stream>>>(gi, gh, s_hat, y_mask, s_out);
    k_logit<<<dim3(64), dim3(256), 0, stream>>>(ctv, s_out, embedded, Wct, Wht,
                                                Wct_b, Wht_b, lg);
    k_head<<<dim3(32), dim3(256), 0, stream>>>(lg, W0, W0_b, out);
}

// Round 15
// 239.703 us; speedup vs baseline: 1.2700x; 1.2512x over previous
//
#include <hip/hip_runtime.h>
#include <hip/hip_bf16.h>
#include <math.h>

#define BB 64
#define KV 128
#define ME 256
#define NH 256
#define DC 684
#define DA 512
#define MC 256
#define HH_ 16
#define WW_ 48
#define HW_ 768
#define NS 22   // K-steps of 32 (684 -> 704 padded)

typedef __attribute__((ext_vector_type(8))) short bf16x8;
typedef __attribute__((ext_vector_type(4))) float f32x4;

// workspace layout (floats)
#define WS_G     0                    // 512*9
#define WS_RB    (WS_G + 4608)        // rowbias 64*512
#define WS_EMB   (WS_RB + 32768)      // 64*256
#define WS_SH    (WS_EMB + 16384)     // 64*256 s_hat
#define WS_AL    (WS_SH + 16384)      // 64*768 alpha logits (fallback)
#define WS_CT    (WS_AL + 49152)      // 64*684 ct
#define WS_APACK (WS_CT + 43776)      // 22*512*32 bf16 = 180224 floats
#define WS_GI    (WS_APACK + 180224)  // 64*768
#define WS_GH    (WS_GI + 49152)      // 64*768
#define WS_LG    WS_GI                // logit 64*256 reuses GI after gru2
#define WS_BP    (WS_GH + 49152)      // = 441600; Bpack 64*12*22*2048 bf16
#define WS_ALQ   (WS_BP + 17301504)   // 2 x 64*768 alpha-logit halves
#define NEED_BYTES ((size_t)(441600 + 17301504 + 98304) * 4)

static __device__ __forceinline__ unsigned short f2b(float v) {
    __hip_bfloat16 h = __float2bfloat16(v);
    return *reinterpret_cast<unsigned short*>(&h);
}

// async global->LDS, 16B per lane. LDS base must be wave-uniform; HW adds
// lane*16. Global address is per-lane.
static __device__ __forceinline__ void gl_lds16(const unsigned short* g,
                                                unsigned short* l) {
    __builtin_amdgcn_global_load_lds(
        (const __attribute__((address_space(1))) unsigned int*)g,
        (__attribute__((address_space(3))) unsigned int*)l, 16, 0, 0);
}

// =================== fused prep ============================================
__global__ __launch_bounds__(512) void k_prep(
    const float* __restrict__ ctx, const float* __restrict__ Ua,
    const float* __restrict__ Uf, const float* __restrict__ convQ,
    const int* __restrict__ y, const float* __restrict__ emb,
    unsigned short* __restrict__ Bpack, unsigned short* __restrict__ Apack,
    float* __restrict__ G, float* __restrict__ embedded) {
    __shared__ unsigned short Ts[64 * 360];  // 45 KB
    int bx = blockIdx.x, t = threadIdx.x;
    if (bx < 768) {
        int b = bx / 12, pt = bx % 12, p0 = pt * 64;
        int w = t >> 6, p = t & 63;  // 8 waves, lane = p
        unsigned short* dst = Bpack + (long)(b * 12 + pt) * 22 * 2048;
        for (int ch = 0; ch < 2; ch++) {
            int dbase = ch * 352;
            if (ch) __syncthreads();
#pragma unroll
            for (int iter = 0; iter < 11; iter++) {
                int d0 = dbase + iter * 32 + w * 4;
                float v0 = 0.f, v1 = 0.f, v2 = 0.f, v3 = 0.f;
                const float* src = ctx + ((long)b * DC + d0) * HW_ + p0 + p;
                if (d0 + 0 < DC) v0 = src[0];
                if (d0 + 1 < DC) v1 = src[HW_];
                if (d0 + 2 < DC) v2 = src[2 * HW_];
                if (d0 + 3 < DC) v3 = src[3 * HW_];
                unsigned u01 = (unsigned)f2b(v0) | ((unsigned)f2b(v1) << 16);
                unsigned u23 = (unsigned)f2b(v2) | ((unsigned)f2b(v3) << 16);
                *(uint2*)&Ts[p * 360 + (d0 - dbase)] = make_uint2(u01, u23);
            }
            __syncthreads();
            int so = t >> 8;
            int tt = t & 255;
            int pp = tt >> 2, slot = tt & 3;
#pragma unroll
            for (int s2 = 0; s2 < 12; s2 += 2) {
                int sl = s2 + so;
                if (sl < 11) {
                    int s = ch * 11 + sl;
                    bf16x8 v = *(const bf16x8*)&Ts[pp * 360 + sl * 32 +
                                                   ((slot ^ ((pp >> 1) & 3))
                                                    << 3)];
                    *(bf16x8*)(dst + (long)(s * 256 + tt) * 8) = v;
                }
            }
        }
    } else if (bx < 856) {
        int bi = bx - 768;
#pragma unroll
        for (int r = 0; r < 8; r++) {
            int idx = bi * 4096 + r * 512 + t;
            int e = idx & 7, slot = (idx >> 3) & 3;
            int a = (idx >> 5) & 511, s = idx >> 14;
            int d = s * 32 + ((slot ^ ((a >> 1) & 3)) << 3) + e;
            float v = (d < DC) ? Ua[a * DC + d] : 0.f;
            Apack[idx] = f2b(v);
        }
    } else if (bx < 865) {
        int idx = (bx - 856) * 512 + t;
        if (idx < DA * 9) {
            int a = idx / 9, k = idx % 9;
            float s = 0.f;
            for (int m = 0; m < MC; m++) s += Uf[a * MC + m] * convQ[m * 9 + k];
            G[idx] = s;
        }
    } else {
        int b = bx - 865;
        if (t < ME) embedded[b * ME + t] = emb[y[b] * ME + t];
    }
}

// =================== fallback-path prep kernels ============================
__global__ __launch_bounds__(256) void k_G(const float* __restrict__ Uf,
                                           const float* __restrict__ convQ,
                                           float* __restrict__ G) {
    int idx = blockIdx.x * 256 + threadIdx.x;
    if (idx >= DA * 9) return;
    int a = idx / 9, k = idx % 9;
    float s = 0.f;
    for (int m = 0; m < MC; m++) s += Uf[a * MC + m] * convQ[m * 9 + k];
    G[idx] = s;
}

__global__ __launch_bounds__(256) void k_prepA(const float* __restrict__ Ua,
                                               unsigned short* __restrict__ Apack) {
    int idx = blockIdx.x * 256 + threadIdx.x;
    if (idx >= NS * DA * 32) return;
    int e = idx & 7, slot = (idx >> 3) & 3;
    int a = (idx >> 5) & 511, s = idx >> 14;
    int d = s * 32 + ((slot ^ ((a >> 1) & 3)) << 3) + e;
    float v = (d < DC) ? Ua[a * DC + d] : 0.f;
    Apack[idx] = f2b(v);
}

__global__ __launch_bounds__(256) void k_emb(const int* __restrict__ y,
                                             const float* __restrict__ emb,
                                             float* __restrict__ embedded) {
    int b = blockIdx.x, t = threadIdx.x;
    embedded[b * ME + t] = emb[y[b] * ME + t];
}

// ------- generic rows-of-W kernel, K=256 -----------------------------------
__global__ __launch_bounds__(256) void k_rows256(
    const float* __restrict__ X, const float* __restrict__ W,
    const float* __restrict__ bias, const float* __restrict__ bias2,
    float* __restrict__ out, int outStride) {
    __shared__ float Xs[64 * 257];
    __shared__ float Ws[4 * 260];
    int t = threadIdx.x, w = t >> 6, lane = t & 63;
    for (int i = t; i < 64 * 256; i += 256) {
        int bb = i >> 8, k = i & 255;
        Xs[bb * 257 + k] = X[bb * 256 + k];
    }
    int r = blockIdx.x * 4 + w;
    *(f32x4*)(Ws + w * 260 + lane * 4) = *(const f32x4*)(W + r * 256 + lane * 4);
    __syncthreads();
    const float* xrow = Xs + lane * 257;
    const float* wrow = Ws + w * 260;
    float acc = 0.f;
#pragma unroll 8
    for (int k = 0; k < 256; k++) acc += wrow[k] * xrow[k];
    acc += bias[r];
    if (bias2) acc += bias2[r];
    out[lane * outStride + r] = acc;
}

// ------- fused GRU1 gate GEMVs ---------------------------------------------
__global__ __launch_bounds__(256) void k_gih1(
    const float* __restrict__ embedded, const float* __restrict__ pre_hidden,
    const float* __restrict__ W_ih1, const float* __restrict__ W_hh1,
    const float* __restrict__ b_ih1, const float* __restrict__ b_hh1,
    float* __restrict__ gi, float* __restrict__ gh) {
    __shared__ float Xs[64 * 257];
    __shared__ float Ws[4 * 260];
    int bx = blockIdx.x, t = threadIdx.x, w = t >> 6, lane = t & 63;
    const float *X, *W, *bias;
    float* outp;
    int r;
    if (bx < 192) {
        X = embedded; W = W_ih1; bias = b_ih1; outp = gi; r = bx * 4 + w;
    } else {
        X = pre_hidden; W = W_hh1; bias = b_hh1; outp = gh; r = (bx - 192) * 4 + w;
    }
    for (int i = t; i < 64 * 256; i += 256) {
        int bb = i >> 8, k = i & 255;
        Xs[bb * 257 + k] = X[bb * 256 + k];
    }
    *(f32x4*)(Ws + w * 260 + lane * 4) = *(const f32x4*)(W + r * 256 + lane * 4);
    __syncthreads();
    const float* xrow = Xs + lane * 257;
    const float* wrow = Ws + w * 260;
    float acc = 0.f;
#pragma unroll 8
    for (int k = 0; k < 256; k++) acc += wrow[k] * xrow[k];
    outp[lane * 768 + r] = acc + bias[r];
}

// ------- fused GRU2 gate GEMVs ---------------------------------------------
__global__ __launch_bounds__(256) void k_gih2(
    const float* __restrict__ ctv, const float* __restrict__ s_hat,
    const float* __restrict__ W_ih2, const float* __restrict__ W_hh2,
    const float* __restrict__ b_ih2, const float* __restrict__ b_hh2,
    float* __restrict__ gi, float* __restrict__ gh) {
    __shared__ float Xs[64 * 257];
    __shared__ float Ws[4 * 260];
    int bx = blockIdx.x, t = threadIdx.x, w = t >> 6, lane = t & 63;
    if (bx < 192) {
        int r = bx * 4 + w;
        float acc = 0.f;
        for (int c = 0; c < 3; c++) {
            int c0 = c * 228;
            __syncthreads();
            for (int i = t; i < 64 * 228; i += 256) {
                int bb = i / 228, kk = i - bb * 228;
                Xs[bb * 229 + kk] = ctv[bb * DC + c0 + kk];
            }
            for (int j = lane; j < 228; j += 64)
                Ws[w * 260 + j] = W_ih2[r * DC + c0 + j];
            __syncthreads();
            const float* xrow = Xs + lane * 229;
            const float* wrow = Ws + w * 260;
#pragma unroll 4
            for (int k = 0; k < 228; k++) acc += wrow[k] * xrow[k];
        }
        gi[lane * 768 + r] = acc + b_ih2[r];
    } else {
        int r = (bx - 192) * 4 + w;
        for (int i = t; i < 64 * 256; i += 256) {
            int bb = i >> 8, k = i & 255;
            Xs[bb * 257 + k] = s_hat[bb * 256 + k];
        }
        *(f32x4*)(Ws + w * 260 + lane * 4) =
            *(const f32x4*)(W_hh2 + r * 256 + lane * 4);
        __syncthreads();
        const float* xrow = Xs + lane * 257;
        const float* wrow = Ws + w * 260;
        float acc = 0.f;
#pragma unroll 8
        for (int k = 0; k < 256; k++) acc += wrow[k] * xrow[k];
        gh[lane * 768 + r] = acc + b_hh2[r];
    }
}

// ---------------- GRU elementwise ------------------------------------------
__global__ __launch_bounds__(256) void k_gru(const float* __restrict__ gi,
                                             const float* __restrict__ gh,
                                             const float* __restrict__ h,
                                             const float* __restrict__ y_mask,
                                             float* __restrict__ outp) {
    int b = blockIdx.x, t = threadIdx.x;
    float hv = h[b * NH + t];
    float r = 1.f / (1.f + expf(-(gi[b * 768 + t] + gh[b * 768 + t])));
    float z = 1.f / (1.f + expf(-(gi[b * 768 + 256 + t] + gh[b * 768 + 256 + t])));
    float n = tanhf(gi[b * 768 + 512 + t] + r * gh[b * 768 + 512 + t]);
    float sv = (1.f - z) * n + z * hv;
    float m = y_mask[b];
    outp[b * NH + t] = m * sv + (1.f - m) * hv;
}

// ======= K2 fast: R9 engine, 256a x 128p tiling (min staged bytes) =========
// R14 post-mortem: k_att is bound by total staged bytes over the L3/fabric
// (R9: 622MB at 6.0 TB/s = ceiling). Keep R9's exact execution shape (512
// thr, acc[4][4], ~100 VGPR < 128 cap, 5 gl_lds/wave/step, counted vmcnt,
// 2 blocks/CU) but cut staged bytes 2.3x: block = 256a x 128p, A-split 2.
// A-traffic 135MB + B 138MB = 273MB. Wave w: aw=w&3 (64a), pw=w>>2 (64p).
// B-chunk index c = pw exactly (pj = pw*64 + j*16 + l15, j<4). Grid (6,2,64).
__global__ __launch_bounds__(512) void k_att3(
    const unsigned short* __restrict__ Apack,
    const unsigned short* __restrict__ Bpack, const float* __restrict__ G,
    const float* __restrict__ rb, const float* __restrict__ va,
    const float* __restrict__ apast, float* __restrict__ alq) {
    __shared__ __attribute__((aligned(16))) unsigned short lsA[2][8192];
    __shared__ __attribute__((aligned(16))) unsigned short lsB[2][4096];
    __shared__ float ap_s[18 * 50];
    __shared__ float part_s[8][64];
    int pt2 = blockIdx.x, ah = blockIdx.y, b = blockIdx.z;
    int t = threadIdx.x, w = t >> 6, lane = t & 63;
    int l15 = lane & 15, lg = lane >> 4;
    int aw = w & 3, pw = w >> 2;
    int sx = lg ^ ((l15 >> 1) & 3);  // swizzled k-slot for ds_read

    for (int idx = t; idx < 900; idx += 512) {
        int hh = idx / 50, ww = idx % 50;
        float v = 0.f;
        if (hh >= 1 && hh <= HH_ && ww >= 1 && ww <= WW_)
            v = apast[b * HW_ + (hh - 1) * WW_ + (ww - 1)];
        ap_s[idx] = v;
    }
    __syncthreads();  // full drain before pipeline starts

    // A: step tile = Apack + s*16384 + ah*8192 (256a x 32k, linear);
    // wave w stages 4x512-short chunks at w*1024? no: 8192/8 waves = 1024
    // shorts... 8192 shorts / 8 waves = 1024 shorts = 2 gl_lds. Use 2 A +
    // re-check: 16KB/step A = 8192 shorts; per wave 1024 shorts = 2 loads.
    // B: 8KB/step = 4096 shorts; per wave 512 shorts = 1 load. => 3/wave?
    // Keep 5-load cadence of R9 NOT required; vmcnt must match: 3 loads.
    const unsigned short* Ap0 = Apack + ah * 8192 + w * 1024 + lane * 8;
    // B sub-chunk l = w&7 over 8 chunks of 512: c=w>>2, q=w&3
    const unsigned short* Bp0 =
        Bpack + (long)(b * 12 + pt2 * 2 + (w >> 2)) * 22 * 2048 +
        (w & 3) * 512 + lane * 8;

#define STAGE(S, BUF)                                                        \
    do {                                                                     \
        _Pragma("unroll") for (int i_ = 0; i_ < 2; i_++)                     \
            gl_lds16(Ap0 + (long)(S)*16384 + i_ * 512,                       \
                     &lsA[BUF][w * 1024 + i_ * 512]);                        \
        gl_lds16(Bp0 + (long)(S)*2048, &lsB[BUF][w * 512]);                  \
    } while (0)

#define STEP_BODY(CUR)                                                       \
    do {                                                                     \
        bf16x8 af[4], bf[4];                                                 \
        _Pragma("unroll") for (int i = 0; i < 4; i++)                        \
            af[i] = *(const bf16x8*)&lsA[CUR][(aw * 64 + i * 16 + l15) * 32 +\
                                             sx * 8];                        \
        _Pragma("unroll") for (int j = 0; j < 4; j++)                        \
            bf[j] = *(const bf16x8*)&lsB[CUR][pw * 2048 +                    \
                                             (j * 16 + l15) * 32 + sx * 8]; \
        _Pragma("unroll") for (int i = 0; i < 4; i++)                        \
            _Pragma("unroll") for (int j = 0; j < 4; j++)                    \
                acc[i][j] = __builtin_amdgcn_mfma_f32_16x16x32_bf16(         \
                    af[i], bf[j], acc[i][j], 0, 0, 0);                       \
    } while (0)

    f32x4 acc[4][4];
#pragma unroll
    for (int i = 0; i < 4; i++)
#pragma unroll
        for (int j = 0; j < 4; j++) acc[i][j] = {0.f, 0.f, 0.f, 0.f};

    STAGE(0, 0);
    STAGE(1, 1);

    for (int s = 0; s < NS - 1; s++) {
        int cur = s & 1;
        asm volatile("s_waitcnt vmcnt(3)" ::: "memory");
        __builtin_amdgcn_sched_barrier(0);
        __builtin_amdgcn_s_barrier();   // step-s stages visible to all waves
        __builtin_amdgcn_sched_barrier(0);
        STEP_BODY(cur);
        __builtin_amdgcn_s_barrier();   // buf cur fully consumed
        __builtin_amdgcn_sched_barrier(0);
        if (s + 2 < NS) STAGE(s + 2, cur);
    }
    asm volatile("s_waitcnt vmcnt(0)" ::: "memory");
    __builtin_amdgcn_sched_barrier(0);
    __builtin_amdgcn_s_barrier();
    __builtin_amdgcn_sched_barrier(0);
    STEP_BODY((NS - 1) & 1);
#undef STAGE
#undef STEP_BODY

    // epilogue: + rowbias + 9-tap coverage, tanh, dot with va, reduce over a
    float partial[4] = {0.f, 0.f, 0.f, 0.f};
#pragma unroll
    for (int i = 0; i < 4; i++) {
#pragma unroll
        for (int r = 0; r < 4; r++) {
            int a = ah * 256 + aw * 64 + i * 16 + lg * 4 + r;
            float rbv = rb[b * DA + a];
            float vav = va[a];
            const float* Ga = G + a * 9;
            float g0 = Ga[0], g1 = Ga[1], g2 = Ga[2], g3 = Ga[3], g4 = Ga[4];
            float g5 = Ga[5], g6 = Ga[6], g7 = Ga[7], g8 = Ga[8];
#pragma unroll
            for (int j = 0; j < 4; j++) {
                int p = pt2 * 128 + pw * 64 + j * 16 + l15;
                int hh = p / WW_, ww = p % WW_;
                const float* ap = ap_s + hh * 50 + ww;
                float cov = g0 * ap[0] + g1 * ap[1] + g2 * ap[2] +
                            g3 * ap[50] + g4 * ap[51] + g5 * ap[52] +
                            g6 * ap[100] + g7 * ap[101] + g8 * ap[102];
                float e = tanhf(acc[i][j][r] + rbv + cov);
                partial[j] += vav * e;
            }
        }
    }
#pragma unroll
    for (int j = 0; j < 4; j++) {
        partial[j] += __shfl_xor(partial[j], 16);
        partial[j] += __shfl_xor(partial[j], 32);
    }
    if (lane < 16) {
#pragma unroll
        for (int j = 0; j < 4; j++) part_s[w][j * 16 + lane] = partial[j];
    }
    __syncthreads();
    if (t < 128) {
        int pg = t >> 6, pl = t & 63;
        float sum = (part_s[pg * 4 + 0][pl] + part_s[pg * 4 + 1][pl]) +
                    (part_s[pg * 4 + 2][pl] + part_s[pg * 4 + 3][pl]);
        alq[ah * 49152 + b * HW_ + pt2 * 128 + t] = sum;
    }
}

// ======= K2 fallback: LDS-staging version (Apack slot-swizzle aware) =======
#define LDW 40
__global__ __launch_bounds__(256) void k_att_lds(
    const unsigned short* __restrict__ Apack, const float* __restrict__ ctx,
    const float* __restrict__ G, const float* __restrict__ rb,
    const float* __restrict__ va, const float* __restrict__ apast,
    float* __restrict__ alogit) {
    __shared__ __attribute__((aligned(16))) short lsB[2][64 * LDW];
    __shared__ float ap_s[18 * 50];
    __shared__ float part_s[4 * 64];
    int b = blockIdx.y;
    int p0 = blockIdx.x * 64;
    int t = threadIdx.x;
    int w = t >> 6, lane = t & 63;
    int l15 = lane & 15, lg = lane >> 4;
    int sxA = lg ^ ((l15 >> 1) & 3);
    int pq = t & 15, kp = t >> 4;
    const float* ctx_b = ctx + (long)b * DC * HW_ + p0;

    for (int idx = t; idx < 900; idx += 256) {
        int hh = idx / 50, ww = idx % 50;
        float v = 0.f;
        if (hh >= 1 && hh <= HH_ && ww >= 1 && ww <= WW_)
            v = apast[b * HW_ + (hh - 1) * WW_ + (ww - 1)];
        ap_s[idx] = v;
    }

#define CTXLOAD(FA, FB, S)                                                   \
    do {                                                                     \
        int d_ = (S) * 32 + 2 * kp;                                          \
        const float* s0_ = ctx_b + (long)d_ * HW_ + pq;                      \
        bool g0_ = d_ < DC, g1_ = (d_ + 1) < DC;                             \
        _Pragma("unroll") for (int j_ = 0; j_ < 4; j_++) {                   \
            FA[j_] = g0_ ? s0_[16 * j_] : 0.f;                               \
            FB[j_] = g1_ ? s0_[HW_ + 16 * j_] : 0.f;                         \
        }                                                                    \
    } while (0)
#define STAGEW(FA, FB, BUF)                                                  \
    do {                                                                     \
        _Pragma("unroll") for (int j_ = 0; j_ < 4; j_++) {                   \
            ((unsigned*)lsB[BUF])[(pq + 16 * j_) * (LDW / 2) + kp] =         \
                (unsigned)f2b(FA[j_]) | ((unsigned)f2b(FB[j_]) << 16);       \
        }                                                                    \
    } while (0)
#define ALOAD(AF, S)                                                         \
    do {                                                                     \
        _Pragma("unroll") for (int i_ = 0; i_ < 8; i_++)                     \
            AF[i_] = *(const bf16x8*)(Apack +                                \
                ((long)((S)*512 + w * 128 + i_ * 16 + l15) * 4 + sxA) * 8);  \
    } while (0)
#define BREAD(BF, BUF)                                                       \
    do {                                                                     \
        _Pragma("unroll") for (int j_ = 0; j_ < 4; j_++)                     \
            BF[j_] = *(const bf16x8*)(&lsB[BUF][(j_ * 16 + l15) * LDW +      \
                                               lg * 8]);                     \
    } while (0)
#define MFMA8x4(AF, BF)                                                      \
    do {                                                                     \
        _Pragma("unroll") for (int i_ = 0; i_ < 8; i_++)                     \
            _Pragma("unroll") for (int j_ = 0; j_ < 4; j_++)                 \
                acc[i_][j_] = __builtin_amdgcn_mfma_f32_16x16x32_bf16(       \
                    AF[i_], BF[j_], acc[i_][j_], 0, 0, 0);                   \
    } while (0)

    f32x4 acc[8][4];
#pragma unroll
    for (int i = 0; i < 8; i++)
#pragma unroll
        for (int j = 0; j < 4; j++) acc[i][j] = {0.f, 0.f, 0.f, 0.f};

    float fa0[4], fb0[4], fa1[4], fb1[4];
    bf16x8 afr0[8], afr1[8], bfr[4];

    CTXLOAD(fa1, fb1, 0);
    ALOAD(afr0, 0);
    STAGEW(fa1, fb1, 0);
    CTXLOAD(fa1, fb1, 1);
    __syncthreads();

    for (int ss = 0; ss < NS; ss += 2) {
        if (ss + 2 < NS) CTXLOAD(fa0, fb0, ss + 2);
        ALOAD(afr1, ss + 1);
        BREAD(bfr, 0);
        STAGEW(fa1, fb1, 1);
        MFMA8x4(afr0, bfr);
        __syncthreads();
        if (ss + 3 < NS) CTXLOAD(fa1, fb1, ss + 3);
        if (ss + 2 < NS) {
            ALOAD(afr0, ss + 2);
            BREAD(bfr, 1);
            STAGEW(fa0, fb0, 0);
            MFMA8x4(afr1, bfr);
        } else {
            BREAD(bfr, 1);
            MFMA8x4(afr1, bfr);
        }
        __syncthreads();
    }

    float partial[4] = {0.f, 0.f, 0.f, 0.f};
#pragma unroll
    for (int i = 0; i < 8; i++) {
#pragma unroll
        for (int r = 0; r < 4; r++) {
            int a = w * 128 + i * 16 + lg * 4 + r;
            float rbv = rb[b * DA + a];
            float vav = va[a];
            const float* Ga = G + a * 9;
            float g0 = Ga[0], g1 = Ga[1], g2 = Ga[2], g3 = Ga[3], g4 = Ga[4];
            float g5 = Ga[5], g6 = Ga[6], g7 = Ga[7], g8 = Ga[8];
#pragma unroll
            for (int j = 0; j < 4; j++) {
                int p = p0 + j * 16 + l15;
                int hh = p / WW_, ww = p % WW_;
                const float* ap = ap_s + hh * 50 + ww;
                float cov = g0 * ap[0] + g1 * ap[1] + g2 * ap[2] +
                            g3 * ap[50] + g4 * ap[51] + g5 * ap[52] +
                            g6 * ap[100] + g7 * ap[101] + g8 * ap[102];
                float e = tanhf(acc[i][j][r] + rbv + cov);
                partial[j] += vav * e;
            }
        }
    }
#pragma unroll
    for (int j = 0; j < 4; j++) {
        partial[j] += __shfl_xor(partial[j], 16);
        partial[j] += __shfl_xor(partial[j], 32);
    }
    if (lane < 16) {
#pragma unroll
        for (int j = 0; j < 4; j++) part_s[w * 64 + j * 16 + lane] = partial[j];
    }
    __syncthreads();
    if (t < 64) {
        float s = part_s[t] + part_s[64 + t] + part_s[128 + t] +
                  part_s[192 + t];
        alogit[b * HW_ + p0 + t] = s;
    }
}

// ---------------- K3+K4 fused: (sum halves) + softmax + ct -----------------
__global__ __launch_bounds__(256) void k_ctsm(const float* __restrict__ ctx,
                                              const float* __restrict__ alq,
                                              float* __restrict__ ct,
                                              float* __restrict__ alpha_out) {
    __shared__ float al_s[HW_];
    __shared__ float red[16];
    int b = blockIdx.y, t = threadIdx.x;
    float v[3];
    float mx = -1e30f;
    for (int i = 0; i < 3; i++) {
        int idx = b * HW_ + i * 256 + t;
        v[i] = alq[idx] + alq[49152 + idx];
        mx = fmaxf(mx, v[i]);
    }
    for (int off = 32; off > 0; off >>= 1) mx = fmaxf(mx, __shfl_down(mx, off));
    if ((t & 63) == 0) red[t >> 6] = mx;
    __syncthreads();
    if (t == 0) red[0] = fmaxf(fmaxf(red[0], red[1]), fmaxf(red[2], red[3]));
    __syncthreads();
    mx = red[0];
    float sum = 0.f;
    for (int i = 0; i < 3; i++) {
        v[i] = expf(v[i] - mx);
        sum += v[i];
    }
    for (int off = 32; off > 0; off >>= 1) sum += __shfl_down(sum, off);
    if ((t & 63) == 0) red[8 + (t >> 6)] = sum;
    __syncthreads();
    if (t == 0) red[8] = red[8] + red[9] + red[10] + red[11];
    __syncthreads();
    float inv = 1.f / red[8];
    for (int i = 0; i < 3; i++) {
        float a = v[i] * inv;
        al_s[i * 256 + t] = a;
        if (blockIdx.x == 0) alpha_out[b * HW_ + i * 256 + t] = a;
    }
    __syncthreads();
    int dc0 = blockIdx.x * 114;
    int wave = t >> 6, lane = t & 63;
    for (int d = dc0 + wave; d < dc0 + 114; d += 4) {
        const float* row = &ctx[((long)b * DC + d) * HW_];
        float s = 0.f;
#pragma unroll
        for (int q = 0; q < 12; q++) s += row[lane + q * 64] * al_s[lane + q * 64];
        for (int off = 32; off > 0; off >>= 1) s += __shfl_down(s, off);
        if (lane == 0) ct[b * DC + d] = s;
    }
}

// ---------------- K5: logit rows -------------------------------------------
__global__ __launch_bounds__(256) void k_logit(
    const float* __restrict__ ctv, const float* __restrict__ s,
    const float* __restrict__ embedded, const float* __restrict__ Wct,
    const float* __restrict__ Wht, const float* __restrict__ Wct_b,
    const float* __restrict__ Wht_b, float* __restrict__ lg) {
    __shared__ float Xs[64 * 257];
    __shared__ float Ws[4 * 232];
    int t = threadIdx.x, w = t >> 6, lane = t & 63;
    int r = blockIdx.x * 4 + w;
    float acc = 0.f;
    for (int c = 0; c < 3; c++) {
        int c0 = c * 228;
        __syncthreads();
        for (int i = t; i < 64 * 228; i += 256) {
            int bb = i / 228, kk = i - bb * 228;
            Xs[bb * 229 + kk] = ctv[bb * DC + c0 + kk];
        }
        for (int j = lane; j < 228; j += 64) Ws[w * 232 + j] = Wct[r * DC + c0 + j];
        __syncthreads();
        const float* xrow = Xs + lane * 229;
        const float* wrow = Ws + w * 232;
#pragma unroll 4
        for (int k = 0; k < 228; k++) acc += wrow[k] * xrow[k];
    }
    __syncthreads();
    for (int i = t; i < 64 * 256; i += 256) {
        int bb = i >> 8, k = i & 255;
        Xs[bb * 257 + k] = s[bb * 256 + k];
    }
    __syncthreads();
    const float* xrow2 = Xs + lane * 257;
    const float* wr = Wht + r * 256;
    float acc2 = 0.f;
#pragma unroll 8
    for (int k = 0; k < 256; k++) acc2 += wr[k] * xrow2[k];
    lg[lane * 256 + r] = acc + acc2 + Wct_b[r] + Wht_b[r] + embedded[lane * 256 + r];
}

// ---------------- K6: maxout + W0 head -------------------------------------
__global__ __launch_bounds__(256) void k_head(const float* __restrict__ lg,
                                              const float* __restrict__ W0,
                                              const float* __restrict__ W0_b,
                                              float* __restrict__ out) {
    __shared__ float Xs[64 * 129];
    __shared__ float Ws[4 * 132];
    int t = threadIdx.x, w = t >> 6, lane = t & 63;
    for (int i = t; i < 64 * 128; i += 256) {
        int bb = i >> 7, m = i & 127;
        Xs[bb * 129 + m] = fmaxf(lg[bb * 256 + 2 * m], lg[bb * 256 + 2 * m + 1]);
    }
    int r = blockIdx.x * 4 + w;
    Ws[w * 132 + lane] = W0[r * 128 + lane];
    Ws[w * 132 + 64 + lane] = W0[r * 128 + 64 + lane];
    __syncthreads();
    const float* xrow = Xs + lane * 129;
    const float* wrow = Ws + w * 132;
    float acc = 0.f;
#pragma unroll 8
    for (int k = 0; k < 128; k++) acc += wrow[k] * xrow[k];
    out[lane * KV + r] = acc + W0_b[r];
}

extern "C" void kernel_launch(void* const* d_in, const int* in_sizes, int n_in,
                              void* d_out, int out_size, void* d_ws,
                              size_t ws_size, hipStream_t stream) {
    const int* y = (const int*)d_in[0];
    const float* y_mask = (const float*)d_in[1];
    const float* context = (const float*)d_in[2];
    const float* pre_hidden = (const float*)d_in[3];
    const float* alpha_past = (const float*)d_in[4];
    const float* emb = (const float*)d_in[5];
    const float* W_ih1 = (const float*)d_in[6];
    const float* W_hh1 = (const float*)d_in[7];
    const float* b_ih1 = (const float*)d_in[8];
    const float* b_hh1 = (const float*)d_in[9];
    const float* conv_Ua_w = (const float*)d_in[10];
    const float* conv_Ua_b = (const float*)d_in[11];
    const float* Wa = (const float*)d_in[12];
    const float* conv_Q_w = (const float*)d_in[13];
    const float* Uf = (const float*)d_in[14];
    const float* Uf_b = (const float*)d_in[15];
    const float* va = (const float*)d_in[16];
    const float* va_b = (const float*)d_in[17];
    const float* W_ih2 = (const float*)d_in[18];
    const float* W_hh2 = (const float*)d_in[19];
    const float* b_ih2 = (const float*)d_in[20];
    const float* b_hh2 = (const float*)d_in[21];
    const float* Wct = (const float*)d_in[22];
    const float* Wct_b = (const float*)d_in[23];
    const float* Wht = (const float*)d_in[24];
    const float* Wht_b = (const float*)d_in[25];
    const float* W0 = (const float*)d_in[26];
    const float* W0_b = (const float*)d_in[27];

    float* ws = (float*)d_ws;
    float* out = (float*)d_out;
    float* G = ws + WS_G;
    float* rbias = ws + WS_RB;
    float* embedded = ws + WS_EMB;
    float* s_hat = ws + WS_SH;
    float* ctv = ws + WS_CT;
    unsigned short* Apack = (unsigned short*)(ws + WS_APACK);
    float* gi = ws + WS_GI;
    float* gh = ws + WS_GH;
    float* lg = ws + WS_LG;
    unsigned short* Bpack = (unsigned short*)(ws + WS_BP);
    float* alq = ws + WS_ALQ;
    float* s_out = out + 8192;
    float* alpha_out = out + 24576;

    bool fast = ws_size >= NEED_BYTES;

    if (fast) {
        k_prep<<<dim3(929), dim3(512), 0, stream>>>(context, conv_Ua_w, Uf,
                                                    conv_Q_w, y, emb, Bpack,
                                                    Apack, G, embedded);
    } else {
        k_G<<<dim3(18), dim3(256), 0, stream>>>(Uf, conv_Q_w, G);
        k_prepA<<<dim3((NS * DA * 32 + 255) / 256), dim3(256), 0, stream>>>(
            conv_Ua_w, Apack);
        k_emb<<<dim3(64), dim3(256), 0, stream>>>(y, emb, embedded);
    }
    k_gih1<<<dim3(384), dim3(256), 0, stream>>>(embedded, pre_hidden, W_ih1,
                                                W_hh1, b_ih1, b_hh1, gi, gh);
    k_gru<<<dim3(64), dim3(256), 0, stream>>>(gi, gh, pre_hidden, y_mask, s_hat);
    k_rows256<<<dim3(128), dim3(256), 0, stream>>>(s_hat, Wa, conv_Ua_b, Uf_b,
                                                   rbias, 512);
    if (fast) {
        k_att3<<<dim3(6, 2, 64), dim3(512), 0, stream>>>(
            Apack, Bpack, G, rbias, va, alpha_past, alq);
    } else {
        // fallback: write half 0, zero half 1
        hipMemsetAsync(alq + 49152, 0, (size_t)49152 * sizeof(float), stream);
        k_att_lds<<<dim3(12, 64), dim3(256), 0, stream>>>(
            Apack, context, G, rbias, va, alpha_past, alq);
    }
    k_ctsm<<<dim3(6, 64), dim3(256), 0, stream>>>(context, alq, ctv, alpha_out);
    k_gih2<<<dim3(384), dim3(256), 0, stream>>>(ctv, s_hat, W_ih2, W_hh2, b_ih2,
                                                b_hh2, gi, gh);
    k_gru<<<dim3(64), dim3(256), 0, stream>>>(gi, gh, s_hat, y_mask, s_out);
    k_logit<<<dim3(64), dim3(256), 0, stream>>>(ctv, s_out, embedded, Wct, Wht,
                                                Wct_b, Wht_b, lg);
    k_head<<<dim3(32), dim3(256), 0, stream>>>(lg, W0, W0_b, out);
}

// Round 16
// 233.870 us; speedup vs baseline: 1.3017x; 1.0249x over previous
//
#include <hip/hip_runtime.h>
#include <hip/hip_bf16.h>
#include <math.h>

#define BB 64
#define KV 128
#define ME 256
#define NH 256
#define DC 684
#define DA 512
#define MC 256
#define HH_ 16
#define WW_ 48
#define HW_ 768
#define NS 22   // K-steps of 32 (684 -> 704 padded)

typedef __attribute__((ext_vector_type(8))) short bf16x8;
typedef __attribute__((ext_vector_type(4))) float f32x4;

// workspace layout (floats)
#define WS_G     0                    // 512*9
#define WS_RB    (WS_G + 4608)        // rowbias 64*512
#define WS_EMB   (WS_RB + 32768)      // 64*256
#define WS_SH    (WS_EMB + 16384)     // 64*256 s_hat
#define WS_AL    (WS_SH + 16384)      // 64*768 alpha logits (fallback)
#define WS_CT    (WS_AL + 49152)      // 64*684 ct
#define WS_APACK (WS_CT + 43776)      // 22*512*32 bf16 = 180224 floats
#define WS_GI    (WS_APACK + 180224)  // 64*768
#define WS_GH    (WS_GI + 49152)      // 64*768
#define WS_LG    WS_GI                // logit 64*256 reuses GI after gru2
#define WS_BP    (WS_GH + 49152)      // = 441600; Bpack 64*12*22*2048 bf16
#define WS_ALQ   (WS_BP + 17301504)   // 2 x 64*768 alpha-logit halves
#define NEED_BYTES ((size_t)(441600 + 17301504 + 98304) * 4)

static __device__ __forceinline__ unsigned short f2b(float v) {
    __hip_bfloat16 h = __float2bfloat16(v);
    return *reinterpret_cast<unsigned short*>(&h);
}

// async global->LDS, 16B per lane. LDS base must be wave-uniform; HW adds
// lane*16. Global address is per-lane.
static __device__ __forceinline__ void gl_lds16(const unsigned short* g,
                                                unsigned short* l) {
    __builtin_amdgcn_global_load_lds(
        (const __attribute__((address_space(1))) unsigned int*)g,
        (__attribute__((address_space(3))) unsigned int*)l, 16, 0, 0);
}

// =================== fused prep ============================================
__global__ __launch_bounds__(512) void k_prep(
    const float* __restrict__ ctx, const float* __restrict__ Ua,
    const float* __restrict__ Uf, const float* __restrict__ convQ,
    const int* __restrict__ y, const float* __restrict__ emb,
    unsigned short* __restrict__ Bpack, unsigned short* __restrict__ Apack,
    float* __restrict__ G, float* __restrict__ embedded) {
    __shared__ unsigned short Ts[64 * 360];  // 45 KB
    int bx = blockIdx.x, t = threadIdx.x;
    if (bx < 768) {
        int b = bx / 12, pt = bx % 12, p0 = pt * 64;
        int w = t >> 6, p = t & 63;  // 8 waves, lane = p
        unsigned short* dst = Bpack + (long)(b * 12 + pt) * 22 * 2048;
        for (int ch = 0; ch < 2; ch++) {
            int dbase = ch * 352;
            if (ch) __syncthreads();
#pragma unroll
            for (int iter = 0; iter < 11; iter++) {
                int d0 = dbase + iter * 32 + w * 4;
                float v0 = 0.f, v1 = 0.f, v2 = 0.f, v3 = 0.f;
                const float* src = ctx + ((long)b * DC + d0) * HW_ + p0 + p;
                if (d0 + 0 < DC) v0 = src[0];
                if (d0 + 1 < DC) v1 = src[HW_];
                if (d0 + 2 < DC) v2 = src[2 * HW_];
                if (d0 + 3 < DC) v3 = src[3 * HW_];
                unsigned u01 = (unsigned)f2b(v0) | ((unsigned)f2b(v1) << 16);
                unsigned u23 = (unsigned)f2b(v2) | ((unsigned)f2b(v3) << 16);
                *(uint2*)&Ts[p * 360 + (d0 - dbase)] = make_uint2(u01, u23);
            }
            __syncthreads();
            int so = t >> 8;
            int tt = t & 255;
            int pp = tt >> 2, slot = tt & 3;
#pragma unroll
            for (int s2 = 0; s2 < 12; s2 += 2) {
                int sl = s2 + so;
                if (sl < 11) {
                    int s = ch * 11 + sl;
                    bf16x8 v = *(const bf16x8*)&Ts[pp * 360 + sl * 32 +
                                                   ((slot ^ ((pp >> 1) & 3))
                                                    << 3)];
                    *(bf16x8*)(dst + (long)(s * 256 + tt) * 8) = v;
                }
            }
        }
    } else if (bx < 856) {
        int bi = bx - 768;
#pragma unroll
        for (int r = 0; r < 8; r++) {
            int idx = bi * 4096 + r * 512 + t;
            int e = idx & 7, slot = (idx >> 3) & 3;
            int a = (idx >> 5) & 511, s = idx >> 14;
            int d = s * 32 + ((slot ^ ((a >> 1) & 3)) << 3) + e;
            float v = (d < DC) ? Ua[a * DC + d] : 0.f;
            Apack[idx] = f2b(v);
        }
    } else if (bx < 865) {
        int idx = (bx - 856) * 512 + t;
        if (idx < DA * 9) {
            int a = idx / 9, k = idx % 9;
            float s = 0.f;
            for (int m = 0; m < MC; m++) s += Uf[a * MC + m] * convQ[m * 9 + k];
            G[idx] = s;
        }
    } else {
        int b = bx - 865;
        if (t < ME) embedded[b * ME + t] = emb[y[b] * ME + t];
    }
}

// =================== fallback-path prep kernels ============================
__global__ __launch_bounds__(256) void k_G(const float* __restrict__ Uf,
                                           const float* __restrict__ convQ,
                                           float* __restrict__ G) {
    int idx = blockIdx.x * 256 + threadIdx.x;
    if (idx >= DA * 9) return;
    int a = idx / 9, k = idx % 9;
    float s = 0.f;
    for (int m = 0; m < MC; m++) s += Uf[a * MC + m] * convQ[m * 9 + k];
    G[idx] = s;
}

__global__ __launch_bounds__(256) void k_prepA(const float* __restrict__ Ua,
                                               unsigned short* __restrict__ Apack) {
    int idx = blockIdx.x * 256 + threadIdx.x;
    if (idx >= NS * DA * 32) return;
    int e = idx & 7, slot = (idx >> 3) & 3;
    int a = (idx >> 5) & 511, s = idx >> 14;
    int d = s * 32 + ((slot ^ ((a >> 1) & 3)) << 3) + e;
    float v = (d < DC) ? Ua[a * DC + d] : 0.f;
    Apack[idx] = f2b(v);
}

__global__ __launch_bounds__(256) void k_emb(const int* __restrict__ y,
                                             const float* __restrict__ emb,
                                             float* __restrict__ embedded) {
    int b = blockIdx.x, t = threadIdx.x;
    embedded[b * ME + t] = emb[y[b] * ME + t];
}

// ------- generic rows-of-W kernel, K=256 -----------------------------------
__global__ __launch_bounds__(256) void k_rows256(
    const float* __restrict__ X, const float* __restrict__ W,
    const float* __restrict__ bias, const float* __restrict__ bias2,
    float* __restrict__ out, int outStride) {
    __shared__ float Xs[64 * 257];
    __shared__ float Ws[4 * 260];
    int t = threadIdx.x, w = t >> 6, lane = t & 63;
    for (int i = t; i < 64 * 256; i += 256) {
        int bb = i >> 8, k = i & 255;
        Xs[bb * 257 + k] = X[bb * 256 + k];
    }
    int r = blockIdx.x * 4 + w;
    *(f32x4*)(Ws + w * 260 + lane * 4) = *(const f32x4*)(W + r * 256 + lane * 4);
    __syncthreads();
    const float* xrow = Xs + lane * 257;
    const float* wrow = Ws + w * 260;
    float acc = 0.f;
#pragma unroll 8
    for (int k = 0; k < 256; k++) acc += wrow[k] * xrow[k];
    acc += bias[r];
    if (bias2) acc += bias2[r];
    out[lane * outStride + r] = acc;
}

// ------- fused GRU1 gate GEMVs ---------------------------------------------
__global__ __launch_bounds__(256) void k_gih1(
    const float* __restrict__ embedded, const float* __restrict__ pre_hidden,
    const float* __restrict__ W_ih1, const float* __restrict__ W_hh1,
    const float* __restrict__ b_ih1, const float* __restrict__ b_hh1,
    float* __restrict__ gi, float* __restrict__ gh) {
    __shared__ float Xs[64 * 257];
    __shared__ float Ws[4 * 260];
    int bx = blockIdx.x, t = threadIdx.x, w = t >> 6, lane = t & 63;
    const float *X, *W, *bias;
    float* outp;
    int r;
    if (bx < 192) {
        X = embedded; W = W_ih1; bias = b_ih1; outp = gi; r = bx * 4 + w;
    } else {
        X = pre_hidden; W = W_hh1; bias = b_hh1; outp = gh; r = (bx - 192) * 4 + w;
    }
    for (int i = t; i < 64 * 256; i += 256) {
        int bb = i >> 8, k = i & 255;
        Xs[bb * 257 + k] = X[bb * 256 + k];
    }
    *(f32x4*)(Ws + w * 260 + lane * 4) = *(const f32x4*)(W + r * 256 + lane * 4);
    __syncthreads();
    const float* xrow = Xs + lane * 257;
    const float* wrow = Ws + w * 260;
    float acc = 0.f;
#pragma unroll 8
    for (int k = 0; k < 256; k++) acc += wrow[k] * xrow[k];
    outp[lane * 768 + r] = acc + bias[r];
}

// ------- fused GRU2 gate GEMVs ---------------------------------------------
__global__ __launch_bounds__(256) void k_gih2(
    const float* __restrict__ ctv, const float* __restrict__ s_hat,
    const float* __restrict__ W_ih2, const float* __restrict__ W_hh2,
    const float* __restrict__ b_ih2, const float* __restrict__ b_hh2,
    float* __restrict__ gi, float* __restrict__ gh) {
    __shared__ float Xs[64 * 257];
    __shared__ float Ws[4 * 260];
    int bx = blockIdx.x, t = threadIdx.x, w = t >> 6, lane = t & 63;
    if (bx < 192) {
        int r = bx * 4 + w;
        float acc = 0.f;
        for (int c = 0; c < 3; c++) {
            int c0 = c * 228;
            __syncthreads();
            for (int i = t; i < 64 * 228; i += 256) {
                int bb = i / 228, kk = i - bb * 228;
                Xs[bb * 229 + kk] = ctv[bb * DC + c0 + kk];
            }
            for (int j = lane; j < 228; j += 64)
                Ws[w * 260 + j] = W_ih2[r * DC + c0 + j];
            __syncthreads();
            const float* xrow = Xs + lane * 229;
            const float* wrow = Ws + w * 260;
#pragma unroll 4
            for (int k = 0; k < 228; k++) acc += wrow[k] * xrow[k];
        }
        gi[lane * 768 + r] = acc + b_ih2[r];
    } else {
        int r = (bx - 192) * 4 + w;
        for (int i = t; i < 64 * 256; i += 256) {
            int bb = i >> 8, k = i & 255;
            Xs[bb * 257 + k] = s_hat[bb * 256 + k];
        }
        *(f32x4*)(Ws + w * 260 + lane * 4) =
            *(const f32x4*)(W_hh2 + r * 256 + lane * 4);
        __syncthreads();
        const float* xrow = Xs + lane * 257;
        const float* wrow = Ws + w * 260;
        float acc = 0.f;
#pragma unroll 8
        for (int k = 0; k < 256; k++) acc += wrow[k] * xrow[k];
        gh[lane * 768 + r] = acc + b_hh2[r];
    }
}

// ---------------- GRU elementwise ------------------------------------------
__global__ __launch_bounds__(256) void k_gru(const float* __restrict__ gi,
                                             const float* __restrict__ gh,
                                             const float* __restrict__ h,
                                             const float* __restrict__ y_mask,
                                             float* __restrict__ outp) {
    int b = blockIdx.x, t = threadIdx.x;
    float hv = h[b * NH + t];
    float r = 1.f / (1.f + expf(-(gi[b * 768 + t] + gh[b * 768 + t])));
    float z = 1.f / (1.f + expf(-(gi[b * 768 + 256 + t] + gh[b * 768 + 256 + t])));
    float n = tanhf(gi[b * 768 + 512 + t] + r * gh[b * 768 + 512 + t]);
    float sv = (1.f - z) * n + z * hv;
    float m = y_mask[b];
    outp[b * NH + t] = m * sv + (1.f - m) * hv;
}

// ======= K2 fast: R15 engine + TRIPLE-buffered LDS (depth-2 pipeline) ======
// R15 post-mortem: with double-buffering, a step's loads are issued at the
// end of step s-1 and consumed at s+1 -> only ONE period in flight, so the
// step period equals the full congested load latency (~3400 cyc) and BW
// never saturates (2.9 of 6 TB/s). Triple-buffer -> loads in flight for
// TWO periods -> T = max(L/2, compute). LDS 79KB (2 blocks/CU), VGPR ~104.
// Steady-state wait: 3 STAGEs x 3 loads outstanding, oldest done = vmcnt(6);
// tail peels vmcnt(6)/(3)/(0). Block = 256a x 128p, grid (6 pt2, 2 ah, 64 b).
__global__ __launch_bounds__(512) void k_att3(
    const unsigned short* __restrict__ Apack,
    const unsigned short* __restrict__ Bpack, const float* __restrict__ G,
    const float* __restrict__ rb, const float* __restrict__ va,
    const float* __restrict__ apast, float* __restrict__ alq) {
    __shared__ __attribute__((aligned(16))) unsigned short lsA[3][8192];
    __shared__ __attribute__((aligned(16))) unsigned short lsB[3][4096];
    __shared__ float ap_s[18 * 50];
    __shared__ float part_s[8][64];
    int pt2 = blockIdx.x, ah = blockIdx.y, b = blockIdx.z;
    int t = threadIdx.x, w = t >> 6, lane = t & 63;
    int l15 = lane & 15, lg = lane >> 4;
    int aw = w & 3, pw = w >> 2;
    int sx = lg ^ ((l15 >> 1) & 3);  // swizzled k-slot for ds_read

    for (int idx = t; idx < 900; idx += 512) {
        int hh = idx / 50, ww = idx % 50;
        float v = 0.f;
        if (hh >= 1 && hh <= HH_ && ww >= 1 && ww <= WW_)
            v = apast[b * HW_ + (hh - 1) * WW_ + (ww - 1)];
        ap_s[idx] = v;
    }
    __syncthreads();  // full drain before pipeline starts

    const unsigned short* Ap0 = Apack + ah * 8192 + w * 1024 + lane * 8;
    const unsigned short* Bp0 =
        Bpack + (long)(b * 12 + pt2 * 2 + (w >> 2)) * 22 * 2048 +
        (w & 3) * 512 + lane * 8;

#define STAGE(S, BUF)                                                        \
    do {                                                                     \
        _Pragma("unroll") for (int i_ = 0; i_ < 2; i_++)                     \
            gl_lds16(Ap0 + (long)(S)*16384 + i_ * 512,                       \
                     &lsA[BUF][w * 1024 + i_ * 512]);                        \
        gl_lds16(Bp0 + (long)(S)*2048, &lsB[BUF][w * 512]);                  \
    } while (0)

#define STEP_BODY(CUR)                                                       \
    do {                                                                     \
        bf16x8 af[4], bf[4];                                                 \
        _Pragma("unroll") for (int i = 0; i < 4; i++)                        \
            af[i] = *(const bf16x8*)&lsA[CUR][(aw * 64 + i * 16 + l15) * 32 +\
                                             sx * 8];                        \
        _Pragma("unroll") for (int j = 0; j < 4; j++)                        \
            bf[j] = *(const bf16x8*)&lsB[CUR][pw * 2048 +                    \
                                             (j * 16 + l15) * 32 + sx * 8]; \
        _Pragma("unroll") for (int i = 0; i < 4; i++)                        \
            _Pragma("unroll") for (int j = 0; j < 4; j++)                    \
                acc[i][j] = __builtin_amdgcn_mfma_f32_16x16x32_bf16(         \
                    af[i], bf[j], acc[i][j], 0, 0, 0);                       \
    } while (0)

    f32x4 acc[4][4];
#pragma unroll
    for (int i = 0; i < 4; i++)
#pragma unroll
        for (int j = 0; j < 4; j++) acc[i][j] = {0.f, 0.f, 0.f, 0.f};

    STAGE(0, 0);
    STAGE(1, 1);
    STAGE(2, 2);

    // main loop: steps 0 .. NS-4; steady-state vmcnt(6)
    int cur = 0;
    for (int s = 0; s < NS - 3; s++) {
        asm volatile("s_waitcnt vmcnt(6)" ::: "memory");
        __builtin_amdgcn_sched_barrier(0);
        __builtin_amdgcn_s_barrier();   // step-s stages visible to all waves
        __builtin_amdgcn_sched_barrier(0);
        STEP_BODY(cur);
        __builtin_amdgcn_s_barrier();   // buf cur fully consumed
        __builtin_amdgcn_sched_barrier(0);
        STAGE(s + 3, cur);
        cur = (cur == 2) ? 0 : cur + 1;
    }
    // s = NS-3: all 3 remaining stages outstanding (9 loads), need oldest
    asm volatile("s_waitcnt vmcnt(6)" ::: "memory");
    __builtin_amdgcn_sched_barrier(0);
    __builtin_amdgcn_s_barrier();
    __builtin_amdgcn_sched_barrier(0);
    STEP_BODY(cur);
    __builtin_amdgcn_s_barrier();
    __builtin_amdgcn_sched_barrier(0);
    cur = (cur == 2) ? 0 : cur + 1;
    // s = NS-2
    asm volatile("s_waitcnt vmcnt(3)" ::: "memory");
    __builtin_amdgcn_sched_barrier(0);
    __builtin_amdgcn_s_barrier();
    __builtin_amdgcn_sched_barrier(0);
    STEP_BODY(cur);
    __builtin_amdgcn_s_barrier();
    __builtin_amdgcn_sched_barrier(0);
    cur = (cur == 2) ? 0 : cur + 1;
    // s = NS-1
    asm volatile("s_waitcnt vmcnt(0)" ::: "memory");
    __builtin_amdgcn_sched_barrier(0);
    __builtin_amdgcn_s_barrier();
    __builtin_amdgcn_sched_barrier(0);
    STEP_BODY(cur);
#undef STAGE
#undef STEP_BODY

    // epilogue: + rowbias + 9-tap coverage, tanh, dot with va, reduce over a
    float partial[4] = {0.f, 0.f, 0.f, 0.f};
#pragma unroll
    for (int i = 0; i < 4; i++) {
#pragma unroll
        for (int r = 0; r < 4; r++) {
            int a = ah * 256 + aw * 64 + i * 16 + lg * 4 + r;
            float rbv = rb[b * DA + a];
            float vav = va[a];
            const float* Ga = G + a * 9;
            float g0 = Ga[0], g1 = Ga[1], g2 = Ga[2], g3 = Ga[3], g4 = Ga[4];
            float g5 = Ga[5], g6 = Ga[6], g7 = Ga[7], g8 = Ga[8];
#pragma unroll
            for (int j = 0; j < 4; j++) {
                int p = pt2 * 128 + pw * 64 + j * 16 + l15;
                int hh = p / WW_, ww = p % WW_;
                const float* ap = ap_s + hh * 50 + ww;
                float cov = g0 * ap[0] + g1 * ap[1] + g2 * ap[2] +
                            g3 * ap[50] + g4 * ap[51] + g5 * ap[52] +
                            g6 * ap[100] + g7 * ap[101] + g8 * ap[102];
                float e = tanhf(acc[i][j][r] + rbv + cov);
                partial[j] += vav * e;
            }
        }
    }
#pragma unroll
    for (int j = 0; j < 4; j++) {
        partial[j] += __shfl_xor(partial[j], 16);
        partial[j] += __shfl_xor(partial[j], 32);
    }
    if (lane < 16) {
#pragma unroll
        for (int j = 0; j < 4; j++) part_s[w][j * 16 + lane] = partial[j];
    }
    __syncthreads();
    if (t < 128) {
        int pg = t >> 6, pl = t & 63;
        float sum = (part_s[pg * 4 + 0][pl] + part_s[pg * 4 + 1][pl]) +
                    (part_s[pg * 4 + 2][pl] + part_s[pg * 4 + 3][pl]);
        alq[ah * 49152 + b * HW_ + pt2 * 128 + t] = sum;
    }
}

// ======= K2 fallback: LDS-staging version (Apack slot-swizzle aware) =======
#define LDW 40
__global__ __launch_bounds__(256) void k_att_lds(
    const unsigned short* __restrict__ Apack, const float* __restrict__ ctx,
    const float* __restrict__ G, const float* __restrict__ rb,
    const float* __restrict__ va, const float* __restrict__ apast,
    float* __restrict__ alogit) {
    __shared__ __attribute__((aligned(16))) short lsB[2][64 * LDW];
    __shared__ float ap_s[18 * 50];
    __shared__ float part_s[4 * 64];
    int b = blockIdx.y;
    int p0 = blockIdx.x * 64;
    int t = threadIdx.x;
    int w = t >> 6, lane = t & 63;
    int l15 = lane & 15, lg = lane >> 4;
    int sxA = lg ^ ((l15 >> 1) & 3);
    int pq = t & 15, kp = t >> 4;
    const float* ctx_b = ctx + (long)b * DC * HW_ + p0;

    for (int idx = t; idx < 900; idx += 256) {
        int hh = idx / 50, ww = idx % 50;
        float v = 0.f;
        if (hh >= 1 && hh <= HH_ && ww >= 1 && ww <= WW_)
            v = apast[b * HW_ + (hh - 1) * WW_ + (ww - 1)];
        ap_s[idx] = v;
    }

#define CTXLOAD(FA, FB, S)                                                   \
    do {                                                                     \
        int d_ = (S) * 32 + 2 * kp;                                          \
        const float* s0_ = ctx_b + (long)d_ * HW_ + pq;                      \
        bool g0_ = d_ < DC, g1_ = (d_ + 1) < DC;                             \
        _Pragma("unroll") for (int j_ = 0; j_ < 4; j_++) {                   \
            FA[j_] = g0_ ? s0_[16 * j_] : 0.f;                               \
            FB[j_] = g1_ ? s0_[HW_ + 16 * j_] : 0.f;                         \
        }                                                                    \
    } while (0)
#define STAGEW(FA, FB, BUF)                                                  \
    do {                                                                     \
        _Pragma("unroll") for (int j_ = 0; j_ < 4; j_++) {                   \
            ((unsigned*)lsB[BUF])[(pq + 16 * j_) * (LDW / 2) + kp] =         \
                (unsigned)f2b(FA[j_]) | ((unsigned)f2b(FB[j_]) << 16);       \
        }                                                                    \
    } while (0)
#define ALOAD(AF, S)                                                         \
    do {                                                                     \
        _Pragma("unroll") for (int i_ = 0; i_ < 8; i_++)                     \
            AF[i_] = *(const bf16x8*)(Apack +                                \
                ((long)((S)*512 + w * 128 + i_ * 16 + l15) * 4 + sxA) * 8);  \
    } while (0)
#define BREAD(BF, BUF)                                                       \
    do {                                                                     \
        _Pragma("unroll") for (int j_ = 0; j_ < 4; j_++)                     \
            BF[j_] = *(const bf16x8*)(&lsB[BUF][(j_ * 16 + l15) * LDW +      \
                                               lg * 8]);                     \
    } while (0)
#define MFMA8x4(AF, BF)                                                      \
    do {                                                                     \
        _Pragma("unroll") for (int i_ = 0; i_ < 8; i_++)                     \
            _Pragma("unroll") for (int j_ = 0; j_ < 4; j_++)                 \
                acc[i_][j_] = __builtin_amdgcn_mfma_f32_16x16x32_bf16(       \
                    AF[i_], BF[j_], acc[i_][j_], 0, 0, 0);                   \
    } while (0)

    f32x4 acc[8][4];
#pragma unroll
    for (int i = 0; i < 8; i++)
#pragma unroll
        for (int j = 0; j < 4; j++) acc[i][j] = {0.f, 0.f, 0.f, 0.f};

    float fa0[4], fb0[4], fa1[4], fb1[4];
    bf16x8 afr0[8], afr1[8], bfr[4];

    CTXLOAD(fa1, fb1, 0);
    ALOAD(afr0, 0);
    STAGEW(fa1, fb1, 0);
    CTXLOAD(fa1, fb1, 1);
    __syncthreads();

    for (int ss = 0; ss < NS; ss += 2) {
        if (ss + 2 < NS) CTXLOAD(fa0, fb0, ss + 2);
        ALOAD(afr1, ss + 1);
        BREAD(bfr, 0);
        STAGEW(fa1, fb1, 1);
        MFMA8x4(afr0, bfr);
        __syncthreads();
        if (ss + 3 < NS) CTXLOAD(fa1, fb1, ss + 3);
        if (ss + 2 < NS) {
            ALOAD(afr0, ss + 2);
            BREAD(bfr, 1);
            STAGEW(fa0, fb0, 0);
            MFMA8x4(afr1, bfr);
        } else {
            BREAD(bfr, 1);
            MFMA8x4(afr1, bfr);
        }
        __syncthreads();
    }

    float partial[4] = {0.f, 0.f, 0.f, 0.f};
#pragma unroll
    for (int i = 0; i < 8; i++) {
#pragma unroll
        for (int r = 0; r < 4; r++) {
            int a = w * 128 + i * 16 + lg * 4 + r;
            float rbv = rb[b * DA + a];
            float vav = va[a];
            const float* Ga = G + a * 9;
            float g0 = Ga[0], g1 = Ga[1], g2 = Ga[2], g3 = Ga[3], g4 = Ga[4];
            float g5 = Ga[5], g6 = Ga[6], g7 = Ga[7], g8 = Ga[8];
#pragma unroll
            for (int j = 0; j < 4; j++) {
                int p = p0 + j * 16 + l15;
                int hh = p / WW_, ww = p % WW_;
                const float* ap = ap_s + hh * 50 + ww;
                float cov = g0 * ap[0] + g1 * ap[1] + g2 * ap[2] +
                            g3 * ap[50] + g4 * ap[51] + g5 * ap[52] +
                            g6 * ap[100] + g7 * ap[101] + g8 * ap[102];
                float e = tanhf(acc[i][j][r] + rbv + cov);
                partial[j] += vav * e;
            }
        }
    }
#pragma unroll
    for (int j = 0; j < 4; j++) {
        partial[j] += __shfl_xor(partial[j], 16);
        partial[j] += __shfl_xor(partial[j], 32);
    }
    if (lane < 16) {
#pragma unroll
        for (int j = 0; j < 4; j++) part_s[w * 64 + j * 16 + lane] = partial[j];
    }
    __syncthreads();
    if (t < 64) {
        float s = part_s[t] + part_s[64 + t] + part_s[128 + t] +
                  part_s[192 + t];
        alogit[b * HW_ + p0 + t] = s;
    }
}

// ---------------- K3+K4 fused: (sum halves) + softmax + ct -----------------
__global__ __launch_bounds__(256) void k_ctsm(const float* __restrict__ ctx,
                                              const float* __restrict__ alq,
                                              float* __restrict__ ct,
                                              float* __restrict__ alpha_out) {
    __shared__ float al_s[HW_];
    __shared__ float red[16];
    int b = blockIdx.y, t = threadIdx.x;
    float v[3];
    float mx = -1e30f;
    for (int i = 0; i < 3; i++) {
        int idx = b * HW_ + i * 256 + t;
        v[i] = alq[idx] + alq[49152 + idx];
        mx = fmaxf(mx, v[i]);
    }
    for (int off = 32; off > 0; off >>= 1) mx = fmaxf(mx, __shfl_down(mx, off));
    if ((t & 63) == 0) red[t >> 6] = mx;
    __syncthreads();
    if (t == 0) red[0] = fmaxf(fmaxf(red[0], red[1]), fmaxf(red[2], red[3]));
    __syncthreads();
    mx = red[0];
    float sum = 0.f;
    for (int i = 0; i < 3; i++) {
        v[i] = expf(v[i] - mx);
        sum += v[i];
    }
    for (int off = 32; off > 0; off >>= 1) sum += __shfl_down(sum, off);
    if ((t & 63) == 0) red[8 + (t >> 6)] = sum;
    __syncthreads();
    if (t == 0) red[8] = red[8] + red[9] + red[10] + red[11];
    __syncthreads();
    float inv = 1.f / red[8];
    for (int i = 0; i < 3; i++) {
        float a = v[i] * inv;
        al_s[i * 256 + t] = a;
        if (blockIdx.x == 0) alpha_out[b * HW_ + i * 256 + t] = a;
    }
    __syncthreads();
    int dc0 = blockIdx.x * 114;
    int wave = t >> 6, lane = t & 63;
    for (int d = dc0 + wave; d < dc0 + 114; d += 4) {
        const float* row = &ctx[((long)b * DC + d) * HW_];
        float s = 0.f;
#pragma unroll
        for (int q = 0; q < 12; q++) s += row[lane + q * 64] * al_s[lane + q * 64];
        for (int off = 32; off > 0; off >>= 1) s += __shfl_down(s, off);
        if (lane == 0) ct[b * DC + d] = s;
    }
}

// ---------------- K5: logit rows -------------------------------------------
__global__ __launch_bounds__(256) void k_logit(
    const float* __restrict__ ctv, const float* __restrict__ s,
    const float* __restrict__ embedded, const float* __restrict__ Wct,
    const float* __restrict__ Wht, const float* __restrict__ Wct_b,
    const float* __restrict__ Wht_b, float* __restrict__ lg) {
    __shared__ float Xs[64 * 257];
    __shared__ float Ws[4 * 232];
    int t = threadIdx.x, w = t >> 6, lane = t & 63;
    int r = blockIdx.x * 4 + w;
    float acc = 0.f;
    for (int c = 0; c < 3; c++) {
        int c0 = c * 228;
        __syncthreads();
        for (int i = t; i < 64 * 228; i += 256) {
            int bb = i / 228, kk = i - bb * 228;
            Xs[bb * 229 + kk] = ctv[bb * DC + c0 + kk];
        }
        for (int j = lane; j < 228; j += 64) Ws[w * 232 + j] = Wct[r * DC + c0 + j];
        __syncthreads();
        const float* xrow = Xs + lane * 229;
        const float* wrow = Ws + w * 232;
#pragma unroll 4
        for (int k = 0; k < 228; k++) acc += wrow[k] * xrow[k];
    }
    __syncthreads();
    for (int i = t; i < 64 * 256; i += 256) {
        int bb = i >> 8, k = i & 255;
        Xs[bb * 257 + k] = s[bb * 256 + k];
    }
    __syncthreads();
    const float* xrow2 = Xs + lane * 257;
    const float* wr = Wht + r * 256;
    float acc2 = 0.f;
#pragma unroll 8
    for (int k = 0; k < 256; k++) acc2 += wr[k] * xrow2[k];
    lg[lane * 256 + r] = acc + acc2 + Wct_b[r] + Wht_b[r] + embedded[lane * 256 + r];
}

// ---------------- K6: maxout + W0 head -------------------------------------
__global__ __launch_bounds__(256) void k_head(const float* __restrict__ lg,
                                              const float* __restrict__ W0,
                                              const float* __restrict__ W0_b,
                                              float* __restrict__ out) {
    __shared__ float Xs[64 * 129];
    __shared__ float Ws[4 * 132];
    int t = threadIdx.x, w = t >> 6, lane = t & 63;
    for (int i = t; i < 64 * 128; i += 256) {
        int bb = i >> 7, m = i & 127;
        Xs[bb * 129 + m] = fmaxf(lg[bb * 256 + 2 * m], lg[bb * 256 + 2 * m + 1]);
    }
    int r = blockIdx.x * 4 + w;
    Ws[w * 132 + lane] = W0[r * 128 + lane];
    Ws[w * 132 + 64 + lane] = W0[r * 128 + 64 + lane];
    __syncthreads();
    const float* xrow = Xs + lane * 129;
    const float* wrow = Ws + w * 132;
    float acc = 0.f;
#pragma unroll 8
    for (int k = 0; k < 128; k++) acc += wrow[k] * xrow[k];
    out[lane * KV + r] = acc + W0_b[r];
}

extern "C" void kernel_launch(void* const* d_in, const int* in_sizes, int n_in,
                              void* d_out, int out_size, void* d_ws,
                              size_t ws_size, hipStream_t stream) {
    const int* y = (const int*)d_in[0];
    const float* y_mask = (const float*)d_in[1];
    const float* context = (const float*)d_in[2];
    const float* pre_hidden = (const float*)d_in[3];
    const float* alpha_past = (const float*)d_in[4];
    const float* emb = (const float*)d_in[5];
    const float* W_ih1 = (const float*)d_in[6];
    const float* W_hh1 = (const float*)d_in[7];
    const float* b_ih1 = (const float*)d_in[8];
    const float* b_hh1 = (const float*)d_in[9];
    const float* conv_Ua_w = (const float*)d_in[10];
    const float* conv_Ua_b = (const float*)d_in[11];
    const float* Wa = (const float*)d_in[12];
    const float* conv_Q_w = (const float*)d_in[13];
    const float* Uf = (const float*)d_in[14];
    const float* Uf_b = (const float*)d_in[15];
    const float* va = (const float*)d_in[16];
    const float* va_b = (const float*)d_in[17];
    const float* W_ih2 = (const float*)d_in[18];
    const float* W_hh2 = (const float*)d_in[19];
    const float* b_ih2 = (const float*)d_in[20];
    const float* b_hh2 = (const float*)d_in[21];
    const float* Wct = (const float*)d_in[22];
    const float* Wct_b = (const float*)d_in[23];
    const float* Wht = (const float*)d_in[24];
    const float* Wht_b = (const float*)d_in[25];
    const float* W0 = (const float*)d_in[26];
    const float* W0_b = (const float*)d_in[27];

    float* ws = (float*)d_ws;
    float* out = (float*)d_out;
    float* G = ws + WS_G;
    float* rbias = ws + WS_RB;
    float* embedded = ws + WS_EMB;
    float* s_hat = ws + WS_SH;
    float* ctv = ws + WS_CT;
    unsigned short* Apack = (unsigned short*)(ws + WS_APACK);
    float* gi = ws + WS_GI;
    float* gh = ws + WS_GH;
    float* lg = ws + WS_LG;
    unsigned short* Bpack = (unsigned short*)(ws + WS_BP);
    float* alq = ws + WS_ALQ;
    float* s_out = out + 8192;
    float* alpha_out = out + 24576;

    bool fast = ws_size >= NEED_BYTES;

    if (fast) {
        k_prep<<<dim3(929), dim3(512), 0, stream>>>(context, conv_Ua_w, Uf,
                                                    conv_Q_w, y, emb, Bpack,
                                                    Apack, G, embedded);
    } else {
        k_G<<<dim3(18), dim3(256), 0, stream>>>(Uf, conv_Q_w, G);
        k_prepA<<<dim3((NS * DA * 32 + 255) / 256), dim3(256), 0, stream>>>(
            conv_Ua_w, Apack);
        k_emb<<<dim3(64), dim3(256), 0, stream>>>(y, emb, embedded);
    }
    k_gih1<<<dim3(384), dim3(256), 0, stream>>>(embedded, pre_hidden, W_ih1,
                                                W_hh1, b_ih1, b_hh1, gi, gh);
    k_gru<<<dim3(64), dim3(256), 0, stream>>>(gi, gh, pre_hidden, y_mask, s_hat);
    k_rows256<<<dim3(128), dim3(256), 0, stream>>>(s_hat, Wa, conv_Ua_b, Uf_b,
                                                   rbias, 512);
    if (fast) {
        k_att3<<<dim3(6, 2, 64), dim3(512), 0, stream>>>(
            Apack, Bpack, G, rbias, va, alpha_past, alq);
    } else {
        // fallback: write half 0, zero half 1
        hipMemsetAsync(alq + 49152, 0, (size_t)49152 * sizeof(float), stream);
        k_att_lds<<<dim3(12, 64), dim3(256), 0, stream>>>(
            Apack, context, G, rbias, va, alpha_past, alq);
    }
    k_ctsm<<<dim3(6, 64), dim3(256), 0, stream>>>(context, alq, ctv, alpha_out);
    k_gih2<<<dim3(384), dim3(256), 0, stream>>>(ctv, s_hat, W_ih2, W_hh2, b_ih2,
                                                b_hh2, gi, gh);
    k_gru<<<dim3(64), dim3(256), 0, stream>>>(gi, gh, s_hat, y_mask, s_out);
    k_logit<<<dim3(64), dim3(256), 0, stream>>>(ctv, s_out, embedded, Wct, Wht,
                                                Wct_b, Wht_b, lg);
    k_head<<<dim3(32), dim3(256), 0, stream>>>(lg, W0, W0_b, out);
}

// Round 17
// 226.366 us; speedup vs baseline: 1.3448x; 1.0331x over previous
//
#include <hip/hip_runtime.h>
#include <hip/hip_bf16.h>
#include <math.h>

#define BB 64
#define KV 128
#define ME 256
#define NH 256
#define DC 684
#define DA 512
#define MC 256
#define HH_ 16
#define WW_ 48
#define HW_ 768
#define NS 22   // K-steps of 32 (684 -> 704 padded)

typedef __attribute__((ext_vector_type(8))) short bf16x8;
typedef __attribute__((ext_vector_type(4))) float f32x4;

// workspace layout (floats)
#define WS_G     0                    // 512*9
#define WS_RB    (WS_G + 4608)        // rowbias 64*512
#define WS_EMB   (WS_RB + 32768)      // 64*256
#define WS_SH    (WS_EMB + 16384)     // 64*256 s_hat
#define WS_AL    (WS_SH + 16384)      // 64*768 alpha logits (fallback)
#define WS_CT    (WS_AL + 49152)      // 64*684 ct
#define WS_APACK (WS_CT + 43776)      // 22*512*32 bf16 = 180224 floats
#define WS_GI    (WS_APACK + 180224)  // 64*768
#define WS_GH    (WS_GI + 49152)      // 64*768
#define WS_LG    WS_GI                // logit 64*256 reuses GI after gru2
#define WS_BP    (WS_GH + 49152)      // = 441600; Bpack 64*12*22*2048 bf16
#define WS_ALQ   (WS_BP + 17301504)   // 2 x 64*768 alpha-logit halves
#define NEED_BYTES ((size_t)(441600 + 17301504 + 98304) * 4)

static __device__ __forceinline__ unsigned short f2b(float v) {
    __hip_bfloat16 h = __float2bfloat16(v);
    return *reinterpret_cast<unsigned short*>(&h);
}

// async global->LDS, 16B per lane. LDS base must be wave-uniform; HW adds
// lane*16. Global address is per-lane.
static __device__ __forceinline__ void gl_lds16(const unsigned short* g,
                                                unsigned short* l) {
    __builtin_amdgcn_global_load_lds(
        (const __attribute__((address_space(1))) unsigned int*)g,
        (__attribute__((address_space(3))) unsigned int*)l, 16, 0, 0);
}

// =================== fused prep ============================================
// Ts stride 362 shorts (181 dwords, 181%32=21 odd -> all 32 banks; the old
// 360 stride was 20 mod 32 -> 8-way conflict on phase-1 writes).
#define TSS 362
__global__ __launch_bounds__(512) void k_prep(
    const float* __restrict__ ctx, const float* __restrict__ Ua,
    const float* __restrict__ Uf, const float* __restrict__ convQ,
    const int* __restrict__ y, const float* __restrict__ emb,
    unsigned short* __restrict__ Bpack, unsigned short* __restrict__ Apack,
    float* __restrict__ G, float* __restrict__ embedded) {
    __shared__ unsigned short Ts[64 * TSS];  // 45.25 KB
    int bx = blockIdx.x, t = threadIdx.x;
    if (bx < 768) {
        int b = bx / 12, pt = bx % 12, p0 = pt * 64;
        int w = t >> 6, p = t & 63;  // 8 waves, lane = p
        unsigned short* dst = Bpack + (long)(b * 12 + pt) * 22 * 2048;
        for (int ch = 0; ch < 2; ch++) {
            int dbase = ch * 352;
            if (ch) __syncthreads();
#pragma unroll
            for (int iter = 0; iter < 11; iter++) {
                int d0 = dbase + iter * 32 + w * 4;
                float v0 = 0.f, v1 = 0.f, v2 = 0.f, v3 = 0.f;
                const float* src = ctx + ((long)b * DC + d0) * HW_ + p0 + p;
                if (d0 + 0 < DC) v0 = src[0];
                if (d0 + 1 < DC) v1 = src[HW_];
                if (d0 + 2 < DC) v2 = src[2 * HW_];
                if (d0 + 3 < DC) v3 = src[3 * HW_];
                unsigned u01 = (unsigned)f2b(v0) | ((unsigned)f2b(v1) << 16);
                unsigned u23 = (unsigned)f2b(v2) | ((unsigned)f2b(v3) << 16);
                *(uint2*)&Ts[p * TSS + (d0 - dbase)] = make_uint2(u01, u23);
            }
            __syncthreads();
            int so = t >> 8;
            int tt = t & 255;
            int pp = tt >> 2, slot = tt & 3;
#pragma unroll
            for (int s2 = 0; s2 < 12; s2 += 2) {
                int sl = s2 + so;
                if (sl < 11) {
                    int s = ch * 11 + sl;
                    bf16x8 v = *(const bf16x8*)&Ts[pp * TSS + sl * 32 +
                                                   ((slot ^ ((pp >> 1) & 3))
                                                    << 3)];
                    *(bf16x8*)(dst + (long)(s * 256 + tt) * 8) = v;
                }
            }
        }
    } else if (bx < 856) {
        int bi = bx - 768;
#pragma unroll
        for (int r = 0; r < 8; r++) {
            int idx = bi * 4096 + r * 512 + t;
            int e = idx & 7, slot = (idx >> 3) & 3;
            int a = (idx >> 5) & 511, s = idx >> 14;
            int d = s * 32 + ((slot ^ ((a >> 1) & 3)) << 3) + e;
            float v = (d < DC) ? Ua[a * DC + d] : 0.f;
            Apack[idx] = f2b(v);
        }
    } else if (bx < 865) {
        int idx = (bx - 856) * 512 + t;
        if (idx < DA * 9) {
            int a = idx / 9, k = idx % 9;
            float s = 0.f;
            for (int m = 0; m < MC; m++) s += Uf[a * MC + m] * convQ[m * 9 + k];
            G[idx] = s;
        }
    } else {
        int b = bx - 865;
        if (t < ME) embedded[b * ME + t] = emb[y[b] * ME + t];
    }
}

// =================== fallback-path prep kernels ============================
__global__ __launch_bounds__(256) void k_G(const float* __restrict__ Uf,
                                           const float* __restrict__ convQ,
                                           float* __restrict__ G) {
    int idx = blockIdx.x * 256 + threadIdx.x;
    if (idx >= DA * 9) return;
    int a = idx / 9, k = idx % 9;
    float s = 0.f;
    for (int m = 0; m < MC; m++) s += Uf[a * MC + m] * convQ[m * 9 + k];
    G[idx] = s;
}

__global__ __launch_bounds__(256) void k_prepA(const float* __restrict__ Ua,
                                               unsigned short* __restrict__ Apack) {
    int idx = blockIdx.x * 256 + threadIdx.x;
    if (idx >= NS * DA * 32) return;
    int e = idx & 7, slot = (idx >> 3) & 3;
    int a = (idx >> 5) & 511, s = idx >> 14;
    int d = s * 32 + ((slot ^ ((a >> 1) & 3)) << 3) + e;
    float v = (d < DC) ? Ua[a * DC + d] : 0.f;
    Apack[idx] = f2b(v);
}

__global__ __launch_bounds__(256) void k_emb(const int* __restrict__ y,
                                             const float* __restrict__ emb,
                                             float* __restrict__ embedded) {
    int b = blockIdx.x, t = threadIdx.x;
    embedded[b * ME + t] = emb[y[b] * ME + t];
}

// ------- generic rows-of-W kernel, K=256 -----------------------------------
__global__ __launch_bounds__(256) void k_rows256(
    const float* __restrict__ X, const float* __restrict__ W,
    const float* __restrict__ bias, const float* __restrict__ bias2,
    float* __restrict__ out, int outStride) {
    __shared__ float Xs[64 * 257];
    __shared__ float Ws[4 * 260];
    int t = threadIdx.x, w = t >> 6, lane = t & 63;
    for (int i = t; i < 64 * 256; i += 256) {
        int bb = i >> 8, k = i & 255;
        Xs[bb * 257 + k] = X[bb * 256 + k];
    }
    int r = blockIdx.x * 4 + w;
    *(f32x4*)(Ws + w * 260 + lane * 4) = *(const f32x4*)(W + r * 256 + lane * 4);
    __syncthreads();
    const float* xrow = Xs + lane * 257;
    const float* wrow = Ws + w * 260;
    float acc = 0.f;
#pragma unroll 8
    for (int k = 0; k < 256; k++) acc += wrow[k] * xrow[k];
    acc += bias[r];
    if (bias2) acc += bias2[r];
    out[lane * outStride + r] = acc;
}

// ------- fused GRU1 gate GEMVs ---------------------------------------------
__global__ __launch_bounds__(256) void k_gih1(
    const float* __restrict__ embedded, const float* __restrict__ pre_hidden,
    const float* __restrict__ W_ih1, const float* __restrict__ W_hh1,
    const float* __restrict__ b_ih1, const float* __restrict__ b_hh1,
    float* __restrict__ gi, float* __restrict__ gh) {
    __shared__ float Xs[64 * 257];
    __shared__ float Ws[4 * 260];
    int bx = blockIdx.x, t = threadIdx.x, w = t >> 6, lane = t & 63;
    const float *X, *W, *bias;
    float* outp;
    int r;
    if (bx < 192) {
        X = embedded; W = W_ih1; bias = b_ih1; outp = gi; r = bx * 4 + w;
    } else {
        X = pre_hidden; W = W_hh1; bias = b_hh1; outp = gh; r = (bx - 192) * 4 + w;
    }
    for (int i = t; i < 64 * 256; i += 256) {
        int bb = i >> 8, k = i & 255;
        Xs[bb * 257 + k] = X[bb * 256 + k];
    }
    *(f32x4*)(Ws + w * 260 + lane * 4) = *(const f32x4*)(W + r * 256 + lane * 4);
    __syncthreads();
    const float* xrow = Xs + lane * 257;
    const float* wrow = Ws + w * 260;
    float acc = 0.f;
#pragma unroll 8
    for (int k = 0; k < 256; k++) acc += wrow[k] * xrow[k];
    outp[lane * 768 + r] = acc + bias[r];
}

// ------- fused GRU2 gate GEMVs ---------------------------------------------
__global__ __launch_bounds__(256) void k_gih2(
    const float* __restrict__ ctv, const float* __restrict__ s_hat,
    const float* __restrict__ W_ih2, const float* __restrict__ W_hh2,
    const float* __restrict__ b_ih2, const float* __restrict__ b_hh2,
    float* __restrict__ gi, float* __restrict__ gh) {
    __shared__ float Xs[64 * 257];
    __shared__ float Ws[4 * 260];
    int bx = blockIdx.x, t = threadIdx.x, w = t >> 6, lane = t & 63;
    if (bx < 192) {
        int r = bx * 4 + w;
        float acc = 0.f;
        for (int c = 0; c < 3; c++) {
            int c0 = c * 228;
            __syncthreads();
            for (int i = t; i < 64 * 228; i += 256) {
                int bb = i / 228, kk = i - bb * 228;
                Xs[bb * 229 + kk] = ctv[bb * DC + c0 + kk];
            }
            for (int j = lane; j < 228; j += 64)
                Ws[w * 260 + j] = W_ih2[r * DC + c0 + j];
            __syncthreads();
            const float* xrow = Xs + lane * 229;
            const float* wrow = Ws + w * 260;
#pragma unroll 4
            for (int k = 0; k < 228; k++) acc += wrow[k] * xrow[k];
        }
        gi[lane * 768 + r] = acc + b_ih2[r];
    } else {
        int r = (bx - 192) * 4 + w;
        for (int i = t; i < 64 * 256; i += 256) {
            int bb = i >> 8, k = i & 255;
            Xs[bb * 257 + k] = s_hat[bb * 256 + k];
        }
        *(f32x4*)(Ws + w * 260 + lane * 4) =
            *(const f32x4*)(W_hh2 + r * 256 + lane * 4);
        __syncthreads();
        const float* xrow = Xs + lane * 257;
        const float* wrow = Ws + w * 260;
        float acc = 0.f;
#pragma unroll 8
        for (int k = 0; k < 256; k++) acc += wrow[k] * xrow[k];
        gh[lane * 768 + r] = acc + b_hh2[r];
    }
}

// ---------------- GRU elementwise ------------------------------------------
__global__ __launch_bounds__(256) void k_gru(const float* __restrict__ gi,
                                             const float* __restrict__ gh,
                                             const float* __restrict__ h,
                                             const float* __restrict__ y_mask,
                                             float* __restrict__ outp) {
    int b = blockIdx.x, t = threadIdx.x;
    float hv = h[b * NH + t];
    float r = 1.f / (1.f + expf(-(gi[b * 768 + t] + gh[b * 768 + t])));
    float z = 1.f / (1.f + expf(-(gi[b * 768 + 256 + t] + gh[b * 768 + 256 + t])));
    float n = tanhf(gi[b * 768 + 512 + t] + r * gh[b * 768 + 512 + t]);
    float sv = (1.f - z) * n + z * hv;
    float m = y_mask[b];
    outp[b * NH + t] = m * sv + (1.f - m) * hv;
}

// ======= K2 fast: single-barrier triple-buffer pipeline ====================
// R16 post-mortem: two barriers/step serialize 16 waves twice per step;
// sync is the marginal cost. With 3 buffers + stage distance 2 the second
// barrier is redundant: reads of buf[(s-1)%3] complete before barrier(s)
// (MFMA consumes via lgkmcnt); the overwrite (STAGE(s+2)) is issued after
// barrier(s). Cross-wave staging visibility: each wave's vmcnt(3) before
// barrier(s+1) retires its STAGE(s+1) loads; readers read after that
// barrier. Loop = { vmcnt(3); barrier; body; stage } - ONE barrier/step.
__global__ __launch_bounds__(512) void k_att3(
    const unsigned short* __restrict__ Apack,
    const unsigned short* __restrict__ Bpack, const float* __restrict__ G,
    const float* __restrict__ rb, const float* __restrict__ va,
    const float* __restrict__ apast, float* __restrict__ alq) {
    __shared__ __attribute__((aligned(16))) unsigned short lsA[3][8192];
    __shared__ __attribute__((aligned(16))) unsigned short lsB[3][4096];
    __shared__ float ap_s[18 * 50];
    __shared__ float part_s[8][64];
    int pt2 = blockIdx.x, ah = blockIdx.y, b = blockIdx.z;
    int t = threadIdx.x, w = t >> 6, lane = t & 63;
    int l15 = lane & 15, lg = lane >> 4;
    int aw = w & 3, pw = w >> 2;
    int sx = lg ^ ((l15 >> 1) & 3);  // swizzled k-slot for ds_read

    for (int idx = t; idx < 900; idx += 512) {
        int hh = idx / 50, ww = idx % 50;
        float v = 0.f;
        if (hh >= 1 && hh <= HH_ && ww >= 1 && ww <= WW_)
            v = apast[b * HW_ + (hh - 1) * WW_ + (ww - 1)];
        ap_s[idx] = v;
    }
    __syncthreads();  // full drain before pipeline starts

    const unsigned short* Ap0 = Apack + ah * 8192 + w * 1024 + lane * 8;
    const unsigned short* Bp0 =
        Bpack + (long)(b * 12 + pt2 * 2 + (w >> 2)) * 22 * 2048 +
        (w & 3) * 512 + lane * 8;

#define STAGE(S, BUF)                                                        \
    do {                                                                     \
        _Pragma("unroll") for (int i_ = 0; i_ < 2; i_++)                     \
            gl_lds16(Ap0 + (long)(S)*16384 + i_ * 512,                       \
                     &lsA[BUF][w * 1024 + i_ * 512]);                        \
        gl_lds16(Bp0 + (long)(S)*2048, &lsB[BUF][w * 512]);                  \
    } while (0)

#define STEP_BODY(CUR)                                                       \
    do {                                                                     \
        const unsigned short* pA_ = &lsA[0][0] + (CUR)*8192;                 \
        const unsigned short* pB_ = &lsB[0][0] + (CUR)*4096;                 \
        bf16x8 af[4], bf[4];                                                 \
        _Pragma("unroll") for (int i = 0; i < 4; i++)                        \
            af[i] = *(const bf16x8*)&pA_[(aw * 64 + i * 16 + l15) * 32 +     \
                                         sx * 8];                            \
        _Pragma("unroll") for (int j = 0; j < 4; j++)                        \
            bf[j] = *(const bf16x8*)&pB_[pw * 2048 +                         \
                                         (j * 16 + l15) * 32 + sx * 8];     \
        _Pragma("unroll") for (int i = 0; i < 4; i++)                        \
            _Pragma("unroll") for (int j = 0; j < 4; j++)                    \
                acc[i][j] = __builtin_amdgcn_mfma_f32_16x16x32_bf16(         \
                    af[i], bf[j], acc[i][j], 0, 0, 0);                       \
    } while (0)

    f32x4 acc[4][4];
#pragma unroll
    for (int i = 0; i < 4; i++)
#pragma unroll
        for (int j = 0; j < 4; j++) acc[i][j] = {0.f, 0.f, 0.f, 0.f};

    STAGE(0, 0);
    STAGE(1, 1);

    // steps 0 .. NS-2: wait STAGE(s) done (allow STAGE(s+1)'s 3 in flight)
    int cur = 0;
    for (int s = 0; s < NS - 1; s++) {
        asm volatile("s_waitcnt vmcnt(3)" ::: "memory");
        __builtin_amdgcn_sched_barrier(0);
        __builtin_amdgcn_s_barrier();
        __builtin_amdgcn_sched_barrier(0);
        STEP_BODY(cur);
        if (s + 2 < NS) STAGE(s + 2, (s + 2) % 3);
        cur = (cur == 2) ? 0 : cur + 1;
    }
    // last step
    asm volatile("s_waitcnt vmcnt(0)" ::: "memory");
    __builtin_amdgcn_sched_barrier(0);
    __builtin_amdgcn_s_barrier();
    __builtin_amdgcn_sched_barrier(0);
    STEP_BODY(cur);
#undef STAGE
#undef STEP_BODY

    // epilogue: + rowbias + 9-tap coverage, tanh, dot with va, reduce over a
    float partial[4] = {0.f, 0.f, 0.f, 0.f};
#pragma unroll
    for (int i = 0; i < 4; i++) {
#pragma unroll
        for (int r = 0; r < 4; r++) {
            int a = ah * 256 + aw * 64 + i * 16 + lg * 4 + r;
            float rbv = rb[b * DA + a];
            float vav = va[a];
            const float* Ga = G + a * 9;
            float g0 = Ga[0], g1 = Ga[1], g2 = Ga[2], g3 = Ga[3], g4 = Ga[4];
            float g5 = Ga[5], g6 = Ga[6], g7 = Ga[7], g8 = Ga[8];
#pragma unroll
            for (int j = 0; j < 4; j++) {
                int p = pt2 * 128 + pw * 64 + j * 16 + l15;
                int hh = p / WW_, ww = p % WW_;
                const float* ap = ap_s + hh * 50 + ww;
                float cov = g0 * ap[0] + g1 * ap[1] + g2 * ap[2] +
                            g3 * ap[50] + g4 * ap[51] + g5 * ap[52] +
                            g6 * ap[100] + g7 * ap[101] + g8 * ap[102];
                float e = tanhf(acc[i][j][r] + rbv + cov);
                partial[j] += vav * e;
            }
        }
    }
#pragma unroll
    for (int j = 0; j < 4; j++) {
        partial[j] += __shfl_xor(partial[j], 16);
        partial[j] += __shfl_xor(partial[j], 32);
    }
    if (lane < 16) {
#pragma unroll
        for (int j = 0; j < 4; j++) part_s[w][j * 16 + lane] = partial[j];
    }
    __syncthreads();
    if (t < 128) {
        int pg = t >> 6, pl = t & 63;
        float sum = (part_s[pg * 4 + 0][pl] + part_s[pg * 4 + 1][pl]) +
                    (part_s[pg * 4 + 2][pl] + part_s[pg * 4 + 3][pl]);
        alq[ah * 49152 + b * HW_ + pt2 * 128 + t] = sum;
    }
}

// ======= K2 fallback: LDS-staging version (Apack slot-swizzle aware) =======
#define LDW 40
__global__ __launch_bounds__(256) void k_att_lds(
    const unsigned short* __restrict__ Apack, const float* __restrict__ ctx,
    const float* __restrict__ G, const float* __restrict__ rb,
    const float* __restrict__ va, const float* __restrict__ apast,
    float* __restrict__ alogit) {
    __shared__ __attribute__((aligned(16))) short lsB[2][64 * LDW];
    __shared__ float ap_s[18 * 50];
    __shared__ float part_s[4 * 64];
    int b = blockIdx.y;
    int p0 = blockIdx.x * 64;
    int t = threadIdx.x;
    int w = t >> 6, lane = t & 63;
    int l15 = lane & 15, lg = lane >> 4;
    int sxA = lg ^ ((l15 >> 1) & 3);
    int pq = t & 15, kp = t >> 4;
    const float* ctx_b = ctx + (long)b * DC * HW_ + p0;

    for (int idx = t; idx < 900; idx += 256) {
        int hh = idx / 50, ww = idx % 50;
        float v = 0.f;
        if (hh >= 1 && hh <= HH_ && ww >= 1 && ww <= WW_)
            v = apast[b * HW_ + (hh - 1) * WW_ + (ww - 1)];
        ap_s[idx] = v;
    }

#define CTXLOAD(FA, FB, S)                                                   \
    do {                                                                     \
        int d_ = (S) * 32 + 2 * kp;                                          \
        const float* s0_ = ctx_b + (long)d_ * HW_ + pq;                      \
        bool g0_ = d_ < DC, g1_ = (d_ + 1) < DC;                             \
        _Pragma("unroll") for (int j_ = 0; j_ < 4; j_++) {                   \
            FA[j_] = g0_ ? s0_[16 * j_] : 0.f;                               \
            FB[j_] = g1_ ? s0_[HW_ + 16 * j_] : 0.f;                         \
        }                                                                    \
    } while (0)
#define STAGEW(FA, FB, BUF)                                                  \
    do {                                                                     \
        _Pragma("unroll") for (int j_ = 0; j_ < 4; j_++) {                   \
            ((unsigned*)lsB[BUF])[(pq + 16 * j_) * (LDW / 2) + kp] =         \
                (unsigned)f2b(FA[j_]) | ((unsigned)f2b(FB[j_]) << 16);       \
        }                                                                    \
    } while (0)
#define ALOAD(AF, S)                                                         \
    do {                                                                     \
        _Pragma("unroll") for (int i_ = 0; i_ < 8; i_++)                     \
            AF[i_] = *(const bf16x8*)(Apack +                                \
                ((long)((S)*512 + w * 128 + i_ * 16 + l15) * 4 + sxA) * 8);  \
    } while (0)
#define BREAD(BF, BUF)                                                       \
    do {                                                                     \
        _Pragma("unroll") for (int j_ = 0; j_ < 4; j_++)                     \
            BF[j_] = *(const bf16x8*)(&lsB[BUF][(j_ * 16 + l15) * LDW +      \
                                               lg * 8]);                     \
    } while (0)
#define MFMA8x4(AF, BF)                                                      \
    do {                                                                     \
        _Pragma("unroll") for (int i_ = 0; i_ < 8; i_++)                     \
            _Pragma("unroll") for (int j_ = 0; j_ < 4; j_++)                 \
                acc[i_][j_] = __builtin_amdgcn_mfma_f32_16x16x32_bf16(       \
                    AF[i_], BF[j_], acc[i_][j_], 0, 0, 0);                   \
    } while (0)

    f32x4 acc[8][4];
#pragma unroll
    for (int i = 0; i < 8; i++)
#pragma unroll
        for (int j = 0; j < 4; j++) acc[i][j] = {0.f, 0.f, 0.f, 0.f};

    float fa0[4], fb0[4], fa1[4], fb1[4];
    bf16x8 afr0[8], afr1[8], bfr[4];

    CTXLOAD(fa1, fb1, 0);
    ALOAD(afr0, 0);
    STAGEW(fa1, fb1, 0);
    CTXLOAD(fa1, fb1, 1);
    __syncthreads();

    for (int ss = 0; ss < NS; ss += 2) {
        if (ss + 2 < NS) CTXLOAD(fa0, fb0, ss + 2);
        ALOAD(afr1, ss + 1);
        BREAD(bfr, 0);
        STAGEW(fa1, fb1, 1);
        MFMA8x4(afr0, bfr);
        __syncthreads();
        if (ss + 3 < NS) CTXLOAD(fa1, fb1, ss + 3);
        if (ss + 2 < NS) {
            ALOAD(afr0, ss + 2);
            BREAD(bfr, 1);
            STAGEW(fa0, fb0, 0);
            MFMA8x4(afr1, bfr);
        } else {
            BREAD(bfr, 1);
            MFMA8x4(afr1, bfr);
        }
        __syncthreads();
    }

    float partial[4] = {0.f, 0.f, 0.f, 0.f};
#pragma unroll
    for (int i = 0; i < 8; i++) {
#pragma unroll
        for (int r = 0; r < 4; r++) {
            int a = w * 128 + i * 16 + lg * 4 + r;
            float rbv = rb[b * DA + a];
            float vav = va[a];
            const float* Ga = G + a * 9;
            float g0 = Ga[0], g1 = Ga[1], g2 = Ga[2], g3 = Ga[3], g4 = Ga[4];
            float g5 = Ga[5], g6 = Ga[6], g7 = Ga[7], g8 = Ga[8];
#pragma unroll
            for (int j = 0; j < 4; j++) {
                int p = p0 + j * 16 + l15;
                int hh = p / WW_, ww = p % WW_;
                const float* ap = ap_s + hh * 50 + ww;
                float cov = g0 * ap[0] + g1 * ap[1] + g2 * ap[2] +
                            g3 * ap[50] + g4 * ap[51] + g5 * ap[52] +
                            g6 * ap[100] + g7 * ap[101] + g8 * ap[102];
                float e = tanhf(acc[i][j][r] + rbv + cov);
                partial[j] += vav * e;
            }
        }
    }
#pragma unroll
    for (int j = 0; j < 4; j++) {
        partial[j] += __shfl_xor(partial[j], 16);
        partial[j] += __shfl_xor(partial[j], 32);
    }
    if (lane < 16) {
#pragma unroll
        for (int j = 0; j < 4; j++) part_s[w * 64 + j * 16 + lane] = partial[j];
    }
    __syncthreads();
    if (t < 64) {
        float s = part_s[t] + part_s[64 + t] + part_s[128 + t] +
                  part_s[192 + t];
        alogit[b * HW_ + p0 + t] = s;
    }
}

// ---------------- K3+K4 fused: (sum halves) + softmax + ct -----------------
__global__ __launch_bounds__(256) void k_ctsm(const float* __restrict__ ctx,
                                              const float* __restrict__ alq,
                                              float* __restrict__ ct,
                                              float* __restrict__ alpha_out) {
    __shared__ float al_s[HW_];
    __shared__ float red[16];
    int b = blockIdx.y, t = threadIdx.x;
    float v[3];
    float mx = -1e30f;
    for (int i = 0; i < 3; i++) {
        int idx = b * HW_ + i * 256 + t;
        v[i] = alq[idx] + alq[49152 + idx];
        mx = fmaxf(mx, v[i]);
    }
    for (int off = 32; off > 0; off >>= 1) mx = fmaxf(mx, __shfl_down(mx, off));
    if ((t & 63) == 0) red[t >> 6] = mx;
    __syncthreads();
    if (t == 0) red[0] = fmaxf(fmaxf(red[0], red[1]), fmaxf(red[2], red[3]));
    __syncthreads();
    mx = red[0];
    float sum = 0.f;
    for (int i = 0; i < 3; i++) {
        v[i] = expf(v[i] - mx);
        sum += v[i];
    }
    for (int off = 32; off > 0; off >>= 1) sum += __shfl_down(sum, off);
    if ((t & 63) == 0) red[8 + (t >> 6)] = sum;
    __syncthreads();
    if (t == 0) red[8] = red[8] + red[9] + red[10] + red[11];
    __syncthreads();
    float inv = 1.f / red[8];
    for (int i = 0; i < 3; i++) {
        float a = v[i] * inv;
        al_s[i * 256 + t] = a;
        if (blockIdx.x == 0) alpha_out[b * HW_ + i * 256 + t] = a;
    }
    __syncthreads();
    int dc0 = blockIdx.x * 114;
    int wave = t >> 6, lane = t & 63;
    for (int d = dc0 + wave; d < dc0 + 114; d += 4) {
        const float* row = &ctx[((long)b * DC + d) * HW_];
        float s = 0.f;
#pragma unroll
        for (int q = 0; q < 12; q++) s += row[lane + q * 64] * al_s[lane + q * 64];
        for (int off = 32; off > 0; off >>= 1) s += __shfl_down(s, off);
        if (lane == 0) ct[b * DC + d] = s;
    }
}

// ---------------- K5: logit rows -------------------------------------------
__global__ __launch_bounds__(256) void k_logit(
    const float* __restrict__ ctv, const float* __restrict__ s,
    const float* __restrict__ embedded, const float* __restrict__ Wct,
    const float* __restrict__ Wht, const float* __restrict__ Wct_b,
    const float* __restrict__ Wht_b, float* __restrict__ lg) {
    __shared__ float Xs[64 * 257];
    __shared__ float Ws[4 * 232];
    int t = threadIdx.x, w = t >> 6, lane = t & 63;
    int r = blockIdx.x * 4 + w;
    float acc = 0.f;
    for (int c = 0; c < 3; c++) {
        int c0 = c * 228;
        __syncthreads();
        for (int i = t; i < 64 * 228; i += 256) {
            int bb = i / 228, kk = i - bb * 228;
            Xs[bb * 229 + kk] = ctv[bb * DC + c0 + kk];
        }
        for (int j = lane; j < 228; j += 64) Ws[w * 232 + j] = Wct[r * DC + c0 + j];
        __syncthreads();
        const float* xrow = Xs + lane * 229;
        const float* wrow = Ws + w * 232;
#pragma unroll 4
        for (int k = 0; k < 228; k++) acc += wrow[k] * xrow[k];
    }
    __syncthreads();
    for (int i = t; i < 64 * 256; i += 256) {
        int bb = i >> 8, k = i & 255;
        Xs[bb * 257 + k] = s[bb * 256 + k];
    }
    __syncthreads();
    const float* xrow2 = Xs + lane * 257;
    const float* wr = Wht + r * 256;
    float acc2 = 0.f;
#pragma unroll 8
    for (int k = 0; k < 256; k++) acc2 += wr[k] * xrow2[k];
    lg[lane * 256 + r] = acc + acc2 + Wct_b[r] + Wht_b[r] + embedded[lane * 256 + r];
}

// ---------------- K6: maxout + W0 head -------------------------------------
__global__ __launch_bounds__(256) void k_head(const float* __restrict__ lg,
                                              const float* __restrict__ W0,
                                              const float* __restrict__ W0_b,
                                              float* __restrict__ out) {
    __shared__ float Xs[64 * 129];
    __shared__ float Ws[4 * 132];
    int t = threadIdx.x, w = t >> 6, lane = t & 63;
    for (int i = t; i < 64 * 128; i += 256) {
        int bb = i >> 7, m = i & 127;
        Xs[bb * 129 + m] = fmaxf(lg[bb * 256 + 2 * m], lg[bb * 256 + 2 * m + 1]);
    }
    int r = blockIdx.x * 4 + w;
    Ws[w * 132 + lane] = W0[r * 128 + lane];
    Ws[w * 132 + 64 + lane] = W0[r * 128 + 64 + lane];
    __syncthreads();
    const float* xrow = Xs + lane * 129;
    const float* wrow = Ws + w * 132;
    float acc = 0.f;
#pragma unroll 8
    for (int k = 0; k < 128; k++) acc += wrow[k] * xrow[k];
    out[lane * KV + r] = acc + W0_b[r];
}

extern "C" void kernel_launch(void* const* d_in, const int* in_sizes, int n_in,
                              void* d_out, int out_size, void* d_ws,
                              size_t ws_size, hipStream_t stream) {
    const int* y = (const int*)d_in[0];
    const float* y_mask = (const float*)d_in[1];
    const float* context = (const float*)d_in[2];
    const float* pre_hidden = (const float*)d_in[3];
    const float* alpha_past = (const float*)d_in[4];
    const float* emb = (const float*)d_in[5];
    const float* W_ih1 = (const float*)d_in[6];
    const float* W_hh1 = (const float*)d_in[7];
    const float* b_ih1 = (const float*)d_in[8];
    const float* b_hh1 = (const float*)d_in[9];
    const float* conv_Ua_w = (const float*)d_in[10];
    const float* conv_Ua_b = (const float*)d_in[11];
    const float* Wa = (const float*)d_in[12];
    const float* conv_Q_w = (const float*)d_in[13];
    const float* Uf = (const float*)d_in[14];
    const float* Uf_b = (const float*)d_in[15];
    const float* va = (const float*)d_in[16];
    const float* va_b = (const float*)d_in[17];
    const float* W_ih2 = (const float*)d_in[18];
    const float* W_hh2 = (const float*)d_in[19];
    const float* b_ih2 = (const float*)d_in[20];
    const float* b_hh2 = (const float*)d_in[21];
    const float* Wct = (const float*)d_in[22];
    const float* Wct_b = (const float*)d_in[23];
    const float* Wht = (const float*)d_in[24];
    const float* Wht_b = (const float*)d_in[25];
    const float* W0 = (const float*)d_in[26];
    const float* W0_b = (const float*)d_in[27];

    float* ws = (float*)d_ws;
    float* out = (float*)d_out;
    float* G = ws + WS_G;
    float* rbias = ws + WS_RB;
    float* embedded = ws + WS_EMB;
    float* s_hat = ws + WS_SH;
    float* ctv = ws + WS_CT;
    unsigned short* Apack = (unsigned short*)(ws + WS_APACK);
    float* gi = ws + WS_GI;
    float* gh = ws + WS_GH;
    float* lg = ws + WS_LG;
    unsigned short* Bpack = (unsigned short*)(ws + WS_BP);
    float* alq = ws + WS_ALQ;
    float* s_out = out + 8192;
    float* alpha_out = out + 24576;

    bool fast = ws_size >= NEED_BYTES;

    if (fast) {
        k_prep<<<dim3(929), dim3(512), 0, stream>>>(context, conv_Ua_w, Uf,
                                                    conv_Q_w, y, emb, Bpack,
                                                    Apack, G, embedded);
    } else {
        k_G<<<dim3(18), dim3(256), 0, stream>>>(Uf, conv_Q_w, G);
        k_prepA<<<dim3((NS * DA * 32 + 255) / 256), dim3(256), 0, stream>>>(
            conv_Ua_w, Apack);
        k_emb<<<dim3(64), dim3(256), 0, stream>>>(y, emb, embedded);
    }
    k_gih1<<<dim3(384), dim3(256), 0, stream>>>(embedded, pre_hidden, W_ih1,
                                                W_hh1, b_ih1, b_hh1, gi, gh);
    k_gru<<<dim3(64), dim3(256), 0, stream>>>(gi, gh, pre_hidden, y_mask, s_hat);
    k_rows256<<<dim3(128), dim3(256), 0, stream>>>(s_hat, Wa, conv_Ua_b, Uf_b,
                                                   rbias, 512);
    if (fast) {
        k_att3<<<dim3(6, 2, 64), dim3(512), 0, stream>>>(
            Apack, Bpack, G, rbias, va, alpha_past, alq);
    } else {
        // fallback: write half 0, zero half 1
        hipMemsetAsync(alq + 49152, 0, (size_t)49152 * sizeof(float), stream);
        k_att_lds<<<dim3(12, 64), dim3(256), 0, stream>>>(
            Apack, context, G, rbias, va, alpha_past, alq);
    }
    k_ctsm<<<dim3(6, 64), dim3(256), 0, stream>>>(context, alq, ctv, alpha_out);
    k_gih2<<<dim3(384), dim3(256), 0, stream>>>(ctv, s_hat, W_ih2, W_hh2, b_ih2,
                                                b_hh2, gi, gh);
    k_gru<<<dim3(64), dim3(256), 0, stream>>>(gi, gh, s_hat, y_mask, s_out);
    k_logit<<<dim3(64), dim3(256), 0, stream>>>(ctv, s_out, embedded, Wct, Wht,
                                                Wct_b, Wht_b, lg);
    k_head<<<dim3(32), dim3(256), 0, stream>>>(lg, W0, W0_b, out);
}

// Round 18
// 225.443 us; speedup vs baseline: 1.3504x; 1.0041x over previous
//
#include <hip/hip_runtime.h>
#include <hip/hip_bf16.h>
#include <math.h>

#define BB 64
#define KV 128
#define ME 256
#define NH 256
#define DC 684
#define DA 512
#define MC 256
#define HH_ 16
#define WW_ 48
#define HW_ 768
#define NS 22   // K-steps of 32 (684 -> 704 padded)

typedef __attribute__((ext_vector_type(8))) short bf16x8;
typedef __attribute__((ext_vector_type(4))) float f32x4;

// workspace layout (floats)
#define WS_G     0                    // 512*9
#define WS_RB    (WS_G + 4608)        // rowbias 64*512
#define WS_EMB   (WS_RB + 32768)      // 64*256
#define WS_SH    (WS_EMB + 16384)     // 64*256 s_hat
#define WS_AL    (WS_SH + 16384)      // 64*768 alpha logits (fallback)
#define WS_CT    (WS_AL + 49152)      // 64*684 ct
#define WS_APACK (WS_CT + 43776)      // 22*512*32 bf16 = 180224 floats
#define WS_GI    (WS_APACK + 180224)  // 64*768
#define WS_GH    (WS_GI + 49152)      // 64*768
#define WS_LG    WS_GI                // logit 64*256 reuses GI after gru2
#define WS_BP    (WS_GH + 49152)      // = 441600; Bpack 64*12*22*2048 bf16
#define WS_ALQ   (WS_BP + 17301504)   // 2 x 64*768 alpha-logit halves
#define NEED_BYTES ((size_t)(441600 + 17301504 + 98304) * 4)

static __device__ __forceinline__ unsigned short f2b(float v) {
    __hip_bfloat16 h = __float2bfloat16(v);
    return *reinterpret_cast<unsigned short*>(&h);
}

// async global->LDS, 16B per lane. LDS base must be wave-uniform; HW adds
// lane*16. Global address is per-lane.
static __device__ __forceinline__ void gl_lds16(const unsigned short* g,
                                                unsigned short* l) {
    __builtin_amdgcn_global_load_lds(
        (const __attribute__((address_space(1))) unsigned int*)g,
        (__attribute__((address_space(3))) unsigned int*)l, 16, 0, 0);
}

// =================== fused prep ============================================
// R17 post-mortem: k_prep was latency under-lapped (VALUBusy 4%, dur equal
// for L3-hot replays): serial {44 loads -> barrier -> stores} x2 idles the
// memory pipe during each store phase. Fix: software-pipeline the chunks -
// after barrier 1, issue ALL chunk-1 loads into registers, run phase-2 of
// chunk 0 (load latency hides under it), then convert+write chunk 1.
// Ts stride 362 shorts (181 dwords, odd -> conflict-free phase-1 writes).
#define TSS 362
__global__ __launch_bounds__(512) void k_prep(
    const float* __restrict__ ctx, const float* __restrict__ Ua,
    const float* __restrict__ Uf, const float* __restrict__ convQ,
    const int* __restrict__ y, const float* __restrict__ emb,
    unsigned short* __restrict__ Bpack, unsigned short* __restrict__ Apack,
    float* __restrict__ G, float* __restrict__ embedded) {
    __shared__ unsigned short Ts[64 * TSS];  // 45.25 KB
    int bx = blockIdx.x, t = threadIdx.x;
    if (bx < 768) {
        int b = bx / 12, pt = bx % 12, p0 = pt * 64;
        int w = t >> 6, p = t & 63;  // 8 waves, lane = p
        unsigned short* dst = Bpack + (long)(b * 12 + pt) * 22 * 2048;
        int so = t >> 8;
        int tt = t & 255;
        int pp = tt >> 2, slot = tt & 3;
        int rdoff = pp * TSS + ((slot ^ ((pp >> 1) & 3)) << 3);

        // phase 1, chunk 0 (d in [0,352): all valid, DC=684)
#pragma unroll
        for (int iter = 0; iter < 11; iter++) {
            int d0 = iter * 32 + w * 4;
            const float* src = ctx + ((long)b * DC + d0) * HW_ + p0 + p;
            float v0 = src[0];
            float v1 = src[HW_];
            float v2 = src[2 * HW_];
            float v3 = src[3 * HW_];
            unsigned u01 = (unsigned)f2b(v0) | ((unsigned)f2b(v1) << 16);
            unsigned u23 = (unsigned)f2b(v2) | ((unsigned)f2b(v3) << 16);
            *(uint2*)&Ts[p * TSS + d0] = make_uint2(u01, u23);
        }
        __syncthreads();

        // prefetch chunk 1 into registers (latency hides under phase 2 ch0)
        float pre[44];
#pragma unroll
        for (int iter = 0; iter < 11; iter++) {
            int d0 = 352 + iter * 32 + w * 4;
            const float* src = ctx + ((long)b * DC + d0) * HW_ + p0 + p;
#pragma unroll
            for (int j = 0; j < 4; j++)
                pre[iter * 4 + j] = (d0 + j < DC) ? src[(long)j * HW_] : 0.f;
        }

        // phase 2, chunk 0: steps s = 0..10
#pragma unroll
        for (int s2 = 0; s2 < 12; s2 += 2) {
            int sl = s2 + so;
            if (sl < 11) {
                bf16x8 v = *(const bf16x8*)&Ts[rdoff + sl * 32];
                *(bf16x8*)(dst + (long)(sl * 256 + tt) * 8) = v;
            }
        }
        __syncthreads();

        // write chunk 1 into Ts
#pragma unroll
        for (int iter = 0; iter < 11; iter++) {
            int d0r = iter * 32 + w * 4;
            unsigned u01 = (unsigned)f2b(pre[iter * 4 + 0]) |
                           ((unsigned)f2b(pre[iter * 4 + 1]) << 16);
            unsigned u23 = (unsigned)f2b(pre[iter * 4 + 2]) |
                           ((unsigned)f2b(pre[iter * 4 + 3]) << 16);
            *(uint2*)&Ts[p * TSS + d0r] = make_uint2(u01, u23);
        }
        __syncthreads();

        // phase 2, chunk 1: steps s = 11..21
#pragma unroll
        for (int s2 = 0; s2 < 12; s2 += 2) {
            int sl = s2 + so;
            if (sl < 11) {
                int s = 11 + sl;
                bf16x8 v = *(const bf16x8*)&Ts[rdoff + sl * 32];
                *(bf16x8*)(dst + (long)(s * 256 + tt) * 8) = v;
            }
        }
    } else if (bx < 856) {
        int bi = bx - 768;
#pragma unroll
        for (int r = 0; r < 8; r++) {
            int idx = bi * 4096 + r * 512 + t;
            int e = idx & 7, slot = (idx >> 3) & 3;
            int a = (idx >> 5) & 511, s = idx >> 14;
            int d = s * 32 + ((slot ^ ((a >> 1) & 3)) << 3) + e;
            float v = (d < DC) ? Ua[a * DC + d] : 0.f;
            Apack[idx] = f2b(v);
        }
    } else if (bx < 865) {
        int idx = (bx - 856) * 512 + t;
        if (idx < DA * 9) {
            int a = idx / 9, k = idx % 9;
            float s = 0.f;
            for (int m = 0; m < MC; m++) s += Uf[a * MC + m] * convQ[m * 9 + k];
            G[idx] = s;
        }
    } else {
        int b = bx - 865;
        if (t < ME) embedded[b * ME + t] = emb[y[b] * ME + t];
    }
}

// =================== fallback-path prep kernels ============================
__global__ __launch_bounds__(256) void k_G(const float* __restrict__ Uf,
                                           const float* __restrict__ convQ,
                                           float* __restrict__ G) {
    int idx = blockIdx.x * 256 + threadIdx.x;
    if (idx >= DA * 9) return;
    int a = idx / 9, k = idx % 9;
    float s = 0.f;
    for (int m = 0; m < MC; m++) s += Uf[a * MC + m] * convQ[m * 9 + k];
    G[idx] = s;
}

__global__ __launch_bounds__(256) void k_prepA(const float* __restrict__ Ua,
                                               unsigned short* __restrict__ Apack) {
    int idx = blockIdx.x * 256 + threadIdx.x;
    if (idx >= NS * DA * 32) return;
    int e = idx & 7, slot = (idx >> 3) & 3;
    int a = (idx >> 5) & 511, s = idx >> 14;
    int d = s * 32 + ((slot ^ ((a >> 1) & 3)) << 3) + e;
    float v = (d < DC) ? Ua[a * DC + d] : 0.f;
    Apack[idx] = f2b(v);
}

__global__ __launch_bounds__(256) void k_emb(const int* __restrict__ y,
                                             const float* __restrict__ emb,
                                             float* __restrict__ embedded) {
    int b = blockIdx.x, t = threadIdx.x;
    embedded[b * ME + t] = emb[y[b] * ME + t];
}

// ------- generic rows-of-W kernel, K=256 -----------------------------------
__global__ __launch_bounds__(256) void k_rows256(
    const float* __restrict__ X, const float* __restrict__ W,
    const float* __restrict__ bias, const float* __restrict__ bias2,
    float* __restrict__ out, int outStride) {
    __shared__ float Xs[64 * 257];
    __shared__ float Ws[4 * 260];
    int t = threadIdx.x, w = t >> 6, lane = t & 63;
    for (int i = t; i < 64 * 256; i += 256) {
        int bb = i >> 8, k = i & 255;
        Xs[bb * 257 + k] = X[bb * 256 + k];
    }
    int r = blockIdx.x * 4 + w;
    *(f32x4*)(Ws + w * 260 + lane * 4) = *(const f32x4*)(W + r * 256 + lane * 4);
    __syncthreads();
    const float* xrow = Xs + lane * 257;
    const float* wrow = Ws + w * 260;
    float acc = 0.f;
#pragma unroll 8
    for (int k = 0; k < 256; k++) acc += wrow[k] * xrow[k];
    acc += bias[r];
    if (bias2) acc += bias2[r];
    out[lane * outStride + r] = acc;
}

// ------- fused GRU1 gate GEMVs ---------------------------------------------
__global__ __launch_bounds__(256) void k_gih1(
    const float* __restrict__ embedded, const float* __restrict__ pre_hidden,
    const float* __restrict__ W_ih1, const float* __restrict__ W_hh1,
    const float* __restrict__ b_ih1, const float* __restrict__ b_hh1,
    float* __restrict__ gi, float* __restrict__ gh) {
    __shared__ float Xs[64 * 257];
    __shared__ float Ws[4 * 260];
    int bx = blockIdx.x, t = threadIdx.x, w = t >> 6, lane = t & 63;
    const float *X, *W, *bias;
    float* outp;
    int r;
    if (bx < 192) {
        X = embedded; W = W_ih1; bias = b_ih1; outp = gi; r = bx * 4 + w;
    } else {
        X = pre_hidden; W = W_hh1; bias = b_hh1; outp = gh; r = (bx - 192) * 4 + w;
    }
    for (int i = t; i < 64 * 256; i += 256) {
        int bb = i >> 8, k = i & 255;
        Xs[bb * 257 + k] = X[bb * 256 + k];
    }
    *(f32x4*)(Ws + w * 260 + lane * 4) = *(const f32x4*)(W + r * 256 + lane * 4);
    __syncthreads();
    const float* xrow = Xs + lane * 257;
    const float* wrow = Ws + w * 260;
    float acc = 0.f;
#pragma unroll 8
    for (int k = 0; k < 256; k++) acc += wrow[k] * xrow[k];
    outp[lane * 768 + r] = acc + bias[r];
}

// ------- fused GRU2 gate GEMVs ---------------------------------------------
__global__ __launch_bounds__(256) void k_gih2(
    const float* __restrict__ ctv, const float* __restrict__ s_hat,
    const float* __restrict__ W_ih2, const float* __restrict__ W_hh2,
    const float* __restrict__ b_ih2, const float* __restrict__ b_hh2,
    float* __restrict__ gi, float* __restrict__ gh) {
    __shared__ float Xs[64 * 257];
    __shared__ float Ws[4 * 260];
    int bx = blockIdx.x, t = threadIdx.x, w = t >> 6, lane = t & 63;
    if (bx < 192) {
        int r = bx * 4 + w;
        float acc = 0.f;
        for (int c = 0; c < 3; c++) {
            int c0 = c * 228;
            __syncthreads();
            for (int i = t; i < 64 * 228; i += 256) {
                int bb = i / 228, kk = i - bb * 228;
                Xs[bb * 229 + kk] = ctv[bb * DC + c0 + kk];
            }
            for (int j = lane; j < 228; j += 64)
                Ws[w * 260 + j] = W_ih2[r * DC + c0 + j];
            __syncthreads();
            const float* xrow = Xs + lane * 229;
            const float* wrow = Ws + w * 260;
#pragma unroll 4
            for (int k = 0; k < 228; k++) acc += wrow[k] * xrow[k];
        }
        gi[lane * 768 + r] = acc + b_ih2[r];
    } else {
        int r = (bx - 192) * 4 + w;
        for (int i = t; i < 64 * 256; i += 256) {
            int bb = i >> 8, k = i & 255;
            Xs[bb * 257 + k] = s_hat[bb * 256 + k];
        }
        *(f32x4*)(Ws + w * 260 + lane * 4) =
            *(const f32x4*)(W_hh2 + r * 256 + lane * 4);
        __syncthreads();
        const float* xrow = Xs + lane * 257;
        const float* wrow = Ws + w * 260;
        float acc = 0.f;
#pragma unroll 8
        for (int k = 0; k < 256; k++) acc += wrow[k] * xrow[k];
        gh[lane * 768 + r] = acc + b_hh2[r];
    }
}

// ---------------- GRU elementwise ------------------------------------------
__global__ __launch_bounds__(256) void k_gru(const float* __restrict__ gi,
                                             const float* __restrict__ gh,
                                             const float* __restrict__ h,
                                             const float* __restrict__ y_mask,
                                             float* __restrict__ outp) {
    int b = blockIdx.x, t = threadIdx.x;
    float hv = h[b * NH + t];
    float r = 1.f / (1.f + expf(-(gi[b * 768 + t] + gh[b * 768 + t])));
    float z = 1.f / (1.f + expf(-(gi[b * 768 + 256 + t] + gh[b * 768 + 256 + t])));
    float n = tanhf(gi[b * 768 + 512 + t] + r * gh[b * 768 + 512 + t]);
    float sv = (1.f - z) * n + z * hv;
    float m = y_mask[b];
    outp[b * NH + t] = m * sv + (1.f - m) * hv;
}

// ======= K2 fast: single-barrier triple-buffer pipeline ====================
__global__ __launch_bounds__(512) void k_att3(
    const unsigned short* __restrict__ Apack,
    const unsigned short* __restrict__ Bpack, const float* __restrict__ G,
    const float* __restrict__ rb, const float* __restrict__ va,
    const float* __restrict__ apast, float* __restrict__ alq) {
    __shared__ __attribute__((aligned(16))) unsigned short lsA[3][8192];
    __shared__ __attribute__((aligned(16))) unsigned short lsB[3][4096];
    __shared__ float ap_s[18 * 50];
    __shared__ float part_s[8][64];
    int pt2 = blockIdx.x, ah = blockIdx.y, b = blockIdx.z;
    int t = threadIdx.x, w = t >> 6, lane = t & 63;
    int l15 = lane & 15, lg = lane >> 4;
    int aw = w & 3, pw = w >> 2;
    int sx = lg ^ ((l15 >> 1) & 3);  // swizzled k-slot for ds_read

    for (int idx = t; idx < 900; idx += 512) {
        int hh = idx / 50, ww = idx % 50;
        float v = 0.f;
        if (hh >= 1 && hh <= HH_ && ww >= 1 && ww <= WW_)
            v = apast[b * HW_ + (hh - 1) * WW_ + (ww - 1)];
        ap_s[idx] = v;
    }
    __syncthreads();  // full drain before pipeline starts

    const unsigned short* Ap0 = Apack + ah * 8192 + w * 1024 + lane * 8;
    const unsigned short* Bp0 =
        Bpack + (long)(b * 12 + pt2 * 2 + (w >> 2)) * 22 * 2048 +
        (w & 3) * 512 + lane * 8;

#define STAGE(S, BUF)                                                        \
    do {                                                                     \
        _Pragma("unroll") for (int i_ = 0; i_ < 2; i_++)                     \
            gl_lds16(Ap0 + (long)(S)*16384 + i_ * 512,                       \
                     &lsA[BUF][w * 1024 + i_ * 512]);                        \
        gl_lds16(Bp0 + (long)(S)*2048, &lsB[BUF][w * 512]);                  \
    } while (0)

#define STEP_BODY(CUR)                                                       \
    do {                                                                     \
        const unsigned short* pA_ = &lsA[0][0] + (CUR)*8192;                 \
        const unsigned short* pB_ = &lsB[0][0] + (CUR)*4096;                 \
        bf16x8 af[4], bf[4];                                                 \
        _Pragma("unroll") for (int i = 0; i < 4; i++)                        \
            af[i] = *(const bf16x8*)&pA_[(aw * 64 + i * 16 + l15) * 32 +     \
                                         sx * 8];                            \
        _Pragma("unroll") for (int j = 0; j < 4; j++)                        \
            bf[j] = *(const bf16x8*)&pB_[pw * 2048 +                         \
                                         (j * 16 + l15) * 32 + sx * 8];     \
        _Pragma("unroll") for (int i = 0; i < 4; i++)                        \
            _Pragma("unroll") for (int j = 0; j < 4; j++)                    \
                acc[i][j] = __builtin_amdgcn_mfma_f32_16x16x32_bf16(         \
                    af[i], bf[j], acc[i][j], 0, 0, 0);                       \
    } while (0)

    f32x4 acc[4][4];
#pragma unroll
    for (int i = 0; i < 4; i++)
#pragma unroll
        for (int j = 0; j < 4; j++) acc[i][j] = {0.f, 0.f, 0.f, 0.f};

    STAGE(0, 0);
    STAGE(1, 1);

    // steps 0 .. NS-2: wait STAGE(s) done (allow STAGE(s+1)'s 3 in flight)
    int cur = 0;
    for (int s = 0; s < NS - 1; s++) {
        asm volatile("s_waitcnt vmcnt(3)" ::: "memory");
        __builtin_amdgcn_sched_barrier(0);
        __builtin_amdgcn_s_barrier();
        __builtin_amdgcn_sched_barrier(0);
        STEP_BODY(cur);
        if (s + 2 < NS) STAGE(s + 2, (s + 2) % 3);
        cur = (cur == 2) ? 0 : cur + 1;
    }
    // last step
    asm volatile("s_waitcnt vmcnt(0)" ::: "memory");
    __builtin_amdgcn_sched_barrier(0);
    __builtin_amdgcn_s_barrier();
    __builtin_amdgcn_sched_barrier(0);
    STEP_BODY(cur);
#undef STAGE
#undef STEP_BODY

    // epilogue: + rowbias + 9-tap coverage, tanh, dot with va, reduce over a
    float partial[4] = {0.f, 0.f, 0.f, 0.f};
#pragma unroll
    for (int i = 0; i < 4; i++) {
#pragma unroll
        for (int r = 0; r < 4; r++) {
            int a = ah * 256 + aw * 64 + i * 16 + lg * 4 + r;
            float rbv = rb[b * DA + a];
            float vav = va[a];
            const float* Ga = G + a * 9;
            float g0 = Ga[0], g1 = Ga[1], g2 = Ga[2], g3 = Ga[3], g4 = Ga[4];
            float g5 = Ga[5], g6 = Ga[6], g7 = Ga[7], g8 = Ga[8];
#pragma unroll
            for (int j = 0; j < 4; j++) {
                int p = pt2 * 128 + pw * 64 + j * 16 + l15;
                int hh = p / WW_, ww = p % WW_;
                const float* ap = ap_s + hh * 50 + ww;
                float cov = g0 * ap[0] + g1 * ap[1] + g2 * ap[2] +
                            g3 * ap[50] + g4 * ap[51] + g5 * ap[52] +
                            g6 * ap[100] + g7 * ap[101] + g8 * ap[102];
                float e = tanhf(acc[i][j][r] + rbv + cov);
                partial[j] += vav * e;
            }
        }
    }
#pragma unroll
    for (int j = 0; j < 4; j++) {
        partial[j] += __shfl_xor(partial[j], 16);
        partial[j] += __shfl_xor(partial[j], 32);
    }
    if (lane < 16) {
#pragma unroll
        for (int j = 0; j < 4; j++) part_s[w][j * 16 + lane] = partial[j];
    }
    __syncthreads();
    if (t < 128) {
        int pg = t >> 6, pl = t & 63;
        float sum = (part_s[pg * 4 + 0][pl] + part_s[pg * 4 + 1][pl]) +
                    (part_s[pg * 4 + 2][pl] + part_s[pg * 4 + 3][pl]);
        alq[ah * 49152 + b * HW_ + pt2 * 128 + t] = sum;
    }
}

// ======= K2 fallback: LDS-staging version (Apack slot-swizzle aware) =======
#define LDW 40
__global__ __launch_bounds__(256) void k_att_lds(
    const unsigned short* __restrict__ Apack, const float* __restrict__ ctx,
    const float* __restrict__ G, const float* __restrict__ rb,
    const float* __restrict__ va, const float* __restrict__ apast,
    float* __restrict__ alogit) {
    __shared__ __attribute__((aligned(16))) short lsB[2][64 * LDW];
    __shared__ float ap_s[18 * 50];
    __shared__ float part_s[4 * 64];
    int b = blockIdx.y;
    int p0 = blockIdx.x * 64;
    int t = threadIdx.x;
    int w = t >> 6, lane = t & 63;
    int l15 = lane & 15, lg = lane >> 4;
    int sxA = lg ^ ((l15 >> 1) & 3);
    int pq = t & 15, kp = t >> 4;
    const float* ctx_b = ctx + (long)b * DC * HW_ + p0;

    for (int idx = t; idx < 900; idx += 256) {
        int hh = idx / 50, ww = idx % 50;
        float v = 0.f;
        if (hh >= 1 && hh <= HH_ && ww >= 1 && ww <= WW_)
            v = apast[b * HW_ + (hh - 1) * WW_ + (ww - 1)];
        ap_s[idx] = v;
    }

#define CTXLOAD(FA, FB, S)                                                   \
    do {                                                                     \
        int d_ = (S) * 32 + 2 * kp;                                          \
        const float* s0_ = ctx_b + (long)d_ * HW_ + pq;                      \
        bool g0_ = d_ < DC, g1_ = (d_ + 1) < DC;                             \
        _Pragma("unroll") for (int j_ = 0; j_ < 4; j_++) {                   \
            FA[j_] = g0_ ? s0_[16 * j_] : 0.f;                               \
            FB[j_] = g1_ ? s0_[HW_ + 16 * j_] : 0.f;                         \
        }                                                                    \
    } while (0)
#define STAGEW(FA, FB, BUF)                                                  \
    do {                                                                     \
        _Pragma("unroll") for (int j_ = 0; j_ < 4; j_++) {                   \
            ((unsigned*)lsB[BUF])[(pq + 16 * j_) * (LDW / 2) + kp] =         \
                (unsigned)f2b(FA[j_]) | ((unsigned)f2b(FB[j_]) << 16);       \
        }                                                                    \
    } while (0)
#define ALOAD(AF, S)                                                         \
    do {                                                                     \
        _Pragma("unroll") for (int i_ = 0; i_ < 8; i_++)                     \
            AF[i_] = *(const bf16x8*)(Apack +                                \
                ((long)((S)*512 + w * 128 + i_ * 16 + l15) * 4 + sxA) * 8);  \
    } while (0)
#define BREAD(BF, BUF)                                                       \
    do {                                                                     \
        _Pragma("unroll") for (int j_ = 0; j_ < 4; j_++)                     \
            BF[j_] = *(const bf16x8*)(&lsB[BUF][(j_ * 16 + l15) * LDW +      \
                                               lg * 8]);                     \
    } while (0)
#define MFMA8x4(AF, BF)                                                      \
    do {                                                                     \
        _Pragma("unroll") for (int i_ = 0; i_ < 8; i_++)                     \
            _Pragma("unroll") for (int j_ = 0; j_ < 4; j_++)                 \
                acc[i_][j_] = __builtin_amdgcn_mfma_f32_16x16x32_bf16(       \
                    AF[i_], BF[j_], acc[i_][j_], 0, 0, 0);                   \
    } while (0)

    f32x4 acc[8][4];
#pragma unroll
    for (int i = 0; i < 8; i++)
#pragma unroll
        for (int j = 0; j < 4; j++) acc[i][j] = {0.f, 0.f, 0.f, 0.f};

    float fa0[4], fb0[4], fa1[4], fb1[4];
    bf16x8 afr0[8], afr1[8], bfr[4];

    CTXLOAD(fa1, fb1, 0);
    ALOAD(afr0, 0);
    STAGEW(fa1, fb1, 0);
    CTXLOAD(fa1, fb1, 1);
    __syncthreads();

    for (int ss = 0; ss < NS; ss += 2) {
        if (ss + 2 < NS) CTXLOAD(fa0, fb0, ss + 2);
        ALOAD(afr1, ss + 1);
        BREAD(bfr, 0);
        STAGEW(fa1, fb1, 1);
        MFMA8x4(afr0, bfr);
        __syncthreads();
        if (ss + 3 < NS) CTXLOAD(fa1, fb1, ss + 3);
        if (ss + 2 < NS) {
            ALOAD(afr0, ss + 2);
            BREAD(bfr, 1);
            STAGEW(fa0, fb0, 0);
            MFMA8x4(afr1, bfr);
        } else {
            BREAD(bfr, 1);
            MFMA8x4(afr1, bfr);
        }
        __syncthreads();
    }

    float partial[4] = {0.f, 0.f, 0.f, 0.f};
#pragma unroll
    for (int i = 0; i < 8; i++) {
#pragma unroll
        for (int r = 0; r < 4; r++) {
            int a = w * 128 + i * 16 + lg * 4 + r;
            float rbv = rb[b * DA + a];
            float vav = va[a];
            const float* Ga = G + a * 9;
            float g0 = Ga[0], g1 = Ga[1], g2 = Ga[2], g3 = Ga[3], g4 = Ga[4];
            float g5 = Ga[5], g6 = Ga[6], g7 = Ga[7], g8 = Ga[8];
#pragma unroll
            for (int j = 0; j < 4; j++) {
                int p = p0 + j * 16 + l15;
                int hh = p / WW_, ww = p % WW_;
                const float* ap = ap_s + hh * 50 + ww;
                float cov = g0 * ap[0] + g1 * ap[1] + g2 * ap[2] +
                            g3 * ap[50] + g4 * ap[51] + g5 * ap[52] +
                            g6 * ap[100] + g7 * ap[101] + g8 * ap[102];
                float e = tanhf(acc[i][j][r] + rbv + cov);
                partial[j] += vav * e;
            }
        }
    }
#pragma unroll
    for (int j = 0; j < 4; j++) {
        partial[j] += __shfl_xor(partial[j], 16);
        partial[j] += __shfl_xor(partial[j], 32);
    }
    if (lane < 16) {
#pragma unroll
        for (int j = 0; j < 4; j++) part_s[w * 64 + j * 16 + lane] = partial[j];
    }
    __syncthreads();
    if (t < 64) {
        float s = part_s[t] + part_s[64 + t] + part_s[128 + t] +
                  part_s[192 + t];
        alogit[b * HW_ + p0 + t] = s;
    }
}

// ---------------- K3+K4 fused: (sum halves) + softmax + ct -----------------
__global__ __launch_bounds__(256) void k_ctsm(const float* __restrict__ ctx,
                                              const float* __restrict__ alq,
                                              float* __restrict__ ct,
                                              float* __restrict__ alpha_out) {
    __shared__ float al_s[HW_];
    __shared__ float red[16];
    int b = blockIdx.y, t = threadIdx.x;
    float v[3];
    float mx = -1e30f;
    for (int i = 0; i < 3; i++) {
        int idx = b * HW_ + i * 256 + t;
        v[i] = alq[idx] + alq[49152 + idx];
        mx = fmaxf(mx, v[i]);
    }
    for (int off = 32; off > 0; off >>= 1) mx = fmaxf(mx, __shfl_down(mx, off));
    if ((t & 63) == 0) red[t >> 6] = mx;
    __syncthreads();
    if (t == 0) red[0] = fmaxf(fmaxf(red[0], red[1]), fmaxf(red[2], red[3]));
    __syncthreads();
    mx = red[0];
    float sum = 0.f;
    for (int i = 0; i < 3; i++) {
        v[i] = expf(v[i] - mx);
        sum += v[i];
    }
    for (int off = 32; off > 0; off >>= 1) sum += __shfl_down(sum, off);
    if ((t & 63) == 0) red[8 + (t >> 6)] = sum;
    __syncthreads();
    if (t == 0) red[8] = red[8] + red[9] + red[10] + red[11];
    __syncthreads();
    float inv = 1.f / red[8];
    for (int i = 0; i < 3; i++) {
        float a = v[i] * inv;
        al_s[i * 256 + t] = a;
        if (blockIdx.x == 0) alpha_out[b * HW_ + i * 256 + t] = a;
    }
    __syncthreads();
    int dc0 = blockIdx.x * 114;
    int wave = t >> 6, lane = t & 63;
    for (int d = dc0 + wave; d < dc0 + 114; d += 4) {
        const float* row = &ctx[((long)b * DC + d) * HW_];
        float s = 0.f;
#pragma unroll
        for (int q = 0; q < 12; q++) s += row[lane + q * 64] * al_s[lane + q * 64];
        for (int off = 32; off > 0; off >>= 1) s += __shfl_down(s, off);
        if (lane == 0) ct[b * DC + d] = s;
    }
}

// ---------------- K5: logit rows -------------------------------------------
__global__ __launch_bounds__(256) void k_logit(
    const float* __restrict__ ctv, const float* __restrict__ s,
    const float* __restrict__ embedded, const float* __restrict__ Wct,
    const float* __restrict__ Wht, const float* __restrict__ Wct_b,
    const float* __restrict__ Wht_b, float* __restrict__ lg) {
    __shared__ float Xs[64 * 257];
    __shared__ float Ws[4 * 232];
    int t = threadIdx.x, w = t >> 6, lane = t & 63;
    int r = blockIdx.x * 4 + w;
    float acc = 0.f;
    for (int c = 0; c < 3; c++) {
        int c0 = c * 228;
        __syncthreads();
        for (int i = t; i < 64 * 228; i += 256) {
            int bb = i / 228, kk = i - bb * 228;
            Xs[bb * 229 + kk] = ctv[bb * DC + c0 + kk];
        }
        for (int j = lane; j < 228; j += 64) Ws[w * 232 + j] = Wct[r * DC + c0 + j];
        __syncthreads();
        const float* xrow = Xs + lane * 229;
        const float* wrow = Ws + w * 232;
#pragma unroll 4
        for (int k = 0; k < 228; k++) acc += wrow[k] * xrow[k];
    }
    __syncthreads();
    for (int i = t; i < 64 * 256; i += 256) {
        int bb = i >> 8, k = i & 255;
        Xs[bb * 257 + k] = s[bb * 256 + k];
    }
    __syncthreads();
    const float* xrow2 = Xs + lane * 257;
    const float* wr = Wht + r * 256;
    float acc2 = 0.f;
#pragma unroll 8
    for (int k = 0; k < 256; k++) acc2 += wr[k] * xrow2[k];
    lg[lane * 256 + r] = acc + acc2 + Wct_b[r] + Wht_b[r] + embedded[lane * 256 + r];
}

// ---------------- K6: maxout + W0 head -------------------------------------
__global__ __launch_bounds__(256) void k_head(const float* __restrict__ lg,
                                              const float* __restrict__ W0,
                                              const float* __restrict__ W0_b,
                                              float* __restrict__ out) {
    __shared__ float Xs[64 * 129];
    __shared__ float Ws[4 * 132];
    int t = threadIdx.x, w = t >> 6, lane = t & 63;
    for (int i = t; i < 64 * 128; i += 256) {
        int bb = i >> 7, m = i & 127;
        Xs[bb * 129 + m] = fmaxf(lg[bb * 256 + 2 * m], lg[bb * 256 + 2 * m + 1]);
    }
    int r = blockIdx.x * 4 + w;
    Ws[w * 132 + lane] = W0[r * 128 + lane];
    Ws[w * 132 + 64 + lane] = W0[r * 128 + 64 + lane];
    __syncthreads();
    const float* xrow = Xs + lane * 129;
    const float* wrow = Ws + w * 132;
    float acc = 0.f;
#pragma unroll 8
    for (int k = 0; k < 128; k++) acc += wrow[k] * xrow[k];
    out[lane * KV + r] = acc + W0_b[r];
}

extern "C" void kernel_launch(void* const* d_in, const int* in_sizes, int n_in,
                              void* d_out, int out_size, void* d_ws,
                              size_t ws_size, hipStream_t stream) {
    const int* y = (const int*)d_in[0];
    const float* y_mask = (const float*)d_in[1];
    const float* context = (const float*)d_in[2];
    const float* pre_hidden = (const float*)d_in[3];
    const float* alpha_past = (const float*)d_in[4];
    const float* emb = (const float*)d_in[5];
    const float* W_ih1 = (const float*)d_in[6];
    const float* W_hh1 = (const float*)d_in[7];
    const float* b_ih1 = (const float*)d_in[8];
    const float* b_hh1 = (const float*)d_in[9];
    const float* conv_Ua_w = (const float*)d_in[10];
    const float* conv_Ua_b = (const float*)d_in[11];
    const float* Wa = (const float*)d_in[12];
    const float* conv_Q_w = (const float*)d_in[13];
    const float* Uf = (const float*)d_in[14];
    const float* Uf_b = (const float*)d_in[15];
    const float* va = (const float*)d_in[16];
    const float* va_b = (const float*)d_in[17];
    const float* W_ih2 = (const float*)d_in[18];
    const float* W_hh2 = (const float*)d_in[19];
    const float* b_ih2 = (const float*)d_in[20];
    const float* b_hh2 = (const float*)d_in[21];
    const float* Wct = (const float*)d_in[22];
    const float* Wct_b = (const float*)d_in[23];
    const float* Wht = (const float*)d_in[24];
    const float* Wht_b = (const float*)d_in[25];
    const float* W0 = (const float*)d_in[26];
    const float* W0_b = (const float*)d_in[27];

    float* ws = (float*)d_ws;
    float* out = (float*)d_out;
    float* G = ws + WS_G;
    float* rbias = ws + WS_RB;
    float* embedded = ws + WS_EMB;
    float* s_hat = ws + WS_SH;
    float* ctv = ws + WS_CT;
    unsigned short* Apack = (unsigned short*)(ws + WS_APACK);
    float* gi = ws + WS_GI;
    float* gh = ws + WS_GH;
    float* lg = ws + WS_LG;
    unsigned short* Bpack = (unsigned short*)(ws + WS_BP);
    float* alq = ws + WS_ALQ;
    float* s_out = out + 8192;
    float* alpha_out = out + 24576;

    bool fast = ws_size >= NEED_BYTES;

    if (fast) {
        k_prep<<<dim3(929), dim3(512), 0, stream>>>(context, conv_Ua_w, Uf,
                                                    conv_Q_w, y, emb, Bpack,
                                                    Apack, G, embedded);
    } else {
        k_G<<<dim3(18), dim3(256), 0, stream>>>(Uf, conv_Q_w, G);
        k_prepA<<<dim3((NS * DA * 32 + 255) / 256), dim3(256), 0, stream>>>(
            conv_Ua_w, Apack);
        k_emb<<<dim3(64), dim3(256), 0, stream>>>(y, emb, embedded);
    }
    k_gih1<<<dim3(384), dim3(256), 0, stream>>>(embedded, pre_hidden, W_ih1,
                                                W_hh1, b_ih1, b_hh1, gi, gh);
    k_gru<<<dim3(64), dim3(256), 0, stream>>>(gi, gh, pre_hidden, y_mask, s_hat);
    k_rows256<<<dim3(128), dim3(256), 0, stream>>>(s_hat, Wa, conv_Ua_b, Uf_b,
                                                   rbias, 512);
    if (fast) {
        k_att3<<<dim3(6, 2, 64), dim3(512), 0, stream>>>(
            Apack, Bpack, G, rbias, va, alpha_past, alq);
    } else {
        // fallback: write half 0, zero half 1
        hipMemsetAsync(alq + 49152, 0, (size_t)49152 * sizeof(float), stream);
        k_att_lds<<<dim3(12, 64), dim3(256), 0, stream>>>(
            Apack, context, G, rbias, va, alpha_past, alq);
    }
    k_ctsm<<<dim3(6, 64), dim3(256), 0, stream>>>(context, alq, ctv, alpha_out);
    k_gih2<<<dim3(384), dim3(256), 0, stream>>>(ctv, s_hat, W_ih2, W_hh2, b_ih2,
                                                b_hh2, gi, gh);
    k_gru<<<dim3(64), dim3(256), 0, stream>>>(gi, gh, s_hat, y_mask, s_out);
    k_logit<<<dim3(64), dim3(256), 0, stream>>>(ctv, s_out, embedded, Wct, Wht,
                                                Wct_b, Wht_b, lg);
    k_head<<<dim3(32), dim3(256), 0, stream>>>(lg, W0, W0_b, out);
}